// Round 1
// baseline (755.493 us; speedup 1.0000x reference)
//
#include <hip/hip_runtime.h>
#include <cstdint>
#include <cstddef>

// Problem constants (B,S,D,H) = (2,2048,2048,16), DH=128
#define Bq  2
#define Sq  2048
#define Dq  2048
#define Hq  16
#define DHq 128
#define E3q 6144   // 3*D

typedef __attribute__((ext_vector_type(8))) short s16x8;   // 8 bf16 (4 VGPRs)
typedef __attribute__((ext_vector_type(4))) float f32x4;   // MFMA accumulator

__device__ __forceinline__ unsigned short f2bf(float f){
  union { float f; unsigned u; } v; v.f = f;
  unsigned r = v.u + 0x7FFFu + ((v.u >> 16) & 1u);   // round-to-nearest-even
  return (unsigned short)(r >> 16);
}
__device__ __forceinline__ float bf2f(unsigned short b){
  union { unsigned u; float f; } v; v.u = ((unsigned)b) << 16;
  return v.f;
}

// ---------------- fp32 -> bf16 convert (vectorized x4) ----------------
__global__ __launch_bounds__(256) void k_convert(const float* __restrict__ in,
                                                 unsigned short* __restrict__ out, int n4){
  int stride = gridDim.x * blockDim.x;
  for (int i = blockIdx.x*blockDim.x + threadIdx.x; i < n4; i += stride){
    float4 v = reinterpret_cast<const float4*>(in)[i];
    ushort4 o;
    o.x = f2bf(v.x); o.y = f2bf(v.y); o.z = f2bf(v.z); o.w = f2bf(v.w);
    reinterpret_cast<ushort4*>(out)[i] = o;
  }
}

// ---------------- bf16 B^T GEMM: C[m,n] = sum_k A[m,k]*Bt[n,k] + bias[n] ----
// 128x128 tile, BK=32, 256 threads (4 waves, 2x2), 4x4 16x16 frags per wave.
// Verified frag recipe: A/B operand = 8 contiguous bf16 at row (lane&15),
// k-base (lane>>4)*8; C/D: row=(lane>>4)*4+r, col=lane&15.
template<int F32OUT>
__global__ __launch_bounds__(256) void k_gemm_bt(const unsigned short* __restrict__ A,
                                                 const unsigned short* __restrict__ Bt,
                                                 const float* __restrict__ bias,
                                                 void* __restrict__ C,
                                                 int M, int N, int K){
  const int tid = threadIdx.x;
  const int w = tid >> 6, lane = tid & 63, g = lane >> 4, c = lane & 15;
  const int wm = w >> 1, wn = w & 1;
  const int m0 = blockIdx.y * 128, n0 = blockIdx.x * 128;

  __shared__ __align__(16) unsigned short As[128*32];
  __shared__ __align__(16) unsigned short Bs[128*32];

  f32x4 acc[4][4];
#pragma unroll
  for (int i=0;i<4;i++)
#pragma unroll
    for (int j=0;j<4;j++)
#pragma unroll
      for (int r=0;r<4;r++) acc[i][j][r] = 0.f;

  const int ch0 = tid, ch1 = tid + 256;   // 512 chunks of 8 bf16 per 128x32 tile

  for (int kt = 0; kt < K; kt += 32){
    // register-staged global loads (16B/lane, coalesced)
    s16x8 ra0 = *(const s16x8*)&A [(size_t)(m0 + (ch0>>2))*K + kt + (ch0&3)*8];
    s16x8 ra1 = *(const s16x8*)&A [(size_t)(m0 + (ch1>>2))*K + kt + (ch1&3)*8];
    s16x8 rb0 = *(const s16x8*)&Bt[(size_t)(n0 + (ch0>>2))*K + kt + (ch0&3)*8];
    s16x8 rb1 = *(const s16x8*)&Bt[(size_t)(n0 + (ch1>>2))*K + kt + (ch1&3)*8];
    __syncthreads();   // previous iteration's LDS reads complete
    *(s16x8*)&As[ch0*8] = ra0;
    *(s16x8*)&As[ch1*8] = ra1;
    *(s16x8*)&Bs[ch0*8] = rb0;
    *(s16x8*)&Bs[ch1*8] = rb1;
    __syncthreads();   // tile staged

    s16x8 af[4], bfr[4];
#pragma unroll
    for (int i=0;i<4;i++){
      af[i]  = *(const s16x8*)&As[(wm*64 + i*16 + c)*32 + g*8];
      bfr[i] = *(const s16x8*)&Bs[(wn*64 + i*16 + c)*32 + g*8];
    }
#pragma unroll
    for (int mi=0;mi<4;mi++)
#pragma unroll
      for (int ni=0;ni<4;ni++)
        acc[mi][ni] = __builtin_amdgcn_mfma_f32_16x16x32_bf16(af[mi], bfr[ni], acc[mi][ni], 0,0,0);
  }

#pragma unroll
  for (int mi=0;mi<4;mi++)
#pragma unroll
    for (int ni=0;ni<4;ni++)
#pragma unroll
      for (int r=0;r<4;r++){
        int row = m0 + wm*64 + mi*16 + g*4 + r;
        int col = n0 + wn*64 + ni*16 + c;
        float v = acc[mi][ni][r] + bias[col];
        if (F32OUT) ((float*)C)[(size_t)row*N + col] = v;
        else ((unsigned short*)C)[(size_t)row*N + col] = f2bf(v);
      }
}

// ---------------- RoPE + qk RMS-norm + split/reshape -----------------------
// block (64,4): tx = rotation pair p (0..63), ty = s-sub. One wave per s.
__global__ __launch_bounds__(256) void k_rope_split(const unsigned short* __restrict__ QKV,
                                                    const float* __restrict__ rp,
                                                    const float* __restrict__ qk_w,
                                                    unsigned short* __restrict__ Qp,
                                                    unsigned short* __restrict__ Kp,
                                                    unsigned short* __restrict__ Vt){
  const int p = threadIdx.x;
  const int s = blockIdx.x*4 + threadIdx.y;
  const int h = blockIdx.y;
  const int b = blockIdx.z;
  const size_t n = (size_t)b*Sq + s;
  const int bh = b*Hq + h;

  float ang = rp[s*64 + p];
  float sn, cs; sincosf(ang, &sn, &cs);
  float w0 = qk_w[2*p], w1 = qk_w[2*p+1];

  // ---- Q ----
  {
    unsigned q01 = *(const unsigned*)&QKV[n*E3q + h*DHq + 2*p];
    float x0 = bf2f((unsigned short)(q01 & 0xFFFFu));
    float x1 = bf2f((unsigned short)(q01 >> 16));
    float r0 = x0*cs - x1*sn, r1 = x0*sn + x1*cs;
    float ss = r0*r0 + r1*r1;
#pragma unroll
    for (int m=1;m<64;m<<=1) ss += __shfl_xor(ss, m);
    float sc = rsqrtf(ss/128.f + 1e-6f);
    unsigned short o0 = f2bf(r0*sc*w0), o1 = f2bf(r1*sc*w1);
    *(unsigned*)&Qp[((size_t)bh*Sq + s)*DHq + 2*p] = (unsigned)o0 | ((unsigned)o1<<16);
  }
  // ---- K ----
  {
    unsigned k01 = *(const unsigned*)&QKV[n*E3q + Dq + h*DHq + 2*p];
    float x0 = bf2f((unsigned short)(k01 & 0xFFFFu));
    float x1 = bf2f((unsigned short)(k01 >> 16));
    float r0 = x0*cs - x1*sn, r1 = x0*sn + x1*cs;
    float ss = r0*r0 + r1*r1;
#pragma unroll
    for (int m=1;m<64;m<<=1) ss += __shfl_xor(ss, m);
    float sc = rsqrtf(ss/128.f + 1e-6f);
    unsigned short o0 = f2bf(r0*sc*w0), o1 = f2bf(r1*sc*w1);
    *(unsigned*)&Kp[((size_t)bh*Sq + s)*DHq + 2*p] = (unsigned)o0 | ((unsigned)o1<<16);
  }
  // ---- V: transpose to [bh][dh][s] so PV B-operand reads are contiguous ----
  {
    unsigned v01 = *(const unsigned*)&QKV[n*E3q + 2*Dq + h*DHq + 2*p];
    Vt[((size_t)bh*DHq + 2*p    )*Sq + s] = (unsigned short)(v01 & 0xFFFFu);
    Vt[((size_t)bh*DHq + 2*p + 1)*Sq + s] = (unsigned short)(v01 >> 16);
  }
}

// ---------------- causal MFMA flash attention ------------------------------
// grid (S/64, B*H), 256 threads. Wave w owns 16 q-rows; j-step = 32 keys.
__global__ __launch_bounds__(256) void k_attn(const unsigned short* __restrict__ Qp,
                                              const unsigned short* __restrict__ Kp,
                                              const unsigned short* __restrict__ Vt,
                                              unsigned short* __restrict__ Ar){
  const int qtile = gridDim.x - 1 - blockIdx.x;   // heavy tiles dispatch first
  const int bh = blockIdx.y;
  const int b = bh / Hq, h = bh % Hq;
  const int tid = threadIdx.x;
  const int w = tid >> 6, lane = tid & 63, g = lane >> 4, c = lane & 15;
  const int r0 = qtile*64 + w*16;

  const unsigned short* Qh = Qp + (size_t)bh * Sq * DHq;
  const unsigned short* Kh = Kp + (size_t)bh * Sq * DHq;
  const unsigned short* Vh = Vt + (size_t)bh * DHq * Sq;

  // Q frags: A[m=c][k=g*8+i] per 32-wide k-chunk
  s16x8 qf[4];
#pragma unroll
  for (int kc=0;kc<4;kc++)
    qf[kc] = *(const s16x8*)&Qh[(size_t)(r0 + c)*DHq + kc*32 + g*8];

  f32x4 acc[8];
#pragma unroll
  for (int d=0;d<8;d++)
#pragma unroll
    for (int r=0;r<4;r++) acc[d][r] = 0.f;
  float m_r[4], l_r[4];
#pragma unroll
  for (int r=0;r<4;r++){ m_r[r] = -INFINITY; l_r[r] = 0.f; }

  __shared__ __align__(16) unsigned short Plds[4][16][32];
  const float scale = 0.08838834764831845f;  // 1/sqrt(128)

  const int nsteps = (r0 + 15)/32 + 1;       // causal bound for this wave
  for (int jt = 0; jt < nsteps; jt++){
    const int j0 = jt*32;
    // ---- S tile 16x32 = Q (16x128) . K^T ----
    f32x4 s01[2];
#pragma unroll
    for (int hh=0; hh<2; hh++){
      f32x4 s;
#pragma unroll
      for (int r=0;r<4;r++) s[r] = 0.f;
#pragma unroll
      for (int kc=0;kc<4;kc++){
        s16x8 kf = *(const s16x8*)&Kh[(size_t)(j0 + hh*16 + c)*DHq + kc*32 + g*8];
        s = __builtin_amdgcn_mfma_f32_16x16x32_bf16(qf[kc], kf, s, 0,0,0);
      }
      s01[hh] = s;
    }
    // ---- scale + causal mask + online softmax ----
    float p0[4], p1[4], pm[4];
#pragma unroll
    for (int r=0;r<4;r++){
      int row = r0 + g*4 + r;
      float v0 = (j0 + c      <= row) ? s01[0][r]*scale : -INFINITY;
      float v1 = (j0 + 16 + c <= row) ? s01[1][r]*scale : -INFINITY;
      p0[r] = v0; p1[r] = v1;
      float mx = fmaxf(v0, v1);
      mx = fmaxf(mx, __shfl_xor(mx, 1));
      mx = fmaxf(mx, __shfl_xor(mx, 2));
      mx = fmaxf(mx, __shfl_xor(mx, 4));
      mx = fmaxf(mx, __shfl_xor(mx, 8));
      pm[r] = mx;
    }
#pragma unroll
    for (int r=0;r<4;r++){
      float mnew = fmaxf(m_r[r], pm[r]);
      float corr = __expf(m_r[r] - mnew);
      float e0 = __expf(p0[r] - mnew);
      float e1 = __expf(p1[r] - mnew);
      p0[r] = e0; p1[r] = e1;
      float rs = e0 + e1;
      rs += __shfl_xor(rs, 1);
      rs += __shfl_xor(rs, 2);
      rs += __shfl_xor(rs, 4);
      rs += __shfl_xor(rs, 8);
      l_r[r] = l_r[r]*corr + rs;
      m_r[r] = mnew;
#pragma unroll
      for (int d=0; d<8; d++) acc[d][r] *= corr;
    }
    // ---- P -> LDS (per-wave region, no barrier needed) ----
#pragma unroll
    for (int r=0;r<4;r++){
      Plds[w][g*4+r][c]      = f2bf(p0[r]);
      Plds[w][g*4+r][16 + c] = f2bf(p1[r]);
    }
    // ---- PV: O += P (16x32) . V (32x128) ----
    s16x8 pf = *(const s16x8*)&Plds[w][c][g*8];
#pragma unroll
    for (int d=0; d<8; d++){
      s16x8 vf = *(const s16x8*)&Vh[(size_t)(d*16 + c)*Sq + j0 + g*8];
      acc[d] = __builtin_amdgcn_mfma_f32_16x16x32_bf16(pf, vf, acc[d], 0,0,0);
    }
  }
  // ---- epilogue: normalize, write A in (b,s,h*DH+dh) layout ----
#pragma unroll
  for (int d=0; d<8; d++)
#pragma unroll
    for (int r=0;r<4;r++){
      int row = r0 + g*4 + r;
      float o = acc[d][r] / l_r[r];
      Ar[((size_t)(b*Sq + row))*Dq + h*DHq + d*16 + c] = f2bf(o);
    }
}

// ---------------- row RMS-norm over D=2048, in place -----------------------
__global__ __launch_bounds__(256) void k_rmsnorm(unsigned short* __restrict__ A,
                                                 const float* __restrict__ w){
  const int row = blockIdx.x;
  const int tid = threadIdx.x;
  s16x8 v = *(const s16x8*)&A[(size_t)row*Dq + tid*8];
  float f[8]; float ss = 0.f;
#pragma unroll
  for (int i=0;i<8;i++){ f[i] = bf2f((unsigned short)v[i]); ss += f[i]*f[i]; }
#pragma unroll
  for (int m=1;m<64;m<<=1) ss += __shfl_xor(ss, m);
  __shared__ float red[4];
  if ((tid&63)==0) red[tid>>6] = ss;
  __syncthreads();
  ss = red[0]+red[1]+red[2]+red[3];
  float sc = rsqrtf(ss/2048.f + 1e-6f);
  unsigned short o[8];
#pragma unroll
  for (int i=0;i<8;i++) o[i] = f2bf(f[i]*sc*w[tid*8+i]);
  *(s16x8*)&A[(size_t)row*Dq + tid*8] = *(const s16x8*)o;
}

extern "C" void kernel_launch(void* const* d_in, const int* in_sizes, int n_in,
                              void* d_out, int out_size, void* d_ws, size_t ws_size,
                              hipStream_t stream){
  const float* x     = (const float*)d_in[0];
  const float* rp    = (const float*)d_in[1];
  const float* Win   = (const float*)d_in[2];
  const float* b_in  = (const float*)d_in[3];
  const float* Wout  = (const float*)d_in[4];
  const float* b_out = (const float*)d_in[5];
  const float* qk_w  = (const float*)d_in[6];
  const float* out_w = (const float*)d_in[7];
  float* outp = (float*)d_out;

  if (ws_size < (160ull<<20)) return;   // need 160 MiB scratch

  char* ws = (char*)d_ws;
  unsigned short* Xb    = (unsigned short*)(ws);                 // 16 MiB
  unsigned short* Wb    = (unsigned short*)(ws + (16ull<<20));   // 24 MiB
  unsigned short* Woutb = (unsigned short*)(ws + (40ull<<20));   //  8 MiB
  unsigned short* QKVb  = (unsigned short*)(ws + (48ull<<20));   // 48 MiB
  unsigned short* Qp    = (unsigned short*)(ws + (96ull<<20));   // 16 MiB
  unsigned short* Kp    = (unsigned short*)(ws + (112ull<<20));  // 16 MiB
  unsigned short* Vt    = (unsigned short*)(ws + (128ull<<20));  // 16 MiB
  unsigned short* Ar    = (unsigned short*)(ws + (144ull<<20));  // 16 MiB

  // 1) converts
  k_convert<<<2048, 256, 0, stream>>>(x,    Xb,    (Bq*Sq*Dq)/4);
  k_convert<<<2048, 256, 0, stream>>>(Win,  Wb,    (E3q*Dq)/4);
  k_convert<<<1024, 256, 0, stream>>>(Wout, Woutb, (Dq*Dq)/4);
  // 2) QKV = X . Win^T + b_in   (M=4096, N=6144, K=2048)
  k_gemm_bt<0><<<dim3(E3q/128, (Bq*Sq)/128), 256, 0, stream>>>(Xb, Wb, b_in, QKVb,
                                                               Bq*Sq, E3q, Dq);
  // 3) RoPE + qk RMS-norm + split (V transposed)
  k_rope_split<<<dim3(Sq/4, Hq, Bq), dim3(64,4), 0, stream>>>(QKVb, rp, qk_w, Qp, Kp, Vt);
  // 4) causal flash attention
  k_attn<<<dim3(Sq/64, Bq*Hq), 256, 0, stream>>>(Qp, Kp, Vt, Ar);
  // 5) out RMS-norm (in place on Ar)
  k_rmsnorm<<<Bq*Sq, 256, 0, stream>>>(Ar, out_w);
  // 6) Out = A . Wout^T + b_out  (M=4096, N=2048, K=2048), fp32 out
  k_gemm_bt<1><<<dim3(Dq/128, (Bq*Sq)/128), 256, 0, stream>>>(Ar, Woutb, b_out, outp,
                                                              Bq*Sq, Dq, Dq);
}

// Round 2
// 431.316 us; speedup vs baseline: 1.7516x; 1.7516x over previous
//
#include <hip/hip_runtime.h>
#include <cstdint>
#include <cstddef>

// Problem constants (B,S,D,H) = (2,2048,2048,16), DH=128
#define Bq  2
#define Sq  2048
#define Dq  2048
#define Hq  16
#define DHq 128
#define E3q 6144   // 3*D

typedef __attribute__((ext_vector_type(8))) short s16x8;   // 8 bf16 (4 VGPRs)
typedef __attribute__((ext_vector_type(4))) float f32x4;   // MFMA accumulator

__device__ __forceinline__ unsigned short f2bf(float f){
  union { float f; unsigned u; } v; v.f = f;
  unsigned r = v.u + 0x7FFFu + ((v.u >> 16) & 1u);   // round-to-nearest-even
  return (unsigned short)(r >> 16);
}
__device__ __forceinline__ float bf2f(unsigned short b){
  union { unsigned u; float f; } v; v.u = ((unsigned)b) << 16;
  return v.f;
}

// async global->LDS, 16B per lane. LDS dest must be wave-uniform base + lane*16.
__device__ __forceinline__ void gload_lds16(const void* g, void* l){
  __builtin_amdgcn_global_load_lds(
      (const __attribute__((address_space(1))) void*)g,
      (__attribute__((address_space(3))) void*)l, 16, 0, 0);
}

// ---------------- fp32 -> bf16 convert (vectorized x4) ----------------
__global__ __launch_bounds__(256) void k_convert(const float* __restrict__ in,
                                                 unsigned short* __restrict__ out, int n4){
  int stride = gridDim.x * blockDim.x;
  for (int i = blockIdx.x*blockDim.x + threadIdx.x; i < n4; i += stride){
    float4 v = reinterpret_cast<const float4*>(in)[i];
    ushort4 o;
    o.x = f2bf(v.x); o.y = f2bf(v.y); o.z = f2bf(v.z); o.w = f2bf(v.w);
    reinterpret_cast<ushort4*>(out)[i] = o;
  }
}

// ---------------- bf16 B^T GEMM: C[m,n] = sum_k A[m,k]*Bt[n,k] + bias[n] ----
// m97 structure: 128x128 tile, BK=32, 4 waves, global_load_lds width-16 staging.
template<int F32OUT>
__global__ __launch_bounds__(256) void k_gemm_bt(const unsigned short* __restrict__ A,
                                                 const unsigned short* __restrict__ Bt,
                                                 const float* __restrict__ bias,
                                                 void* __restrict__ C,
                                                 int M, int N, int K){
  const int tid = threadIdx.x;
  const int w = tid >> 6, lane = tid & 63, g = lane >> 4, c = lane & 15;
  const int wm = w >> 1, wn = w & 1;
  const int m0 = blockIdx.y * 128, n0 = blockIdx.x * 128;

  __shared__ __align__(16) unsigned short As[128*32];
  __shared__ __align__(16) unsigned short Bs[128*32];

  f32x4 acc[4][4];
#pragma unroll
  for (int i=0;i<4;i++)
#pragma unroll
    for (int j=0;j<4;j++)
#pragma unroll
      for (int r=0;r<4;r++) acc[i][j][r] = 0.f;

  const int ch0 = tid, ch1 = tid + 256;   // 512 chunks of 8 bf16 per 128x32 tile

  for (int kt = 0; kt < K; kt += 32){
    __syncthreads();   // prev iteration's LDS reads complete before overwrite
    gload_lds16(&A [(size_t)(m0 + (ch0>>2))*K + kt + (ch0&3)*8], &As[ch0*8]);
    gload_lds16(&A [(size_t)(m0 + (ch1>>2))*K + kt + (ch1&3)*8], &As[ch1*8]);
    gload_lds16(&Bt[(size_t)(n0 + (ch0>>2))*K + kt + (ch0&3)*8], &Bs[ch0*8]);
    gload_lds16(&Bt[(size_t)(n0 + (ch1>>2))*K + kt + (ch1&3)*8], &Bs[ch1*8]);
    __syncthreads();   // tile staged (syncthreads drains vmcnt)

    s16x8 af[4], bfr[4];
#pragma unroll
    for (int i=0;i<4;i++){
      af[i]  = *(const s16x8*)&As[(wm*64 + i*16 + c)*32 + g*8];
      bfr[i] = *(const s16x8*)&Bs[(wn*64 + i*16 + c)*32 + g*8];
    }
#pragma unroll
    for (int mi=0;mi<4;mi++)
#pragma unroll
      for (int ni=0;ni<4;ni++)
        acc[mi][ni] = __builtin_amdgcn_mfma_f32_16x16x32_bf16(af[mi], bfr[ni], acc[mi][ni], 0,0,0);
  }

#pragma unroll
  for (int mi=0;mi<4;mi++)
#pragma unroll
    for (int ni=0;ni<4;ni++)
#pragma unroll
      for (int r=0;r<4;r++){
        int row = m0 + wm*64 + mi*16 + g*4 + r;
        int col = n0 + wn*64 + ni*16 + c;
        float v = acc[mi][ni][r] + bias[col];
        if (F32OUT) ((float*)C)[(size_t)row*N + col] = v;
        else ((unsigned short*)C)[(size_t)row*N + col] = f2bf(v);
      }
}

// ---------------- RoPE + qk RMS-norm + split/reshape -----------------------
__global__ __launch_bounds__(256) void k_rope_split(const unsigned short* __restrict__ QKV,
                                                    const float* __restrict__ rp,
                                                    const float* __restrict__ qk_w,
                                                    unsigned short* __restrict__ Qp,
                                                    unsigned short* __restrict__ Kp,
                                                    unsigned short* __restrict__ Vt){
  const int p = threadIdx.x;
  const int s = blockIdx.x*4 + threadIdx.y;
  const int h = blockIdx.y;
  const int b = blockIdx.z;
  const size_t n = (size_t)b*Sq + s;
  const int bh = b*Hq + h;

  float ang = rp[s*64 + p];
  float sn, cs; sincosf(ang, &sn, &cs);
  float w0 = qk_w[2*p], w1 = qk_w[2*p+1];

  {
    unsigned q01 = *(const unsigned*)&QKV[n*E3q + h*DHq + 2*p];
    float x0 = bf2f((unsigned short)(q01 & 0xFFFFu));
    float x1 = bf2f((unsigned short)(q01 >> 16));
    float r0 = x0*cs - x1*sn, r1 = x0*sn + x1*cs;
    float ss = r0*r0 + r1*r1;
#pragma unroll
    for (int m=1;m<64;m<<=1) ss += __shfl_xor(ss, m);
    float sc = rsqrtf(ss/128.f + 1e-6f);
    unsigned short o0 = f2bf(r0*sc*w0), o1 = f2bf(r1*sc*w1);
    *(unsigned*)&Qp[((size_t)bh*Sq + s)*DHq + 2*p] = (unsigned)o0 | ((unsigned)o1<<16);
  }
  {
    unsigned k01 = *(const unsigned*)&QKV[n*E3q + Dq + h*DHq + 2*p];
    float x0 = bf2f((unsigned short)(k01 & 0xFFFFu));
    float x1 = bf2f((unsigned short)(k01 >> 16));
    float r0 = x0*cs - x1*sn, r1 = x0*sn + x1*cs;
    float ss = r0*r0 + r1*r1;
#pragma unroll
    for (int m=1;m<64;m<<=1) ss += __shfl_xor(ss, m);
    float sc = rsqrtf(ss/128.f + 1e-6f);
    unsigned short o0 = f2bf(r0*sc*w0), o1 = f2bf(r1*sc*w1);
    *(unsigned*)&Kp[((size_t)bh*Sq + s)*DHq + 2*p] = (unsigned)o0 | ((unsigned)o1<<16);
  }
  {
    unsigned v01 = *(const unsigned*)&QKV[n*E3q + 2*Dq + h*DHq + 2*p];
    Vt[((size_t)bh*DHq + 2*p    )*Sq + s] = (unsigned short)(v01 & 0xFFFFu);
    Vt[((size_t)bh*DHq + 2*p + 1)*Sq + s] = (unsigned short)(v01 >> 16);
  }
}

// ---------------- causal MFMA flash attention ------------------------------
// Q-block 128 (4 waves x 32 rows), KV-step 64. K/V double-buffered in LDS via
// global_load_lds; XOR-swizzled source + swizzled reads (rule 21).
__global__ __launch_bounds__(256, 2) void k_attn(const unsigned short* __restrict__ Qp,
                                                 const unsigned short* __restrict__ Kp,
                                                 const unsigned short* __restrict__ Vt,
                                                 unsigned short* __restrict__ Ar){
  const int qtile = gridDim.x - 1 - blockIdx.x;   // heavy tiles dispatch first
  const int bh = blockIdx.y;
  const int b = bh >> 4, h = bh & 15;
  const int tid = threadIdx.x;
  const int w = tid >> 6, lane = tid & 63, g = lane >> 4, c = lane & 15;
  const int r0w = qtile*128 + w*32;

  const unsigned short* Qh = Qp + (size_t)bh * Sq * DHq;
  const unsigned short* Kh = Kp + (size_t)bh * Sq * DHq;
  const unsigned short* Vh = Vt + (size_t)bh * DHq * Sq;

  __shared__ __align__(16) unsigned short Ks[2][64*128];   // 32 KB
  __shared__ __align__(16) unsigned short Vs[2][128*64];   // 32 KB
  __shared__ __align__(16) unsigned short Pl[4][32*64];    // 16 KB
  unsigned short* Pw = &Pl[w][0];

  // Q fragments: A[m = c][k = kc*32 + g*8 ..+8], rows r0w + mi*16 + c
  s16x8 qf[2][4];
#pragma unroll
  for (int mi=0;mi<2;mi++)
#pragma unroll
    for (int kc=0;kc<4;kc++)
      qf[mi][kc] = *(const s16x8*)&Qh[(size_t)(r0w + mi*16 + c)*DHq + kc*32 + g*8];

  f32x4 acc[2][8];
#pragma unroll
  for (int mi=0;mi<2;mi++)
#pragma unroll
    for (int d=0;d<8;d++)
#pragma unroll
      for (int r=0;r<4;r++) acc[mi][d][r] = 0.f;
  float m_r[2][4], l_r[2][4];
#pragma unroll
  for (int mi=0;mi<2;mi++)
#pragma unroll
    for (int r=0;r<4;r++){ m_r[mi][r] = -INFINITY; l_r[mi][r] = 0.f; }

  const float scale = 0.08838834764831845f;  // 1/sqrt(128)
  const int nsteps = 2*qtile + 2;

  // stage K (64x128) and V^T (128x64) tiles; linear LDS dest, swizzled source
  auto stage = [&](int j0s, int bufi){
#pragma unroll
    for (int i=0;i<4;i++){
      int p = tid + i*256;               // K: 1024 chunks of 16B
      int row = p>>4, pc = p&15;
      gload_lds16(&Kh[(size_t)(j0s+row)*DHq + ((pc^(row&7))<<3)], &Ks[bufi][p*8]);
    }
#pragma unroll
    for (int i=0;i<4;i++){
      int p = tid + i*256;               // V: 1024 chunks of 16B
      int row = p>>3, pc = p&7;
      gload_lds16(&Vh[(size_t)row*Sq + j0s + ((pc^(row&7))<<3)], &Vs[bufi][p*8]);
    }
  };

  stage(0, 0);
  __syncthreads();

  for (int t=0; t<nsteps; ++t){
    const int j0 = t*64;
    if (t+1 < nsteps) stage((t+1)*64, (t+1)&1);

    if (j0 <= r0w + 31){
      const unsigned short* Kc = &Ks[t&1][0];
      const unsigned short* Vc = &Vs[t&1][0];

      // ---- S = Q.K^T : 32x64 per wave ----
      f32x4 sv[2][4];
#pragma unroll
      for (int mi=0;mi<2;mi++)
#pragma unroll
        for (int js=0;js<4;js++)
#pragma unroll
          for (int r=0;r<4;r++) sv[mi][js][r] = 0.f;

#pragma unroll
      for (int js=0;js<4;js++){
        s16x8 kf[4];
#pragma unroll
        for (int kc=0;kc<4;kc++)
          kf[kc] = *(const s16x8*)&Kc[(js*16 + c)*128 + (((kc*4+g)^(c&7))<<3)];
#pragma unroll
        for (int mi=0;mi<2;mi++)
#pragma unroll
          for (int kc=0;kc<4;kc++)
            sv[mi][js] = __builtin_amdgcn_mfma_f32_16x16x32_bf16(qf[mi][kc], kf[kc], sv[mi][js], 0,0,0);
      }

      const bool diag = (j0 + 63 > r0w);
      // ---- online softmax over 64 cols ----
#pragma unroll
      for (int mi=0;mi<2;mi++){
#pragma unroll
        for (int r=0;r<4;r++){
          const int row = r0w + mi*16 + g*4 + r;
          float v0 = sv[mi][0][r]*scale, v1 = sv[mi][1][r]*scale;
          float v2 = sv[mi][2][r]*scale, v3 = sv[mi][3][r]*scale;
          if (diag){
            if (j0 +      c > row) v0 = -INFINITY;
            if (j0 + 16 + c > row) v1 = -INFINITY;
            if (j0 + 32 + c > row) v2 = -INFINITY;
            if (j0 + 48 + c > row) v3 = -INFINITY;
          }
          float mx = fmaxf(fmaxf(v0,v1), fmaxf(v2,v3));
          mx = fmaxf(mx, __shfl_xor(mx, 1));
          mx = fmaxf(mx, __shfl_xor(mx, 2));
          mx = fmaxf(mx, __shfl_xor(mx, 4));
          mx = fmaxf(mx, __shfl_xor(mx, 8));
          float mnew = fmaxf(m_r[mi][r], mx);
          float corr = __expf(m_r[mi][r] - mnew);
          float e0 = __expf(v0 - mnew), e1 = __expf(v1 - mnew);
          float e2 = __expf(v2 - mnew), e3 = __expf(v3 - mnew);
          float rs = (e0+e1)+(e2+e3);
          rs += __shfl_xor(rs, 1);
          rs += __shfl_xor(rs, 2);
          rs += __shfl_xor(rs, 4);
          rs += __shfl_xor(rs, 8);
          l_r[mi][r] = l_r[mi][r]*corr + rs;
          m_r[mi][r] = mnew;
#pragma unroll
          for (int d=0; d<8; d++) acc[mi][d][r] *= corr;
          // P -> per-wave LDS, swizzled (elem ^ (row&7)<<3)
          const int prow = mi*16 + g*4 + r;
          const int sw = (prow&7)<<3;
          Pw[(prow*64 +      c) ^ sw] = f2bf(e0);
          Pw[(prow*64 + 16 + c) ^ sw] = f2bf(e1);
          Pw[(prow*64 + 32 + c) ^ sw] = f2bf(e2);
          Pw[(prow*64 + 48 + c) ^ sw] = f2bf(e3);
        }
      }

      // ---- O += P (32x64) . V (64x128) ----
      s16x8 pfr[2][2];
#pragma unroll
      for (int mi=0;mi<2;mi++)
#pragma unroll
        for (int k2=0;k2<2;k2++)
          pfr[mi][k2] = *(const s16x8*)&Pw[(mi*16 + c)*64 + (((k2*4+g)^(c&7))<<3)];
#pragma unroll
      for (int d=0; d<8; d++){
#pragma unroll
        for (int k2=0;k2<2;k2++){
          s16x8 vfr = *(const s16x8*)&Vc[(d*16 + c)*64 + (((k2*4+g)^(c&7))<<3)];
#pragma unroll
          for (int mi=0;mi<2;mi++)
            acc[mi][d] = __builtin_amdgcn_mfma_f32_16x16x32_bf16(pfr[mi][k2], vfr, acc[mi][d], 0,0,0);
        }
      }
    }
    __syncthreads();
  }

  // ---- epilogue ----
#pragma unroll
  for (int mi=0;mi<2;mi++)
#pragma unroll
    for (int d=0; d<8; d++)
#pragma unroll
      for (int r=0;r<4;r++){
        int row = r0w + mi*16 + g*4 + r;
        float o = acc[mi][d][r] / l_r[mi][r];
        Ar[((size_t)(b*Sq + row))*Dq + h*DHq + d*16 + c] = f2bf(o);
      }
}

// ---------------- row RMS-norm over D=2048, in place -----------------------
__global__ __launch_bounds__(256) void k_rmsnorm(unsigned short* __restrict__ A,
                                                 const float* __restrict__ w){
  const int row = blockIdx.x;
  const int tid = threadIdx.x;
  s16x8 v = *(const s16x8*)&A[(size_t)row*Dq + tid*8];
  float f[8]; float ss = 0.f;
#pragma unroll
  for (int i=0;i<8;i++){ f[i] = bf2f((unsigned short)v[i]); ss += f[i]*f[i]; }
#pragma unroll
  for (int m=1;m<64;m<<=1) ss += __shfl_xor(ss, m);
  __shared__ float red[4];
  if ((tid&63)==0) red[tid>>6] = ss;
  __syncthreads();
  ss = red[0]+red[1]+red[2]+red[3];
  float sc = rsqrtf(ss/2048.f + 1e-6f);
  unsigned short o[8];
#pragma unroll
  for (int i=0;i<8;i++) o[i] = f2bf(f[i]*sc*w[tid*8+i]);
  *(s16x8*)&A[(size_t)row*Dq + tid*8] = *(const s16x8*)o;
}

extern "C" void kernel_launch(void* const* d_in, const int* in_sizes, int n_in,
                              void* d_out, int out_size, void* d_ws, size_t ws_size,
                              hipStream_t stream){
  const float* x     = (const float*)d_in[0];
  const float* rp    = (const float*)d_in[1];
  const float* Win   = (const float*)d_in[2];
  const float* b_in  = (const float*)d_in[3];
  const float* Wout  = (const float*)d_in[4];
  const float* b_out = (const float*)d_in[5];
  const float* qk_w  = (const float*)d_in[6];
  const float* out_w = (const float*)d_in[7];
  float* outp = (float*)d_out;

  if (ws_size < (160ull<<20)) return;   // need 160 MiB scratch

  char* ws = (char*)d_ws;
  unsigned short* Xb    = (unsigned short*)(ws);                 // 16 MiB
  unsigned short* Wb    = (unsigned short*)(ws + (16ull<<20));   // 24 MiB
  unsigned short* Woutb = (unsigned short*)(ws + (40ull<<20));   //  8 MiB
  unsigned short* QKVb  = (unsigned short*)(ws + (48ull<<20));   // 48 MiB
  unsigned short* Qp    = (unsigned short*)(ws + (96ull<<20));   // 16 MiB
  unsigned short* Kp    = (unsigned short*)(ws + (112ull<<20));  // 16 MiB
  unsigned short* Vt    = (unsigned short*)(ws + (128ull<<20));  // 16 MiB
  unsigned short* Ar    = (unsigned short*)(ws + (144ull<<20));  // 16 MiB

  // 1) converts
  k_convert<<<2048, 256, 0, stream>>>(x,    Xb,    (Bq*Sq*Dq)/4);
  k_convert<<<2048, 256, 0, stream>>>(Win,  Wb,    (E3q*Dq)/4);
  k_convert<<<1024, 256, 0, stream>>>(Wout, Woutb, (Dq*Dq)/4);
  // 2) QKV = X . Win^T + b_in   (M=4096, N=6144, K=2048)
  k_gemm_bt<0><<<dim3(E3q/128, (Bq*Sq)/128), 256, 0, stream>>>(Xb, Wb, b_in, QKVb,
                                                               Bq*Sq, E3q, Dq);
  // 3) RoPE + qk RMS-norm + split (V transposed)
  k_rope_split<<<dim3(Sq/4, Hq, Bq), dim3(64,4), 0, stream>>>(QKVb, rp, qk_w, Qp, Kp, Vt);
  // 4) causal flash attention
  k_attn<<<dim3(Sq/128, Bq*Hq), 256, 0, stream>>>(Qp, Kp, Vt, Ar);
  // 5) out RMS-norm (in place on Ar)
  k_rmsnorm<<<Bq*Sq, 256, 0, stream>>>(Ar, out_w);
  // 6) Out = A . Wout^T + b_out  (M=4096, N=2048, K=2048), fp32 out
  k_gemm_bt<1><<<dim3(Dq/128, (Bq*Sq)/128), 256, 0, stream>>>(Ar, Woutb, b_out, outp,
                                                              Bq*Sq, Dq, Dq);
}

// Round 3
// 376.673 us; speedup vs baseline: 2.0057x; 1.1451x over previous
//
#include <hip/hip_runtime.h>
#include <cstdint>
#include <cstddef>

// Problem constants (B,S,D,H) = (2,2048,2048,16), DH=128
#define Bq  2
#define Sq  2048
#define Dq  2048
#define Hq  16
#define DHq 128
#define E3q 6144   // 3*D

typedef __attribute__((ext_vector_type(8))) short s16x8;   // 8 bf16 (4 VGPRs)
typedef __attribute__((ext_vector_type(4))) float f32x4;   // MFMA accumulator

__device__ __forceinline__ unsigned short f2bf(float f){
  union { float f; unsigned u; } v; v.f = f;
  unsigned r = v.u + 0x7FFFu + ((v.u >> 16) & 1u);   // round-to-nearest-even
  return (unsigned short)(r >> 16);
}
__device__ __forceinline__ float bf2f(unsigned short b){
  union { unsigned u; float f; } v; v.u = ((unsigned)b) << 16;
  return v.f;
}

// async global->LDS, 16B per lane. LDS dest must be wave-uniform base + lane*16.
__device__ __forceinline__ void gload_lds16(const void* g, void* l){
  __builtin_amdgcn_global_load_lds(
      (const __attribute__((address_space(1))) void*)g,
      (__attribute__((address_space(3))) void*)l, 16, 0, 0);
}

// ---------------- fp32 -> bf16 convert (vectorized x4) ----------------
__global__ __launch_bounds__(256) void k_convert(const float* __restrict__ in,
                                                 unsigned short* __restrict__ out, int n4){
  int stride = gridDim.x * blockDim.x;
  for (int i = blockIdx.x*blockDim.x + threadIdx.x; i < n4; i += stride){
    float4 v = reinterpret_cast<const float4*>(in)[i];
    ushort4 o;
    o.x = f2bf(v.x); o.y = f2bf(v.y); o.z = f2bf(v.z); o.w = f2bf(v.w);
    reinterpret_cast<ushort4*>(out)[i] = o;
  }
}

// ---------------- bf16 B^T GEMM: C[m,n] = sum_k A[m,k]*Bt[n,k] + bias[n] ----
// m97 structure: 128x128 tile, BK=32, 4 waves, global_load_lds width-16 staging.
template<int F32OUT>
__global__ __launch_bounds__(256) void k_gemm_bt(const unsigned short* __restrict__ A,
                                                 const unsigned short* __restrict__ Bt,
                                                 const float* __restrict__ bias,
                                                 void* __restrict__ C,
                                                 int M, int N, int K){
  const int tid = threadIdx.x;
  const int w = tid >> 6, lane = tid & 63, g = lane >> 4, c = lane & 15;
  const int wm = w >> 1, wn = w & 1;
  const int m0 = blockIdx.y * 128, n0 = blockIdx.x * 128;

  __shared__ __align__(16) unsigned short As[128*32];
  __shared__ __align__(16) unsigned short Bs[128*32];

  f32x4 acc[4][4];
#pragma unroll
  for (int i=0;i<4;i++)
#pragma unroll
    for (int j=0;j<4;j++)
#pragma unroll
      for (int r=0;r<4;r++) acc[i][j][r] = 0.f;

  const int ch0 = tid, ch1 = tid + 256;   // 512 chunks of 8 bf16 per 128x32 tile

  for (int kt = 0; kt < K; kt += 32){
    __syncthreads();   // prev iteration's LDS reads complete before overwrite
    gload_lds16(&A [(size_t)(m0 + (ch0>>2))*K + kt + (ch0&3)*8], &As[ch0*8]);
    gload_lds16(&A [(size_t)(m0 + (ch1>>2))*K + kt + (ch1&3)*8], &As[ch1*8]);
    gload_lds16(&Bt[(size_t)(n0 + (ch0>>2))*K + kt + (ch0&3)*8], &Bs[ch0*8]);
    gload_lds16(&Bt[(size_t)(n0 + (ch1>>2))*K + kt + (ch1&3)*8], &Bs[ch1*8]);
    __syncthreads();   // tile staged (syncthreads drains vmcnt)

    s16x8 af[4], bfr[4];
#pragma unroll
    for (int i=0;i<4;i++){
      af[i]  = *(const s16x8*)&As[(wm*64 + i*16 + c)*32 + g*8];
      bfr[i] = *(const s16x8*)&Bs[(wn*64 + i*16 + c)*32 + g*8];
    }
#pragma unroll
    for (int mi=0;mi<4;mi++)
#pragma unroll
      for (int ni=0;ni<4;ni++)
        acc[mi][ni] = __builtin_amdgcn_mfma_f32_16x16x32_bf16(af[mi], bfr[ni], acc[mi][ni], 0,0,0);
  }

#pragma unroll
  for (int mi=0;mi<4;mi++)
#pragma unroll
    for (int ni=0;ni<4;ni++)
#pragma unroll
      for (int r=0;r<4;r++){
        int row = m0 + wm*64 + mi*16 + g*4 + r;
        int col = n0 + wn*64 + ni*16 + c;
        float v = acc[mi][ni][r] + bias[col];
        if (F32OUT) ((float*)C)[(size_t)row*N + col] = v;
        else ((unsigned short*)C)[(size_t)row*N + col] = f2bf(v);
      }
}

// ---------------- RoPE + qk RMS-norm for Q,K only --------------------------
// Q additionally pre-scaled by 1/sqrt(DH) * log2(e) so attention scores come
// out of QK^T already in log2 units (softmax uses exp2, no per-score muls).
__global__ __launch_bounds__(256) void k_rope_qk(const unsigned short* __restrict__ QKV,
                                                 const float* __restrict__ rp,
                                                 const float* __restrict__ qk_w,
                                                 unsigned short* __restrict__ Qp,
                                                 unsigned short* __restrict__ Kp){
  const int p = threadIdx.x;
  const int s = blockIdx.x*4 + threadIdx.y;
  const int h = blockIdx.y;
  const int b = blockIdx.z;
  const size_t n = (size_t)b*Sq + s;
  const int bh = b*Hq + h;

  float ang = rp[s*64 + p];
  float sn, cs; sincosf(ang, &sn, &cs);
  float w0 = qk_w[2*p], w1 = qk_w[2*p+1];
  const float QSCALE = 0.08838834764831845f * 1.4426950408889634f; // 1/sqrt(128)*log2e

  {
    unsigned q01 = *(const unsigned*)&QKV[n*E3q + h*DHq + 2*p];
    float x0 = bf2f((unsigned short)(q01 & 0xFFFFu));
    float x1 = bf2f((unsigned short)(q01 >> 16));
    float r0 = x0*cs - x1*sn, r1 = x0*sn + x1*cs;
    float ss = r0*r0 + r1*r1;
#pragma unroll
    for (int m=1;m<64;m<<=1) ss += __shfl_xor(ss, m);
    float sc = rsqrtf(ss/128.f + 1e-6f) * QSCALE;
    unsigned short o0 = f2bf(r0*sc*w0), o1 = f2bf(r1*sc*w1);
    *(unsigned*)&Qp[((size_t)bh*Sq + s)*DHq + 2*p] = (unsigned)o0 | ((unsigned)o1<<16);
  }
  {
    unsigned k01 = *(const unsigned*)&QKV[n*E3q + Dq + h*DHq + 2*p];
    float x0 = bf2f((unsigned short)(k01 & 0xFFFFu));
    float x1 = bf2f((unsigned short)(k01 >> 16));
    float r0 = x0*cs - x1*sn, r1 = x0*sn + x1*cs;
    float ss = r0*r0 + r1*r1;
#pragma unroll
    for (int m=1;m<64;m<<=1) ss += __shfl_xor(ss, m);
    float sc = rsqrtf(ss/128.f + 1e-6f);
    unsigned short o0 = f2bf(r0*sc*w0), o1 = f2bf(r1*sc*w1);
    *(unsigned*)&Kp[((size_t)bh*Sq + s)*DHq + 2*p] = (unsigned)o0 | ((unsigned)o1<<16);
  }
}

// ---------------- V transpose via LDS: QKV[s][v-part] -> Vt[bh][dh][s] ------
// Coalesced 16B reads, padded-LDS transpose, coalesced 128B-chunk writes.
__global__ __launch_bounds__(256) void k_transpose_v(const unsigned short* __restrict__ QKV,
                                                     unsigned short* __restrict__ Vt){
  const int sblk = blockIdx.x;          // 16 blocks of 128 s
  const int bh = blockIdx.y;            // 32
  const int b = bh >> 4, h = bh & 15;
  const int tid = threadIdx.x;
  __shared__ unsigned short T[128][136];  // +8 pad keeps 16B align, breaks bank stride

  const size_t base = ((size_t)(b*Sq) + sblk*128) * E3q + 2*(size_t)Dq + h*DHq;
#pragma unroll
  for (int i=0;i<8;i++){
    int pk = tid + i*256;               // 2048 chunks of 8 ushort
    int row = pk >> 4, cc = (pk & 15) * 8;
    s16x8 v = *(const s16x8*)&QKV[base + (size_t)row*E3q + cc];
    *(s16x8*)&T[row][cc] = v;
  }
  __syncthreads();
  const int dh = tid >> 1, sh = (tid & 1) * 64;
  unsigned short buf[64];
#pragma unroll
  for (int s=0;s<64;s++) buf[s] = T[sh + s][dh];
  size_t obase = ((size_t)bh*DHq + dh)*Sq + sblk*128 + sh;
#pragma unroll
  for (int i=0;i<8;i++)
    *(s16x8*)&Vt[obase + i*8] = *(const s16x8*)&buf[i*8];
}

// ---------------- causal MFMA flash attention ------------------------------
// Q-block 128 (4 waves x 32 rows), KV-step 64, double-buffered LDS staging.
// Scores arrive in log2 units (Q pre-scaled); exp2 softmax with defer-max.
// Grid: 512 blocks, pair-balanced so block L and L+256 (same CU at 2/CU)
// carry complementary causal workloads (sum of steps constant).
__global__ __launch_bounds__(256, 2) void k_attn(const unsigned short* __restrict__ Qp,
                                                 const unsigned short* __restrict__ Kp,
                                                 const unsigned short* __restrict__ Vt,
                                                 unsigned short* __restrict__ Ar){
  const int L = blockIdx.x;
  int bh, qtile;
  if (L < 256){ bh = L >> 3; qtile = 8 + (L & 7); }
  else { int Ml = L - 256; bh = Ml >> 3; qtile = 7 - (Ml & 7); }
  const int b = bh >> 4, h = bh & 15;
  const int tid = threadIdx.x;
  const int w = tid >> 6, lane = tid & 63, g = lane >> 4, c = lane & 15;
  const int r0w = qtile*128 + w*32;

  const unsigned short* Qh = Qp + (size_t)bh * Sq * DHq;
  const unsigned short* Kh = Kp + (size_t)bh * Sq * DHq;
  const unsigned short* Vh = Vt + (size_t)bh * DHq * Sq;

  __shared__ __align__(16) unsigned short Ks[2][64*128];   // 32 KB
  __shared__ __align__(16) unsigned short Vs[2][128*64];   // 32 KB
  __shared__ __align__(16) unsigned short Pl[4][32*64];    // 16 KB
  unsigned short* Pw = &Pl[w][0];

  s16x8 qf[2][4];
#pragma unroll
  for (int mi=0;mi<2;mi++)
#pragma unroll
    for (int kc=0;kc<4;kc++)
      qf[mi][kc] = *(const s16x8*)&Qh[(size_t)(r0w + mi*16 + c)*DHq + kc*32 + g*8];

  f32x4 acc[2][8];
#pragma unroll
  for (int mi=0;mi<2;mi++)
#pragma unroll
    for (int d=0;d<8;d++)
#pragma unroll
      for (int r=0;r<4;r++) acc[mi][d][r] = 0.f;
  float m_r[2][4], l_r[2][4];
#pragma unroll
  for (int mi=0;mi<2;mi++)
#pragma unroll
    for (int r=0;r<4;r++){ m_r[mi][r] = -INFINITY; l_r[mi][r] = 0.f; }

  const int nsteps = 2*qtile + 2;

  auto stage = [&](int j0s, int bufi){
#pragma unroll
    for (int i=0;i<4;i++){
      int pk = tid + i*256;              // K: 1024 chunks of 16B
      int row = pk>>4, pc = pk&15;
      gload_lds16(&Kh[(size_t)(j0s+row)*DHq + ((pc^(row&7))<<3)], &Ks[bufi][pk*8]);
    }
#pragma unroll
    for (int i=0;i<4;i++){
      int pk = tid + i*256;              // V: 1024 chunks of 16B
      int row = pk>>3, pc = pk&7;
      gload_lds16(&Vh[(size_t)row*Sq + j0s + ((pc^(row&7))<<3)], &Vs[bufi][pk*8]);
    }
  };

  stage(0, 0);
  __syncthreads();

  for (int t=0; t<nsteps; ++t){
    const int j0 = t*64;
    if (t+1 < nsteps) stage((t+1)*64, (t+1)&1);

    if (j0 <= r0w + 31){
      const unsigned short* Kc = &Ks[t&1][0];
      const unsigned short* Vc = &Vs[t&1][0];

      // ---- S = Q.K^T : 32x64 per wave (log2 units) ----
      f32x4 sv[2][4];
#pragma unroll
      for (int mi=0;mi<2;mi++)
#pragma unroll
        for (int js=0;js<4;js++)
#pragma unroll
          for (int r=0;r<4;r++) sv[mi][js][r] = 0.f;

#pragma unroll
      for (int js=0;js<4;js++){
        s16x8 kf[4];
#pragma unroll
        for (int kc=0;kc<4;kc++)
          kf[kc] = *(const s16x8*)&Kc[(js*16 + c)*128 + (((kc*4+g)^(c&7))<<3)];
#pragma unroll
        for (int mi=0;mi<2;mi++)
#pragma unroll
          for (int kc=0;kc<4;kc++)
            sv[mi][js] = __builtin_amdgcn_mfma_f32_16x16x32_bf16(qf[mi][kc], kf[kc], sv[mi][js], 0,0,0);
      }

      const bool diag = (j0 + 63 > r0w);
      // ---- defer-max online softmax (log2 domain) ----
      float pm[2][4];
      int need = 0;
#pragma unroll
      for (int mi=0;mi<2;mi++){
#pragma unroll
        for (int r=0;r<4;r++){
          const int row = r0w + mi*16 + g*4 + r;
          float v0 = sv[mi][0][r], v1 = sv[mi][1][r];
          float v2 = sv[mi][2][r], v3 = sv[mi][3][r];
          if (diag){
            if (j0 +      c > row) v0 = -INFINITY;
            if (j0 + 16 + c > row) v1 = -INFINITY;
            if (j0 + 32 + c > row) v2 = -INFINITY;
            if (j0 + 48 + c > row) v3 = -INFINITY;
            sv[mi][0][r]=v0; sv[mi][1][r]=v1; sv[mi][2][r]=v2; sv[mi][3][r]=v3;
          }
          float mx = fmaxf(fmaxf(v0,v1), fmaxf(v2,v3));
          mx = fmaxf(mx, __shfl_xor(mx, 1));
          mx = fmaxf(mx, __shfl_xor(mx, 2));
          mx = fmaxf(mx, __shfl_xor(mx, 4));
          mx = fmaxf(mx, __shfl_xor(mx, 8));
          pm[mi][r] = mx;
          need |= (mx > m_r[mi][r] + 8.f) ? 1 : 0;
        }
      }
      if (__any(need)){
#pragma unroll
        for (int mi=0;mi<2;mi++)
#pragma unroll
          for (int r=0;r<4;r++){
            float mnew = fmaxf(m_r[mi][r], pm[mi][r]);
            float corr = exp2f(m_r[mi][r] - mnew);
            l_r[mi][r] *= corr;
            m_r[mi][r] = mnew;
#pragma unroll
            for (int d=0;d<8;d++) acc[mi][d][r] *= corr;
          }
      }
#pragma unroll
      for (int mi=0;mi<2;mi++){
#pragma unroll
        for (int r=0;r<4;r++){
          float mm = m_r[mi][r];
          float e0 = exp2f(sv[mi][0][r] - mm);
          float e1 = exp2f(sv[mi][1][r] - mm);
          float e2 = exp2f(sv[mi][2][r] - mm);
          float e3 = exp2f(sv[mi][3][r] - mm);
          float rs = (e0+e1)+(e2+e3);
          rs += __shfl_xor(rs, 1);
          rs += __shfl_xor(rs, 2);
          rs += __shfl_xor(rs, 4);
          rs += __shfl_xor(rs, 8);
          l_r[mi][r] += rs;
          const int prow = mi*16 + g*4 + r;
          const int sw = (prow&7)<<3;
          Pw[(prow*64 +      c) ^ sw] = f2bf(e0);
          Pw[(prow*64 + 16 + c) ^ sw] = f2bf(e1);
          Pw[(prow*64 + 32 + c) ^ sw] = f2bf(e2);
          Pw[(prow*64 + 48 + c) ^ sw] = f2bf(e3);
        }
      }

      // ---- O += P (32x64) . V (64x128) ----
      s16x8 pfr[2][2];
#pragma unroll
      for (int mi=0;mi<2;mi++)
#pragma unroll
        for (int k2=0;k2<2;k2++)
          pfr[mi][k2] = *(const s16x8*)&Pw[(mi*16 + c)*64 + (((k2*4+g)^(c&7))<<3)];
#pragma unroll
      for (int d=0; d<8; d++){
#pragma unroll
        for (int k2=0;k2<2;k2++){
          s16x8 vfr = *(const s16x8*)&Vc[(d*16 + c)*64 + (((k2*4+g)^(c&7))<<3)];
#pragma unroll
          for (int mi=0;mi<2;mi++)
            acc[mi][d] = __builtin_amdgcn_mfma_f32_16x16x32_bf16(pfr[mi][k2], vfr, acc[mi][d], 0,0,0);
        }
      }
    }
    __syncthreads();
  }

  // ---- epilogue ----
#pragma unroll
  for (int mi=0;mi<2;mi++)
#pragma unroll
    for (int r=0;r<4;r++){
      float inv = 1.f / l_r[mi][r];
      int row = r0w + mi*16 + g*4 + r;
#pragma unroll
      for (int d=0; d<8; d++)
        Ar[((size_t)(b*Sq + row))*Dq + h*DHq + d*16 + c] = f2bf(acc[mi][d][r] * inv);
    }
}

// ---------------- row RMS-norm over D=2048, in place -----------------------
__global__ __launch_bounds__(256) void k_rmsnorm(unsigned short* __restrict__ A,
                                                 const float* __restrict__ w){
  const int row = blockIdx.x;
  const int tid = threadIdx.x;
  s16x8 v = *(const s16x8*)&A[(size_t)row*Dq + tid*8];
  float f[8]; float ss = 0.f;
#pragma unroll
  for (int i=0;i<8;i++){ f[i] = bf2f((unsigned short)v[i]); ss += f[i]*f[i]; }
#pragma unroll
  for (int m=1;m<64;m<<=1) ss += __shfl_xor(ss, m);
  __shared__ float red[4];
  if ((tid&63)==0) red[tid>>6] = ss;
  __syncthreads();
  ss = red[0]+red[1]+red[2]+red[3];
  float sc = rsqrtf(ss/2048.f + 1e-6f);
  unsigned short o[8];
#pragma unroll
  for (int i=0;i<8;i++) o[i] = f2bf(f[i]*sc*w[tid*8+i]);
  *(s16x8*)&A[(size_t)row*Dq + tid*8] = *(const s16x8*)o;
}

extern "C" void kernel_launch(void* const* d_in, const int* in_sizes, int n_in,
                              void* d_out, int out_size, void* d_ws, size_t ws_size,
                              hipStream_t stream){
  const float* x     = (const float*)d_in[0];
  const float* rp    = (const float*)d_in[1];
  const float* Win   = (const float*)d_in[2];
  const float* b_in  = (const float*)d_in[3];
  const float* Wout  = (const float*)d_in[4];
  const float* b_out = (const float*)d_in[5];
  const float* qk_w  = (const float*)d_in[6];
  const float* out_w = (const float*)d_in[7];
  float* outp = (float*)d_out;

  if (ws_size < (160ull<<20)) return;   // need 160 MiB scratch

  char* ws = (char*)d_ws;
  unsigned short* Xb    = (unsigned short*)(ws);                 // 16 MiB
  unsigned short* Wb    = (unsigned short*)(ws + (16ull<<20));   // 24 MiB
  unsigned short* Woutb = (unsigned short*)(ws + (40ull<<20));   //  8 MiB
  unsigned short* QKVb  = (unsigned short*)(ws + (48ull<<20));   // 48 MiB
  unsigned short* Qp    = (unsigned short*)(ws + (96ull<<20));   // 16 MiB
  unsigned short* Kp    = (unsigned short*)(ws + (112ull<<20));  // 16 MiB
  unsigned short* Vt    = (unsigned short*)(ws + (128ull<<20));  // 16 MiB
  unsigned short* Ar    = (unsigned short*)(ws + (144ull<<20));  // 16 MiB

  // 1) converts
  k_convert<<<2048, 256, 0, stream>>>(x,    Xb,    (Bq*Sq*Dq)/4);
  k_convert<<<2048, 256, 0, stream>>>(Win,  Wb,    (E3q*Dq)/4);
  k_convert<<<1024, 256, 0, stream>>>(Wout, Woutb, (Dq*Dq)/4);
  // 2) QKV = X . Win^T + b_in   (M=4096, N=6144, K=2048)
  k_gemm_bt<0><<<dim3(E3q/128, (Bq*Sq)/128), 256, 0, stream>>>(Xb, Wb, b_in, QKVb,
                                                               Bq*Sq, E3q, Dq);
  // 3) RoPE + qk RMS-norm (Q pre-scaled to log2 units) ; V transpose
  k_rope_qk<<<dim3(Sq/4, Hq, Bq), dim3(64,4), 0, stream>>>(QKVb, rp, qk_w, Qp, Kp);
  k_transpose_v<<<dim3(Sq/128, Bq*Hq), 256, 0, stream>>>(QKVb, Vt);
  // 4) causal flash attention (pair-balanced 1D grid)
  k_attn<<<512, 256, 0, stream>>>(Qp, Kp, Vt, Ar);
  // 5) out RMS-norm (in place on Ar)
  k_rmsnorm<<<Bq*Sq, 256, 0, stream>>>(Ar, out_w);
  // 6) Out = A . Wout^T + b_out  (M=4096, N=2048, K=2048), fp32 out
  k_gemm_bt<1><<<dim3(Dq/128, (Bq*Sq)/128), 256, 0, stream>>>(Ar, Woutb, b_out, outp,
                                                              Bq*Sq, Dq, Dq);
}

// Round 4
// 349.908 us; speedup vs baseline: 2.1591x; 1.0765x over previous
//
#include <hip/hip_runtime.h>
#include <cstdint>
#include <cstddef>

// Problem constants (B,S,D,H) = (2,2048,2048,16), DH=128
#define Bq  2
#define Sq  2048
#define Dq  2048
#define Hq  16
#define DHq 128
#define E3q 6144   // 3*D

typedef __attribute__((ext_vector_type(8))) short s16x8;   // 8 bf16 (4 VGPRs)
typedef __attribute__((ext_vector_type(4))) float f32x4;   // MFMA accumulator

__device__ __forceinline__ unsigned short f2bf(float f){
  union { float f; unsigned u; } v; v.f = f;
  unsigned r = v.u + 0x7FFFu + ((v.u >> 16) & 1u);   // round-to-nearest-even
  return (unsigned short)(r >> 16);
}
__device__ __forceinline__ float bf2f(unsigned short b){
  union { unsigned u; float f; } v; v.u = ((unsigned)b) << 16;
  return v.f;
}

// async global->LDS, 16B per lane. LDS dest must be wave-uniform base + lane*16.
__device__ __forceinline__ void gload_lds16(const void* g, void* l){
  __builtin_amdgcn_global_load_lds(
      (const __attribute__((address_space(1))) void*)g,
      (__attribute__((address_space(3))) void*)l, 16, 0, 0);
}

// ---------------- fp32 -> bf16 convert (vectorized x4) ----------------
__global__ __launch_bounds__(256) void k_convert(const float* __restrict__ in,
                                                 unsigned short* __restrict__ out, int n4){
  int stride = gridDim.x * blockDim.x;
  for (int i = blockIdx.x*blockDim.x + threadIdx.x; i < n4; i += stride){
    float4 v = reinterpret_cast<const float4*>(in)[i];
    ushort4 o;
    o.x = f2bf(v.x); o.y = f2bf(v.y); o.z = f2bf(v.z); o.w = f2bf(v.w);
    reinterpret_cast<ushort4*>(out)[i] = o;
  }
}

// ---------------- bf16 B^T GEMM, counted-vmcnt deep pipeline ----------------
// C[m,n] = sum_k A[m,k]*Bt[n,k] + bias[n].
// BM=128, BN=256, BK=32, 512 threads (8 waves 2x4), per-wave 64x64 (4x4 frags).
// LDS: ring-4 of K-tiles (A 128x32 + B 256x32 = 24KB/tile, 96KB total).
// Pipeline: prefetch distance 3; per iter: vmcnt(6) [never 0 in steady state],
// raw s_barrier (no drain), issue tile t+3 into slot of tile t-1 (reads of
// t-1 finished before this barrier => race-free), ds_read + MFMA.
// T2 swizzle: LDS dest linear, global source chunk pc^((row>>1)&3), read with
// the same involution => rows 0..7 hit 8 distinct 16B slots (2-way, free).
template<int F32OUT>
__global__ __launch_bounds__(512, 1) void k_gemm_bt(const unsigned short* __restrict__ A,
                                                    const unsigned short* __restrict__ Bt,
                                                    const float* __restrict__ bias,
                                                    void* __restrict__ C,
                                                    int M, int N, int K, int gx){
  // flat grid, bijective XCD chunking (nwg % 8 == 0 for our sizes)
  const int nwg = gridDim.x;
  const int cpx = nwg >> 3;
  const int bid = blockIdx.x;
  const int swz = (bid & 7) * cpx + (bid >> 3);
  const int by = swz / gx, bx = swz - by*gx;
  const int m0 = by * 128, n0 = bx * 256;

  const int tid = threadIdx.x;
  const int w = tid >> 6, lane = tid & 63, g = lane >> 4, c = lane & 15;
  const int wm = w >> 2, wn = w & 3;       // 2 x 4 waves

  // ring-4 LDS: per slot A[128][32] at 0, B[256][32] at 4096 (elements)
  __shared__ __align__(16) unsigned short L[4 * 12288];

  const int NT = K >> 5;                   // 64 K-tiles

  // staging: 3 x gload_lds16 per thread per tile (A:1, B:2)
  const int arow = tid >> 2, apc = tid & 3;
  const int brow0 = tid >> 2, bpc0 = tid & 3;            // B chunk p = tid
  const int brow1 = (tid + 512) >> 2, bpc1 = tid & 3;    // B chunk p = tid+512
  const unsigned short* Abase = &A [(size_t)(m0 + arow )*K + (size_t)((apc ^ ((arow >>1)&3))*8)];
  const unsigned short* Bbase0 = &Bt[(size_t)(n0 + brow0)*K + (size_t)((bpc0 ^ ((brow0>>1)&3))*8)];
  const unsigned short* Bbase1 = &Bt[(size_t)(n0 + brow1)*K + (size_t)((bpc1 ^ ((brow1>>1)&3))*8)];

  auto stage = [&](int tile, int slot){
    const int kt = tile << 5;
    unsigned short* Ls = &L[slot * 12288];
    gload_lds16(Abase  + kt, &Ls[tid*8]);
    gload_lds16(Bbase0 + kt, &Ls[4096 + tid*8]);
    gload_lds16(Bbase1 + kt, &Ls[4096 + (tid+512)*8]);
  };

  f32x4 acc[4][4];
#pragma unroll
  for (int i=0;i<4;i++)
#pragma unroll
    for (int j=0;j<4;j++)
#pragma unroll
      for (int r=0;r<4;r++) acc[i][j][r] = 0.f;

  // precomputed swizzled LDS element offsets for fragment reads
  int aoff[4], boff[4];
#pragma unroll
  for (int mi=0;mi<4;mi++){
    int row = wm*64 + mi*16 + c;
    aoff[mi] = row*32 + ((g ^ ((row>>1)&3)) << 3);
  }
#pragma unroll
  for (int ni=0;ni<4;ni++){
    int row = wn*64 + ni*16 + c;
    boff[ni] = 4096 + row*32 + ((g ^ ((row>>1)&3)) << 3);
  }

  // prologue: fill 3 slots
  stage(0, 0); stage(1, 1); stage(2, 2);

  for (int t = 0; t < NT; ++t){
    if (t < NT-2)      { asm volatile("s_waitcnt vmcnt(6)" ::: "memory"); }
    else if (t == NT-2){ asm volatile("s_waitcnt vmcnt(3)" ::: "memory"); }
    else               { asm volatile("s_waitcnt vmcnt(0)" ::: "memory"); }
    __builtin_amdgcn_s_barrier();
    __builtin_amdgcn_sched_barrier(0);
    if (t+3 < NT) stage(t+3, (t+3)&3);

    const unsigned short* Ls = &L[(t&3) * 12288];
    s16x8 bfr[4];
#pragma unroll
    for (int ni=0;ni<4;ni++) bfr[ni] = *(const s16x8*)&Ls[boff[ni]];
    __builtin_amdgcn_s_setprio(1);
#pragma unroll
    for (int mi=0;mi<4;mi++){
      s16x8 af = *(const s16x8*)&Ls[aoff[mi]];
#pragma unroll
      for (int ni=0;ni<4;ni++)
        acc[mi][ni] = __builtin_amdgcn_mfma_f32_16x16x32_bf16(af, bfr[ni], acc[mi][ni], 0,0,0);
    }
    __builtin_amdgcn_s_setprio(0);
  }

  // epilogue
#pragma unroll
  for (int ni=0;ni<4;ni++){
    const int col = n0 + wn*64 + ni*16 + c;
    const float bv = bias[col];
#pragma unroll
    for (int mi=0;mi<4;mi++){
      const int row = m0 + wm*64 + mi*16 + g*4;
#pragma unroll
      for (int r=0;r<4;r++){
        float v = acc[mi][ni][r] + bv;
        if (F32OUT) ((float*)C)[(size_t)(row+r)*N + col] = v;
        else ((unsigned short*)C)[(size_t)(row+r)*N + col] = f2bf(v);
      }
    }
  }
}

// ---------------- RoPE + qk RMS-norm for Q,K only --------------------------
// Q additionally pre-scaled by 1/sqrt(DH) * log2(e) so attention scores come
// out of QK^T already in log2 units (softmax uses exp2, no per-score muls).
__global__ __launch_bounds__(256) void k_rope_qk(const unsigned short* __restrict__ QKV,
                                                 const float* __restrict__ rp,
                                                 const float* __restrict__ qk_w,
                                                 unsigned short* __restrict__ Qp,
                                                 unsigned short* __restrict__ Kp){
  const int p = threadIdx.x;
  const int s = blockIdx.x*4 + threadIdx.y;
  const int h = blockIdx.y;
  const int b = blockIdx.z;
  const size_t n = (size_t)b*Sq + s;
  const int bh = b*Hq + h;

  float ang = rp[s*64 + p];
  float sn, cs; sincosf(ang, &sn, &cs);
  float w0 = qk_w[2*p], w1 = qk_w[2*p+1];
  const float QSCALE = 0.08838834764831845f * 1.4426950408889634f; // 1/sqrt(128)*log2e

  {
    unsigned q01 = *(const unsigned*)&QKV[n*E3q + h*DHq + 2*p];
    float x0 = bf2f((unsigned short)(q01 & 0xFFFFu));
    float x1 = bf2f((unsigned short)(q01 >> 16));
    float r0 = x0*cs - x1*sn, r1 = x0*sn + x1*cs;
    float ss = r0*r0 + r1*r1;
#pragma unroll
    for (int m=1;m<64;m<<=1) ss += __shfl_xor(ss, m);
    float sc = rsqrtf(ss/128.f + 1e-6f) * QSCALE;
    unsigned short o0 = f2bf(r0*sc*w0), o1 = f2bf(r1*sc*w1);
    *(unsigned*)&Qp[((size_t)bh*Sq + s)*DHq + 2*p] = (unsigned)o0 | ((unsigned)o1<<16);
  }
  {
    unsigned k01 = *(const unsigned*)&QKV[n*E3q + Dq + h*DHq + 2*p];
    float x0 = bf2f((unsigned short)(k01 & 0xFFFFu));
    float x1 = bf2f((unsigned short)(k01 >> 16));
    float r0 = x0*cs - x1*sn, r1 = x0*sn + x1*cs;
    float ss = r0*r0 + r1*r1;
#pragma unroll
    for (int m=1;m<64;m<<=1) ss += __shfl_xor(ss, m);
    float sc = rsqrtf(ss/128.f + 1e-6f);
    unsigned short o0 = f2bf(r0*sc*w0), o1 = f2bf(r1*sc*w1);
    *(unsigned*)&Kp[((size_t)bh*Sq + s)*DHq + 2*p] = (unsigned)o0 | ((unsigned)o1<<16);
  }
}

// ---------------- V transpose via LDS: QKV[s][v-part] -> Vt[bh][dh][s] ------
__global__ __launch_bounds__(256) void k_transpose_v(const unsigned short* __restrict__ QKV,
                                                     unsigned short* __restrict__ Vt){
  const int sblk = blockIdx.x;          // 16 blocks of 128 s
  const int bh = blockIdx.y;            // 32
  const int b = bh >> 4, h = bh & 15;
  const int tid = threadIdx.x;
  __shared__ unsigned short T[128][136];  // +8 pad keeps 16B align, breaks bank stride

  const size_t base = ((size_t)(b*Sq) + sblk*128) * E3q + 2*(size_t)Dq + h*DHq;
#pragma unroll
  for (int i=0;i<8;i++){
    int pk = tid + i*256;               // 2048 chunks of 8 ushort
    int row = pk >> 4, cc = (pk & 15) * 8;
    s16x8 v = *(const s16x8*)&QKV[base + (size_t)row*E3q + cc];
    *(s16x8*)&T[row][cc] = v;
  }
  __syncthreads();
  const int dh = tid >> 1, sh = (tid & 1) * 64;
  unsigned short buf[64];
#pragma unroll
  for (int s=0;s<64;s++) buf[s] = T[sh + s][dh];
  size_t obase = ((size_t)bh*DHq + dh)*Sq + sblk*128 + sh;
#pragma unroll
  for (int i=0;i<8;i++)
    *(s16x8*)&Vt[obase + i*8] = *(const s16x8*)&buf[i*8];
}

// ---------------- causal MFMA flash attention ------------------------------
// Q-block 128 (4 waves x 32 rows), KV-step 64, double-buffered LDS staging.
// Scores arrive in log2 units (Q pre-scaled); exp2 softmax with defer-max.
__global__ __launch_bounds__(256, 2) void k_attn(const unsigned short* __restrict__ Qp,
                                                 const unsigned short* __restrict__ Kp,
                                                 const unsigned short* __restrict__ Vt,
                                                 unsigned short* __restrict__ Ar){
  const int L = blockIdx.x;
  int bh, qtile;
  if (L < 256){ bh = L >> 3; qtile = 8 + (L & 7); }
  else { int Ml = L - 256; bh = Ml >> 3; qtile = 7 - (Ml & 7); }
  const int b = bh >> 4, h = bh & 15;
  const int tid = threadIdx.x;
  const int w = tid >> 6, lane = tid & 63, g = lane >> 4, c = lane & 15;
  const int r0w = qtile*128 + w*32;

  const unsigned short* Qh = Qp + (size_t)bh * Sq * DHq;
  const unsigned short* Kh = Kp + (size_t)bh * Sq * DHq;
  const unsigned short* Vh = Vt + (size_t)bh * DHq * Sq;

  __shared__ __align__(16) unsigned short Ks[2][64*128];   // 32 KB
  __shared__ __align__(16) unsigned short Vs[2][128*64];   // 32 KB
  __shared__ __align__(16) unsigned short Pl[4][32*64];    // 16 KB
  unsigned short* Pw = &Pl[w][0];

  s16x8 qf[2][4];
#pragma unroll
  for (int mi=0;mi<2;mi++)
#pragma unroll
    for (int kc=0;kc<4;kc++)
      qf[mi][kc] = *(const s16x8*)&Qh[(size_t)(r0w + mi*16 + c)*DHq + kc*32 + g*8];

  f32x4 acc[2][8];
#pragma unroll
  for (int mi=0;mi<2;mi++)
#pragma unroll
    for (int d=0;d<8;d++)
#pragma unroll
      for (int r=0;r<4;r++) acc[mi][d][r] = 0.f;
  float m_r[2][4], l_r[2][4];
#pragma unroll
  for (int mi=0;mi<2;mi++)
#pragma unroll
    for (int r=0;r<4;r++){ m_r[mi][r] = -INFINITY; l_r[mi][r] = 0.f; }

  const int nsteps = 2*qtile + 2;

  auto stage = [&](int j0s, int bufi){
#pragma unroll
    for (int i=0;i<4;i++){
      int pk = tid + i*256;              // K: 1024 chunks of 16B
      int row = pk>>4, pc = pk&15;
      gload_lds16(&Kh[(size_t)(j0s+row)*DHq + ((pc^(row&7))<<3)], &Ks[bufi][pk*8]);
    }
#pragma unroll
    for (int i=0;i<4;i++){
      int pk = tid + i*256;              // V: 1024 chunks of 16B
      int row = pk>>3, pc = pk&7;
      gload_lds16(&Vh[(size_t)row*Sq + j0s + ((pc^(row&7))<<3)], &Vs[bufi][pk*8]);
    }
  };

  stage(0, 0);
  __syncthreads();

  for (int t=0; t<nsteps; ++t){
    const int j0 = t*64;
    if (t+1 < nsteps) stage((t+1)*64, (t+1)&1);

    if (j0 <= r0w + 31){
      const unsigned short* Kc = &Ks[t&1][0];
      const unsigned short* Vc = &Vs[t&1][0];

      // ---- S = Q.K^T : 32x64 per wave (log2 units) ----
      f32x4 sv[2][4];
#pragma unroll
      for (int mi=0;mi<2;mi++)
#pragma unroll
        for (int js=0;js<4;js++)
#pragma unroll
          for (int r=0;r<4;r++) sv[mi][js][r] = 0.f;

#pragma unroll
      for (int js=0;js<4;js++){
        s16x8 kf[4];
#pragma unroll
        for (int kc=0;kc<4;kc++)
          kf[kc] = *(const s16x8*)&Kc[(js*16 + c)*128 + (((kc*4+g)^(c&7))<<3)];
#pragma unroll
        for (int mi=0;mi<2;mi++)
#pragma unroll
          for (int kc=0;kc<4;kc++)
            sv[mi][js] = __builtin_amdgcn_mfma_f32_16x16x32_bf16(qf[mi][kc], kf[kc], sv[mi][js], 0,0,0);
      }

      const bool diag = (j0 + 63 > r0w);
      // ---- defer-max online softmax (log2 domain) ----
      float pm[2][4];
      int need = 0;
#pragma unroll
      for (int mi=0;mi<2;mi++){
#pragma unroll
        for (int r=0;r<4;r++){
          const int row = r0w + mi*16 + g*4 + r;
          float v0 = sv[mi][0][r], v1 = sv[mi][1][r];
          float v2 = sv[mi][2][r], v3 = sv[mi][3][r];
          if (diag){
            if (j0 +      c > row) v0 = -INFINITY;
            if (j0 + 16 + c > row) v1 = -INFINITY;
            if (j0 + 32 + c > row) v2 = -INFINITY;
            if (j0 + 48 + c > row) v3 = -INFINITY;
            sv[mi][0][r]=v0; sv[mi][1][r]=v1; sv[mi][2][r]=v2; sv[mi][3][r]=v3;
          }
          float mx = fmaxf(fmaxf(v0,v1), fmaxf(v2,v3));
          mx = fmaxf(mx, __shfl_xor(mx, 1));
          mx = fmaxf(mx, __shfl_xor(mx, 2));
          mx = fmaxf(mx, __shfl_xor(mx, 4));
          mx = fmaxf(mx, __shfl_xor(mx, 8));
          pm[mi][r] = mx;
          need |= (mx > m_r[mi][r] + 8.f) ? 1 : 0;
        }
      }
      if (__any(need)){
#pragma unroll
        for (int mi=0;mi<2;mi++)
#pragma unroll
          for (int r=0;r<4;r++){
            float mnew = fmaxf(m_r[mi][r], pm[mi][r]);
            float corr = exp2f(m_r[mi][r] - mnew);
            l_r[mi][r] *= corr;
            m_r[mi][r] = mnew;
#pragma unroll
            for (int d=0;d<8;d++) acc[mi][d][r] *= corr;
          }
      }
#pragma unroll
      for (int mi=0;mi<2;mi++){
#pragma unroll
        for (int r=0;r<4;r++){
          float mm = m_r[mi][r];
          float e0 = exp2f(sv[mi][0][r] - mm);
          float e1 = exp2f(sv[mi][1][r] - mm);
          float e2 = exp2f(sv[mi][2][r] - mm);
          float e3 = exp2f(sv[mi][3][r] - mm);
          float rs = (e0+e1)+(e2+e3);
          rs += __shfl_xor(rs, 1);
          rs += __shfl_xor(rs, 2);
          rs += __shfl_xor(rs, 4);
          rs += __shfl_xor(rs, 8);
          l_r[mi][r] += rs;
          const int prow = mi*16 + g*4 + r;
          const int sw = (prow&7)<<3;
          Pw[(prow*64 +      c) ^ sw] = f2bf(e0);
          Pw[(prow*64 + 16 + c) ^ sw] = f2bf(e1);
          Pw[(prow*64 + 32 + c) ^ sw] = f2bf(e2);
          Pw[(prow*64 + 48 + c) ^ sw] = f2bf(e3);
        }
      }

      // ---- O += P (32x64) . V (64x128) ----
      s16x8 pfr[2][2];
#pragma unroll
      for (int mi=0;mi<2;mi++)
#pragma unroll
        for (int k2=0;k2<2;k2++)
          pfr[mi][k2] = *(const s16x8*)&Pw[(mi*16 + c)*64 + (((k2*4+g)^(c&7))<<3)];
#pragma unroll
      for (int d=0; d<8; d++){
#pragma unroll
        for (int k2=0;k2<2;k2++){
          s16x8 vfr = *(const s16x8*)&Vc[(d*16 + c)*64 + (((k2*4+g)^(c&7))<<3)];
#pragma unroll
          for (int mi=0;mi<2;mi++)
            acc[mi][d] = __builtin_amdgcn_mfma_f32_16x16x32_bf16(pfr[mi][k2], vfr, acc[mi][d], 0,0,0);
        }
      }
    }
    __syncthreads();
  }

  // ---- epilogue ----
#pragma unroll
  for (int mi=0;mi<2;mi++)
#pragma unroll
    for (int r=0;r<4;r++){
      float inv = 1.f / l_r[mi][r];
      int row = r0w + mi*16 + g*4 + r;
#pragma unroll
      for (int d=0; d<8; d++)
        Ar[((size_t)(b*Sq + row))*Dq + h*DHq + d*16 + c] = f2bf(acc[mi][d][r] * inv);
    }
}

// ---------------- row RMS-norm over D=2048, in place -----------------------
__global__ __launch_bounds__(256) void k_rmsnorm(unsigned short* __restrict__ A,
                                                 const float* __restrict__ w){
  const int row = blockIdx.x;
  const int tid = threadIdx.x;
  s16x8 v = *(const s16x8*)&A[(size_t)row*Dq + tid*8];
  float f[8]; float ss = 0.f;
#pragma unroll
  for (int i=0;i<8;i++){ f[i] = bf2f((unsigned short)v[i]); ss += f[i]*f[i]; }
#pragma unroll
  for (int m=1;m<64;m<<=1) ss += __shfl_xor(ss, m);
  __shared__ float red[4];
  if ((tid&63)==0) red[tid>>6] = ss;
  __syncthreads();
  ss = red[0]+red[1]+red[2]+red[3];
  float sc = rsqrtf(ss/2048.f + 1e-6f);
  unsigned short o[8];
#pragma unroll
  for (int i=0;i<8;i++) o[i] = f2bf(f[i]*sc*w[tid*8+i]);
  *(s16x8*)&A[(size_t)row*Dq + tid*8] = *(const s16x8*)o;
}

extern "C" void kernel_launch(void* const* d_in, const int* in_sizes, int n_in,
                              void* d_out, int out_size, void* d_ws, size_t ws_size,
                              hipStream_t stream){
  const float* x     = (const float*)d_in[0];
  const float* rp    = (const float*)d_in[1];
  const float* Win   = (const float*)d_in[2];
  const float* b_in  = (const float*)d_in[3];
  const float* Wout  = (const float*)d_in[4];
  const float* b_out = (const float*)d_in[5];
  const float* qk_w  = (const float*)d_in[6];
  const float* out_w = (const float*)d_in[7];
  float* outp = (float*)d_out;

  if (ws_size < (160ull<<20)) return;   // need 160 MiB scratch

  char* ws = (char*)d_ws;
  unsigned short* Xb    = (unsigned short*)(ws);                 // 16 MiB
  unsigned short* Wb    = (unsigned short*)(ws + (16ull<<20));   // 24 MiB
  unsigned short* Woutb = (unsigned short*)(ws + (40ull<<20));   //  8 MiB
  unsigned short* QKVb  = (unsigned short*)(ws + (48ull<<20));   // 48 MiB
  unsigned short* Qp    = (unsigned short*)(ws + (96ull<<20));   // 16 MiB
  unsigned short* Kp    = (unsigned short*)(ws + (112ull<<20));  // 16 MiB
  unsigned short* Vt    = (unsigned short*)(ws + (128ull<<20));  // 16 MiB
  unsigned short* Ar    = (unsigned short*)(ws + (144ull<<20));  // 16 MiB

  // 1) converts
  k_convert<<<2048, 256, 0, stream>>>(x,    Xb,    (Bq*Sq*Dq)/4);
  k_convert<<<2048, 256, 0, stream>>>(Win,  Wb,    (E3q*Dq)/4);
  k_convert<<<1024, 256, 0, stream>>>(Wout, Woutb, (Dq*Dq)/4);
  // 2) QKV = X . Win^T + b_in   (M=4096, N=6144, K=2048): grid 24x32 = 768
  k_gemm_bt<0><<<768, 512, 0, stream>>>(Xb, Wb, b_in, QKVb, Bq*Sq, E3q, Dq, E3q/256);
  // 3) RoPE + qk RMS-norm (Q pre-scaled to log2 units) ; V transpose
  k_rope_qk<<<dim3(Sq/4, Hq, Bq), dim3(64,4), 0, stream>>>(QKVb, rp, qk_w, Qp, Kp);
  k_transpose_v<<<dim3(Sq/128, Bq*Hq), 256, 0, stream>>>(QKVb, Vt);
  // 4) causal flash attention (pair-balanced 1D grid)
  k_attn<<<512, 256, 0, stream>>>(Qp, Kp, Vt, Ar);
  // 5) out RMS-norm (in place on Ar)
  k_rmsnorm<<<Bq*Sq, 256, 0, stream>>>(Ar, out_w);
  // 6) Out = A . Wout^T + b_out  (M=4096, N=2048, K=2048): grid 8x32 = 256
  k_gemm_bt<1><<<256, 512, 0, stream>>>(Ar, Woutb, b_out, outp, Bq*Sq, Dq, Dq, Dq/256);
}

// Round 5
// 303.189 us; speedup vs baseline: 2.4918x; 1.1541x over previous
//
#include <hip/hip_runtime.h>
#include <cstdint>
#include <cstddef>

// Problem constants (B,S,D,H) = (2,2048,2048,16), DH=128
#define Bq  2
#define Sq  2048
#define Dq  2048
#define Hq  16
#define DHq 128
#define E3q 6144   // 3*D

typedef __attribute__((ext_vector_type(8))) short s16x8;   // 8 bf16 (4 VGPRs)
typedef __attribute__((ext_vector_type(4))) float f32x4;   // MFMA accumulator

__device__ __forceinline__ unsigned short f2bf(float f){
  union { float f; unsigned u; } v; v.f = f;
  unsigned r = v.u + 0x7FFFu + ((v.u >> 16) & 1u);   // round-to-nearest-even
  return (unsigned short)(r >> 16);
}
__device__ __forceinline__ float bf2f(unsigned short b){
  union { unsigned u; float f; } v; v.u = ((unsigned)b) << 16;
  return v.f;
}
// pack two f32 -> two bf16 in one op (no builtin on gfx950; T12 recipe)
__device__ __forceinline__ unsigned cvtpk_bf16(float lo, float hi){
  unsigned r;
  asm("v_cvt_pk_bf16_f32 %0, %1, %2" : "=v"(r) : "v"(lo), "v"(hi));
  return r;
}

// async global->LDS, 16B per lane. LDS dest must be wave-uniform base + lane*16.
__device__ __forceinline__ void gload_lds16(const void* g, void* l){
  __builtin_amdgcn_global_load_lds(
      (const __attribute__((address_space(1))) void*)g,
      (__attribute__((address_space(3))) void*)l, 16, 0, 0);
}

// ---------------- fp32 -> bf16 convert (vectorized x4) ----------------
__global__ __launch_bounds__(256) void k_convert(const float* __restrict__ in,
                                                 unsigned short* __restrict__ out, int n4){
  int stride = gridDim.x * blockDim.x;
  for (int i = blockIdx.x*blockDim.x + threadIdx.x; i < n4; i += stride){
    float4 v = reinterpret_cast<const float4*>(in)[i];
    ushort4 o;
    o.x = f2bf(v.x); o.y = f2bf(v.y); o.z = f2bf(v.z); o.w = f2bf(v.w);
    reinterpret_cast<ushort4*>(out)[i] = o;
  }
}

// ---------------- bf16 B^T GEMM, counted-vmcnt deep pipeline ----------------
template<int F32OUT>
__global__ __launch_bounds__(512, 1) void k_gemm_bt(const unsigned short* __restrict__ A,
                                                    const unsigned short* __restrict__ Bt,
                                                    const float* __restrict__ bias,
                                                    void* __restrict__ C,
                                                    int M, int N, int K, int gx){
  const int nwg = gridDim.x;
  const int cpx = nwg >> 3;
  const int bid = blockIdx.x;
  const int swz = (bid & 7) * cpx + (bid >> 3);
  const int by = swz / gx, bx = swz - by*gx;
  const int m0 = by * 128, n0 = bx * 256;

  const int tid = threadIdx.x;
  const int w = tid >> 6, lane = tid & 63, g = lane >> 4, c = lane & 15;
  const int wm = w >> 2, wn = w & 3;       // 2 x 4 waves

  __shared__ __align__(16) unsigned short L[4 * 12288];

  const int NT = K >> 5;                   // 64 K-tiles

  const int arow = tid >> 2, apc = tid & 3;
  const int brow0 = tid >> 2, bpc0 = tid & 3;
  const int brow1 = (tid + 512) >> 2, bpc1 = tid & 3;
  const unsigned short* Abase = &A [(size_t)(m0 + arow )*K + (size_t)((apc ^ ((arow >>1)&3))*8)];
  const unsigned short* Bbase0 = &Bt[(size_t)(n0 + brow0)*K + (size_t)((bpc0 ^ ((brow0>>1)&3))*8)];
  const unsigned short* Bbase1 = &Bt[(size_t)(n0 + brow1)*K + (size_t)((bpc1 ^ ((brow1>>1)&3))*8)];

  auto stage = [&](int tile, int slot){
    const int kt = tile << 5;
    unsigned short* Ls = &L[slot * 12288];
    gload_lds16(Abase  + kt, &Ls[tid*8]);
    gload_lds16(Bbase0 + kt, &Ls[4096 + tid*8]);
    gload_lds16(Bbase1 + kt, &Ls[4096 + (tid+512)*8]);
  };

  f32x4 acc[4][4];
#pragma unroll
  for (int i=0;i<4;i++)
#pragma unroll
    for (int j=0;j<4;j++)
#pragma unroll
      for (int r=0;r<4;r++) acc[i][j][r] = 0.f;

  int aoff[4], boff[4];
#pragma unroll
  for (int mi=0;mi<4;mi++){
    int row = wm*64 + mi*16 + c;
    aoff[mi] = row*32 + ((g ^ ((row>>1)&3)) << 3);
  }
#pragma unroll
  for (int ni=0;ni<4;ni++){
    int row = wn*64 + ni*16 + c;
    boff[ni] = 4096 + row*32 + ((g ^ ((row>>1)&3)) << 3);
  }

  stage(0, 0); stage(1, 1); stage(2, 2);

  for (int t = 0; t < NT; ++t){
    if (t < NT-2)      { asm volatile("s_waitcnt vmcnt(6)" ::: "memory"); }
    else if (t == NT-2){ asm volatile("s_waitcnt vmcnt(3)" ::: "memory"); }
    else               { asm volatile("s_waitcnt vmcnt(0)" ::: "memory"); }
    __builtin_amdgcn_s_barrier();
    __builtin_amdgcn_sched_barrier(0);
    if (t+3 < NT) stage(t+3, (t+3)&3);

    const unsigned short* Ls = &L[(t&3) * 12288];
    s16x8 bfr[4];
#pragma unroll
    for (int ni=0;ni<4;ni++) bfr[ni] = *(const s16x8*)&Ls[boff[ni]];
    __builtin_amdgcn_s_setprio(1);
#pragma unroll
    for (int mi=0;mi<4;mi++){
      s16x8 af = *(const s16x8*)&Ls[aoff[mi]];
#pragma unroll
      for (int ni=0;ni<4;ni++)
        acc[mi][ni] = __builtin_amdgcn_mfma_f32_16x16x32_bf16(af, bfr[ni], acc[mi][ni], 0,0,0);
    }
    __builtin_amdgcn_s_setprio(0);
  }

#pragma unroll
  for (int ni=0;ni<4;ni++){
    const int col = n0 + wn*64 + ni*16 + c;
    const float bv = bias[col];
#pragma unroll
    for (int mi=0;mi<4;mi++){
      const int row = m0 + wm*64 + mi*16 + g*4;
#pragma unroll
      for (int r=0;r<4;r++){
        float v = acc[mi][ni][r] + bv;
        if (F32OUT) ((float*)C)[(size_t)(row+r)*N + col] = v;
        else ((unsigned short*)C)[(size_t)(row+r)*N + col] = f2bf(v);
      }
    }
  }
}

// ---------------- RoPE + qk RMS-norm for Q,K only --------------------------
__global__ __launch_bounds__(256) void k_rope_qk(const unsigned short* __restrict__ QKV,
                                                 const float* __restrict__ rp,
                                                 const float* __restrict__ qk_w,
                                                 unsigned short* __restrict__ Qp,
                                                 unsigned short* __restrict__ Kp){
  const int p = threadIdx.x;
  const int s = blockIdx.x*4 + threadIdx.y;
  const int h = blockIdx.y;
  const int b = blockIdx.z;
  const size_t n = (size_t)b*Sq + s;
  const int bh = b*Hq + h;

  float ang = rp[s*64 + p];
  float sn, cs; sincosf(ang, &sn, &cs);
  float w0 = qk_w[2*p], w1 = qk_w[2*p+1];
  const float QSCALE = 0.08838834764831845f * 1.4426950408889634f; // 1/sqrt(128)*log2e

  {
    unsigned q01 = *(const unsigned*)&QKV[n*E3q + h*DHq + 2*p];
    float x0 = bf2f((unsigned short)(q01 & 0xFFFFu));
    float x1 = bf2f((unsigned short)(q01 >> 16));
    float r0 = x0*cs - x1*sn, r1 = x0*sn + x1*cs;
    float ss = r0*r0 + r1*r1;
#pragma unroll
    for (int m=1;m<64;m<<=1) ss += __shfl_xor(ss, m);
    float sc = rsqrtf(ss/128.f + 1e-6f) * QSCALE;
    unsigned short o0 = f2bf(r0*sc*w0), o1 = f2bf(r1*sc*w1);
    *(unsigned*)&Qp[((size_t)bh*Sq + s)*DHq + 2*p] = (unsigned)o0 | ((unsigned)o1<<16);
  }
  {
    unsigned k01 = *(const unsigned*)&QKV[n*E3q + Dq + h*DHq + 2*p];
    float x0 = bf2f((unsigned short)(k01 & 0xFFFFu));
    float x1 = bf2f((unsigned short)(k01 >> 16));
    float r0 = x0*cs - x1*sn, r1 = x0*sn + x1*cs;
    float ss = r0*r0 + r1*r1;
#pragma unroll
    for (int m=1;m<64;m<<=1) ss += __shfl_xor(ss, m);
    float sc = rsqrtf(ss/128.f + 1e-6f);
    unsigned short o0 = f2bf(r0*sc*w0), o1 = f2bf(r1*sc*w1);
    *(unsigned*)&Kp[((size_t)bh*Sq + s)*DHq + 2*p] = (unsigned)o0 | ((unsigned)o1<<16);
  }
}

// ---------------- V transpose via LDS: QKV[s][v-part] -> Vt[bh][dh][s] ------
__global__ __launch_bounds__(256) void k_transpose_v(const unsigned short* __restrict__ QKV,
                                                     unsigned short* __restrict__ Vt){
  const int sblk = blockIdx.x;
  const int bh = blockIdx.y;
  const int b = bh >> 4, h = bh & 15;
  const int tid = threadIdx.x;
  __shared__ unsigned short T[128][136];

  const size_t base = ((size_t)(b*Sq) + sblk*128) * E3q + 2*(size_t)Dq + h*DHq;
#pragma unroll
  for (int i=0;i<8;i++){
    int pk = tid + i*256;
    int row = pk >> 4, cc = (pk & 15) * 8;
    s16x8 v = *(const s16x8*)&QKV[base + (size_t)row*E3q + cc];
    *(s16x8*)&T[row][cc] = v;
  }
  __syncthreads();
  const int dh = tid >> 1, sh = (tid & 1) * 64;
  unsigned short buf[64];
#pragma unroll
  for (int s=0;s<64;s++) buf[s] = T[sh + s][dh];
  size_t obase = ((size_t)bh*DHq + dh)*Sq + sblk*128 + sh;
#pragma unroll
  for (int i=0;i<8;i++)
    *(s16x8*)&Vt[obase + i*8] = *(const s16x8*)&buf[i*8];
}

// ---------------- causal MFMA flash attention (swapped-operand) -------------
// Q-block 128 (4 waves x 32 rows), KV-step 64, double-buffered LDS staging.
// QK^T computed TRANSPOSED: S^T = mfma(K-frag, Q-frag) so each lane holds
// S[q=c][k-slice] => k-reduction is lane-local (2 shfls per mi, not 32);
// row-sum accumulates per-lane partials (epilogue-only reduce); P^T packed
// via v_cvt_pk_bf16_f32 into LDS [q][k] (16B-chunk XOR swizzle), PV computes
// O^T = mfma(V^T-frag, P^T-frag). Scores in log2 units (Q pre-scaled).
__global__ __launch_bounds__(256, 2) void k_attn(const unsigned short* __restrict__ Qp,
                                                 const unsigned short* __restrict__ Kp,
                                                 const unsigned short* __restrict__ Vt,
                                                 unsigned short* __restrict__ Ar){
  const int L = blockIdx.x;
  int bh, qtile;
  if (L < 256){ bh = L >> 3; qtile = 8 + (L & 7); }
  else { int Ml = L - 256; bh = Ml >> 3; qtile = 7 - (Ml & 7); }
  const int b = bh >> 4, h = bh & 15;
  const int tid = threadIdx.x;
  const int w = tid >> 6, lane = tid & 63, g = lane >> 4, c = lane & 15;
  const int r0w = qtile*128 + w*32;

  const unsigned short* Qh = Qp + (size_t)bh * Sq * DHq;
  const unsigned short* Kh = Kp + (size_t)bh * Sq * DHq;
  const unsigned short* Vh = Vt + (size_t)bh * DHq * Sq;

  __shared__ __align__(16) unsigned short Ks[2][64*128];   // 32 KB
  __shared__ __align__(16) unsigned short Vs[2][128*64];   // 32 KB
  __shared__ __align__(16) unsigned short Pl[4][32*64];    // 16 KB  (per-wave [q][k])
  unsigned short* Pw = &Pl[w][0];

  // Q fragments (used as MFMA B-operand): Q[r0w+mi*16+c][kc*32+g*8 ..]
  s16x8 qf[2][4];
#pragma unroll
  for (int mi=0;mi<2;mi++)
#pragma unroll
    for (int kc=0;kc<4;kc++)
      qf[mi][kc] = *(const s16x8*)&Qh[(size_t)(r0w + mi*16 + c)*DHq + kc*32 + g*8];

  // acc[mi][dt] holds O^T[d = dt*16+g*4+r][q = r0w+mi*16+c]
  f32x4 acc[2][8];
#pragma unroll
  for (int mi=0;mi<2;mi++)
#pragma unroll
    for (int dt=0;dt<8;dt++)
#pragma unroll
      for (int r=0;r<4;r++) acc[mi][dt][r] = 0.f;
  float m_r[2] = { -INFINITY, -INFINITY };
  float l_p[2] = { 0.f, 0.f };             // per-lane PARTIAL sums

  const int nsteps = 2*qtile + 2;

  auto stage = [&](int j0s, int bufi){
#pragma unroll
    for (int i=0;i<4;i++){
      int pk = tid + i*256;              // K: 1024 chunks of 16B
      int row = pk>>4, pc = pk&15;
      gload_lds16(&Kh[(size_t)(j0s+row)*DHq + ((pc^(row&7))<<3)], &Ks[bufi][pk*8]);
    }
#pragma unroll
    for (int i=0;i<4;i++){
      int pk = tid + i*256;              // V: 1024 chunks of 16B
      int row = pk>>3, pc = pk&7;
      gload_lds16(&Vh[(size_t)row*Sq + j0s + ((pc^(row&7))<<3)], &Vs[bufi][pk*8]);
    }
  };

  stage(0, 0);
  __syncthreads();

  for (int t=0; t<nsteps; ++t){
    const int j0 = t*64;
    if (t+1 < nsteps) stage((t+1)*64, (t+1)&1);

    if (j0 <= r0w + 31){
      const unsigned short* Kc = &Ks[t&1][0];
      const unsigned short* Vc = &Vs[t&1][0];

      // ---- S^T = K.Q^T : sv[mi][js][r] = S[q=c+mi*16][k=j0+js*16+g*4+r] ----
      f32x4 sv[2][4];
#pragma unroll
      for (int mi=0;mi<2;mi++)
#pragma unroll
        for (int js=0;js<4;js++)
#pragma unroll
          for (int r=0;r<4;r++) sv[mi][js][r] = 0.f;

      __builtin_amdgcn_s_setprio(1);
#pragma unroll
      for (int js=0;js<4;js++){
        s16x8 kf[4];
#pragma unroll
        for (int kc=0;kc<4;kc++)
          kf[kc] = *(const s16x8*)&Kc[(js*16 + c)*128 + (((kc*4+g)^(c&7))<<3)];
#pragma unroll
        for (int mi=0;mi<2;mi++)
#pragma unroll
          for (int kc=0;kc<4;kc++)
            sv[mi][js] = __builtin_amdgcn_mfma_f32_16x16x32_bf16(kf[kc], qf[mi][kc], sv[mi][js], 0,0,0);
      }
      __builtin_amdgcn_s_setprio(0);

      // ---- causal mask (diag steps only) ----
      if (j0 + 63 > r0w){
#pragma unroll
        for (int mi=0;mi<2;mi++){
          const int q = r0w + mi*16 + c;
#pragma unroll
          for (int js=0;js<4;js++)
#pragma unroll
            for (int r=0;r<4;r++)
              if (j0 + js*16 + g*4 + r > q) sv[mi][js][r] = -INFINITY;
        }
      }

      // ---- lane-local max; cross-lane over g-groups only ----
      float pmx[2];
#pragma unroll
      for (int mi=0;mi<2;mi++){
        float mx = fmaxf(fmaxf(sv[mi][0][0],sv[mi][0][1]), fmaxf(sv[mi][0][2],sv[mi][0][3]));
#pragma unroll
        for (int js=1;js<4;js++){
          float a = fmaxf(fmaxf(sv[mi][js][0],sv[mi][js][1]), fmaxf(sv[mi][js][2],sv[mi][js][3]));
          mx = fmaxf(mx, a);
        }
        mx = fmaxf(mx, __shfl_xor(mx, 16));
        mx = fmaxf(mx, __shfl_xor(mx, 32));
        pmx[mi] = mx;
      }
      // ---- defer-max rescale ----
      int need = (pmx[0] > m_r[0] + 8.f) | (pmx[1] > m_r[1] + 8.f);
      if (__any(need)){
#pragma unroll
        for (int mi=0;mi<2;mi++){
          float mnew = fmaxf(m_r[mi], pmx[mi]);
          float corr = exp2f(m_r[mi] - mnew);
          l_p[mi] *= corr;
          m_r[mi] = mnew;
#pragma unroll
          for (int dt=0;dt<8;dt++)
#pragma unroll
            for (int r=0;r<4;r++) acc[mi][dt][r] *= corr;
        }
      }
      // ---- exp2, per-lane partial sum, packed P^T -> LDS [q][k] ----
#pragma unroll
      for (int mi=0;mi<2;mi++){
        const float mm = m_r[mi];
        const int rowoff = (mi*16 + c)*64;
#pragma unroll
        for (int js=0;js<4;js++){
          float e0 = exp2f(sv[mi][js][0] - mm);
          float e1 = exp2f(sv[mi][js][1] - mm);
          float e2 = exp2f(sv[mi][js][2] - mm);
          float e3 = exp2f(sv[mi][js][3] - mm);
          l_p[mi] += (e0+e1)+(e2+e3);
          uint2 pk2;
          pk2.x = cvtpk_bf16(e0, e1);
          pk2.y = cvtpk_bf16(e2, e3);
          const int kc8 = js*2 + (g>>1);
          *(uint2*)&Pw[rowoff + ((kc8 ^ (c&7))<<3) + (g&1)*4] = pk2;
        }
      }

      // ---- O^T += V^T (128x64) . P^T (64x32) ----
      s16x8 pfr[2][2];
#pragma unroll
      for (int mi=0;mi<2;mi++)
#pragma unroll
        for (int kc=0;kc<2;kc++)
          pfr[mi][kc] = *(const s16x8*)&Pw[(mi*16 + c)*64 + (((kc*4+g)^(c&7))<<3)];
      __builtin_amdgcn_s_setprio(1);
#pragma unroll
      for (int dt=0; dt<8; dt++){
#pragma unroll
        for (int kc=0;kc<2;kc++){
          s16x8 vfr = *(const s16x8*)&Vc[(dt*16 + c)*64 + (((kc*4+g)^(c&7))<<3)];
#pragma unroll
          for (int mi=0;mi<2;mi++)
            acc[mi][dt] = __builtin_amdgcn_mfma_f32_16x16x32_bf16(vfr, pfr[mi][kc], acc[mi][dt], 0,0,0);
        }
      }
      __builtin_amdgcn_s_setprio(0);
    }
    __syncthreads();
  }

  // ---- epilogue: reduce l across g-groups, normalize, write O^T ----
#pragma unroll
  for (int mi=0;mi<2;mi++){
    float l = l_p[mi];
    l += __shfl_xor(l, 16);
    l += __shfl_xor(l, 32);
    const float inv = 1.f / l;
    const int row = r0w + mi*16 + c;
    unsigned short* dst = &Ar[((size_t)(b*Sq + row))*Dq + h*DHq];
#pragma unroll
    for (int dt=0; dt<8; dt++){
      uint2 o2;
      o2.x = cvtpk_bf16(acc[mi][dt][0]*inv, acc[mi][dt][1]*inv);
      o2.y = cvtpk_bf16(acc[mi][dt][2]*inv, acc[mi][dt][3]*inv);
      *(uint2*)&dst[dt*16 + g*4] = o2;
    }
  }
}

// ---------------- row RMS-norm over D=2048, in place -----------------------
__global__ __launch_bounds__(256) void k_rmsnorm(unsigned short* __restrict__ A,
                                                 const float* __restrict__ w){
  const int row = blockIdx.x;
  const int tid = threadIdx.x;
  s16x8 v = *(const s16x8*)&A[(size_t)row*Dq + tid*8];
  float f[8]; float ss = 0.f;
#pragma unroll
  for (int i=0;i<8;i++){ f[i] = bf2f((unsigned short)v[i]); ss += f[i]*f[i]; }
#pragma unroll
  for (int m=1;m<64;m<<=1) ss += __shfl_xor(ss, m);
  __shared__ float red[4];
  if ((tid&63)==0) red[tid>>6] = ss;
  __syncthreads();
  ss = red[0]+red[1]+red[2]+red[3];
  float sc = rsqrtf(ss/2048.f + 1e-6f);
  unsigned short o[8];
#pragma unroll
  for (int i=0;i<8;i++) o[i] = f2bf(f[i]*sc*w[tid*8+i]);
  *(s16x8*)&A[(size_t)row*Dq + tid*8] = *(const s16x8*)o;
}

extern "C" void kernel_launch(void* const* d_in, const int* in_sizes, int n_in,
                              void* d_out, int out_size, void* d_ws, size_t ws_size,
                              hipStream_t stream){
  const float* x     = (const float*)d_in[0];
  const float* rp    = (const float*)d_in[1];
  const float* Win   = (const float*)d_in[2];
  const float* b_in  = (const float*)d_in[3];
  const float* Wout  = (const float*)d_in[4];
  const float* b_out = (const float*)d_in[5];
  const float* qk_w  = (const float*)d_in[6];
  const float* out_w = (const float*)d_in[7];
  float* outp = (float*)d_out;

  if (ws_size < (160ull<<20)) return;   // need 160 MiB scratch

  char* ws = (char*)d_ws;
  unsigned short* Xb    = (unsigned short*)(ws);                 // 16 MiB
  unsigned short* Wb    = (unsigned short*)(ws + (16ull<<20));   // 24 MiB
  unsigned short* Woutb = (unsigned short*)(ws + (40ull<<20));   //  8 MiB
  unsigned short* QKVb  = (unsigned short*)(ws + (48ull<<20));   // 48 MiB
  unsigned short* Qp    = (unsigned short*)(ws + (96ull<<20));   // 16 MiB
  unsigned short* Kp    = (unsigned short*)(ws + (112ull<<20));  // 16 MiB
  unsigned short* Vt    = (unsigned short*)(ws + (128ull<<20));  // 16 MiB
  unsigned short* Ar    = (unsigned short*)(ws + (144ull<<20));  // 16 MiB

  // 1) converts
  k_convert<<<2048, 256, 0, stream>>>(x,    Xb,    (Bq*Sq*Dq)/4);
  k_convert<<<2048, 256, 0, stream>>>(Win,  Wb,    (E3q*Dq)/4);
  k_convert<<<1024, 256, 0, stream>>>(Wout, Woutb, (Dq*Dq)/4);
  // 2) QKV = X . Win^T + b_in   (M=4096, N=6144, K=2048): grid 24x32 = 768
  k_gemm_bt<0><<<768, 512, 0, stream>>>(Xb, Wb, b_in, QKVb, Bq*Sq, E3q, Dq, E3q/256);
  // 3) RoPE + qk RMS-norm (Q pre-scaled to log2 units) ; V transpose
  k_rope_qk<<<dim3(Sq/4, Hq, Bq), dim3(64,4), 0, stream>>>(QKVb, rp, qk_w, Qp, Kp);
  k_transpose_v<<<dim3(Sq/128, Bq*Hq), 256, 0, stream>>>(QKVb, Vt);
  // 4) causal flash attention (pair-balanced 1D grid)
  k_attn<<<512, 256, 0, stream>>>(Qp, Kp, Vt, Ar);
  // 5) out RMS-norm (in place on Ar)
  k_rmsnorm<<<Bq*Sq, 256, 0, stream>>>(Ar, out_w);
  // 6) Out = A . Wout^T + b_out  (M=4096, N=2048, K=2048): grid 8x32 = 256
  k_gemm_bt<1><<<256, 512, 0, stream>>>(Ar, Woutb, b_out, outp, Bq*Sq, Dq, Dq, Dq/256);
}

// Round 6
// 300.056 us; speedup vs baseline: 2.5178x; 1.0104x over previous
//
#include <hip/hip_runtime.h>
#include <cstdint>
#include <cstddef>

// Problem constants (B,S,D,H) = (2,2048,2048,16), DH=128
#define Bq  2
#define Sq  2048
#define Dq  2048
#define Hq  16
#define DHq 128
#define E3q 6144   // 3*D

typedef __attribute__((ext_vector_type(8))) short s16x8;   // 8 bf16 (4 VGPRs)
typedef __attribute__((ext_vector_type(4))) float f32x4;   // MFMA accumulator

__device__ __forceinline__ unsigned short f2bf(float f){
  union { float f; unsigned u; } v; v.f = f;
  unsigned r = v.u + 0x7FFFu + ((v.u >> 16) & 1u);   // round-to-nearest-even
  return (unsigned short)(r >> 16);
}
__device__ __forceinline__ float bf2f(unsigned short b){
  union { unsigned u; float f; } v; v.u = ((unsigned)b) << 16;
  return v.f;
}
// pack two f32 -> two bf16 in one op (no builtin on gfx950; T12 recipe)
__device__ __forceinline__ unsigned cvtpk_bf16(float lo, float hi){
  unsigned r;
  asm("v_cvt_pk_bf16_f32 %0, %1, %2" : "=v"(r) : "v"(lo), "v"(hi));
  return r;
}

// async global->LDS, 16B per lane. LDS dest must be wave-uniform base + lane*16.
__device__ __forceinline__ void gload_lds16(const void* g, void* l){
  __builtin_amdgcn_global_load_lds(
      (const __attribute__((address_space(1))) void*)g,
      (__attribute__((address_space(3))) void*)l, 16, 0, 0);
}

// ---------------- fp32 -> bf16 convert (vectorized x4) ----------------
__global__ __launch_bounds__(256) void k_convert(const float* __restrict__ in,
                                                 unsigned short* __restrict__ out, int n4){
  int stride = gridDim.x * blockDim.x;
  for (int i = blockIdx.x*blockDim.x + threadIdx.x; i < n4; i += stride){
    float4 v = reinterpret_cast<const float4*>(in)[i];
    ushort4 o;
    o.x = f2bf(v.x); o.y = f2bf(v.y); o.z = f2bf(v.z); o.w = f2bf(v.w);
    reinterpret_cast<ushort4*>(out)[i] = o;
  }
}

// ---------------- bf16 B^T GEMM, ring-6 counted-vmcnt pipeline --------------
// C[m,n] = sum_k A[m,k]*Bt[n,k] + bias[n].
// BM=128, BN=256, BK=32, 512 threads (8 waves 2x4), per-wave 64x64 (4x4 frags).
// LDS: ring-6 of K-tiles (24KB each, 144KB) -> prefetch distance 5 (~770cy)
// covers L2/LLC fill latency. Per iter: counted vmcnt (never 0 until tail),
// raw s_barrier, stage tile t+5 into slot (t-1)%6 (reads done pre-barrier).
// XCD mapping: xcd = bid&7 owns rows [xcd*4, xcd*4+4); within-chunk traversal
// is COLUMN-major so the 32 concurrent blocks = ~8 cols x 4 rows: each
// B-panel K-slice is L2-filled once and shared by 4 rows; 2MB A-set resident.
// Requires M == 4096 (32 row-tiles, 4 per XCD) -- true for both GEMMs.
template<int F32OUT>
__global__ __launch_bounds__(512, 1) void k_gemm_bt(const unsigned short* __restrict__ A,
                                                    const unsigned short* __restrict__ Bt,
                                                    const float* __restrict__ bias,
                                                    void* __restrict__ C,
                                                    int M, int N, int K){
  const int bid = blockIdx.x;
  const int xcd = bid & 7, u = bid >> 3;
  const int by = xcd*4 + (u & 3);          // 32 row-tiles, 4 per XCD
  const int bx = u >> 2;                   // column index (col-major in chunk)
  const int m0 = by * 128, n0 = bx * 256;

  const int tid = threadIdx.x;
  const int w = tid >> 6, lane = tid & 63, g = lane >> 4, c = lane & 15;
  const int wm = w >> 2, wn = w & 3;       // 2 x 4 waves

  __shared__ __align__(16) unsigned short L[6 * 12288];   // 144 KB ring-6

  const int NT = K >> 5;                   // 64 K-tiles

  const int arow = tid >> 2, apc = tid & 3;
  const int brow0 = tid >> 2, bpc0 = tid & 3;
  const int brow1 = (tid + 512) >> 2, bpc1 = tid & 3;
  const unsigned short* Abase  = &A [(size_t)(m0 + arow )*K + (size_t)((apc ^ ((arow >>1)&3))*8)];
  const unsigned short* Bbase0 = &Bt[(size_t)(n0 + brow0)*K + (size_t)((bpc0 ^ ((brow0>>1)&3))*8)];
  const unsigned short* Bbase1 = &Bt[(size_t)(n0 + brow1)*K + (size_t)((bpc1 ^ ((brow1>>1)&3))*8)];

  auto stage = [&](int tile, int slot){
    const int kt = tile << 5;
    unsigned short* Ls = &L[slot * 12288];
    gload_lds16(Abase  + kt, &Ls[tid*8]);
    gload_lds16(Bbase0 + kt, &Ls[4096 + tid*8]);
    gload_lds16(Bbase1 + kt, &Ls[4096 + (tid+512)*8]);
  };

  f32x4 acc[4][4];
#pragma unroll
  for (int i=0;i<4;i++)
#pragma unroll
    for (int j=0;j<4;j++)
#pragma unroll
      for (int r=0;r<4;r++) acc[i][j][r] = 0.f;

  int aoff[4], boff[4];
#pragma unroll
  for (int mi=0;mi<4;mi++){
    int row = wm*64 + mi*16 + c;
    aoff[mi] = row*32 + ((g ^ ((row>>1)&3)) << 3);
  }
#pragma unroll
  for (int ni=0;ni<4;ni++){
    int row = wn*64 + ni*16 + c;
    boff[ni] = 4096 + row*32 + ((g ^ ((row>>1)&3)) << 3);
  }

  // prologue: fill 5 slots (15 loads in flight)
  stage(0,0); stage(1,1); stage(2,2); stage(3,3); stage(4,4);

  int slot = 0;                            // t % 6
  for (int t = 0; t < NT; ++t){
    const int rem = NT-1-t;                // tiles still outstanding beyond t
    if (rem >= 4)      asm volatile("s_waitcnt vmcnt(12)" ::: "memory");
    else if (rem == 3) asm volatile("s_waitcnt vmcnt(9)"  ::: "memory");
    else if (rem == 2) asm volatile("s_waitcnt vmcnt(6)"  ::: "memory");
    else if (rem == 1) asm volatile("s_waitcnt vmcnt(3)"  ::: "memory");
    else               asm volatile("s_waitcnt vmcnt(0)"  ::: "memory");
    __builtin_amdgcn_s_barrier();
    __builtin_amdgcn_sched_barrier(0);
    if (t+5 < NT) stage(t+5, slot == 0 ? 5 : slot-1);   // (t+5)%6 == (t-1)%6

    const unsigned short* Ls = &L[slot * 12288];
    s16x8 bfr[4];
#pragma unroll
    for (int ni=0;ni<4;ni++) bfr[ni] = *(const s16x8*)&Ls[boff[ni]];
    __builtin_amdgcn_s_setprio(1);
#pragma unroll
    for (int mi=0;mi<4;mi++){
      s16x8 af = *(const s16x8*)&Ls[aoff[mi]];
#pragma unroll
      for (int ni=0;ni<4;ni++)
        acc[mi][ni] = __builtin_amdgcn_mfma_f32_16x16x32_bf16(af, bfr[ni], acc[mi][ni], 0,0,0);
    }
    __builtin_amdgcn_s_setprio(0);
    slot = (slot == 5) ? 0 : slot+1;
  }

  // epilogue
#pragma unroll
  for (int ni=0;ni<4;ni++){
    const int col = n0 + wn*64 + ni*16 + c;
    const float bv = bias[col];
#pragma unroll
    for (int mi=0;mi<4;mi++){
      const int row = m0 + wm*64 + mi*16 + g*4;
#pragma unroll
      for (int r=0;r<4;r++){
        float v = acc[mi][ni][r] + bv;
        if (F32OUT) ((float*)C)[(size_t)(row+r)*N + col] = v;
        else ((unsigned short*)C)[(size_t)(row+r)*N + col] = f2bf(v);
      }
    }
  }
}

// ---------------- RoPE + qk RMS-norm for Q,K only --------------------------
__global__ __launch_bounds__(256) void k_rope_qk(const unsigned short* __restrict__ QKV,
                                                 const float* __restrict__ rp,
                                                 const float* __restrict__ qk_w,
                                                 unsigned short* __restrict__ Qp,
                                                 unsigned short* __restrict__ Kp){
  const int p = threadIdx.x;
  const int s = blockIdx.x*4 + threadIdx.y;
  const int h = blockIdx.y;
  const int b = blockIdx.z;
  const size_t n = (size_t)b*Sq + s;
  const int bh = b*Hq + h;

  float ang = rp[s*64 + p];
  float sn, cs; sincosf(ang, &sn, &cs);
  float w0 = qk_w[2*p], w1 = qk_w[2*p+1];
  const float QSCALE = 0.08838834764831845f * 1.4426950408889634f; // 1/sqrt(128)*log2e

  {
    unsigned q01 = *(const unsigned*)&QKV[n*E3q + h*DHq + 2*p];
    float x0 = bf2f((unsigned short)(q01 & 0xFFFFu));
    float x1 = bf2f((unsigned short)(q01 >> 16));
    float r0 = x0*cs - x1*sn, r1 = x0*sn + x1*cs;
    float ss = r0*r0 + r1*r1;
#pragma unroll
    for (int m=1;m<64;m<<=1) ss += __shfl_xor(ss, m);
    float sc = rsqrtf(ss/128.f + 1e-6f) * QSCALE;
    unsigned short o0 = f2bf(r0*sc*w0), o1 = f2bf(r1*sc*w1);
    *(unsigned*)&Qp[((size_t)bh*Sq + s)*DHq + 2*p] = (unsigned)o0 | ((unsigned)o1<<16);
  }
  {
    unsigned k01 = *(const unsigned*)&QKV[n*E3q + Dq + h*DHq + 2*p];
    float x0 = bf2f((unsigned short)(k01 & 0xFFFFu));
    float x1 = bf2f((unsigned short)(k01 >> 16));
    float r0 = x0*cs - x1*sn, r1 = x0*sn + x1*cs;
    float ss = r0*r0 + r1*r1;
#pragma unroll
    for (int m=1;m<64;m<<=1) ss += __shfl_xor(ss, m);
    float sc = rsqrtf(ss/128.f + 1e-6f);
    unsigned short o0 = f2bf(r0*sc*w0), o1 = f2bf(r1*sc*w1);
    *(unsigned*)&Kp[((size_t)bh*Sq + s)*DHq + 2*p] = (unsigned)o0 | ((unsigned)o1<<16);
  }
}

// ---------------- V transpose via LDS: QKV[s][v-part] -> Vt[bh][dh][s] ------
__global__ __launch_bounds__(256) void k_transpose_v(const unsigned short* __restrict__ QKV,
                                                     unsigned short* __restrict__ Vt){
  const int sblk = blockIdx.x;
  const int bh = blockIdx.y;
  const int b = bh >> 4, h = bh & 15;
  const int tid = threadIdx.x;
  __shared__ unsigned short T[128][136];

  const size_t base = ((size_t)(b*Sq) + sblk*128) * E3q + 2*(size_t)Dq + h*DHq;
#pragma unroll
  for (int i=0;i<8;i++){
    int pk = tid + i*256;
    int row = pk >> 4, cc = (pk & 15) * 8;
    s16x8 v = *(const s16x8*)&QKV[base + (size_t)row*E3q + cc];
    *(s16x8*)&T[row][cc] = v;
  }
  __syncthreads();
  const int dh = tid >> 1, sh = (tid & 1) * 64;
  unsigned short buf[64];
#pragma unroll
  for (int s=0;s<64;s++) buf[s] = T[sh + s][dh];
  size_t obase = ((size_t)bh*DHq + dh)*Sq + sblk*128 + sh;
#pragma unroll
  for (int i=0;i<8;i++)
    *(s16x8*)&Vt[obase + i*8] = *(const s16x8*)&buf[i*8];
}

// ---------------- causal MFMA flash attention (swapped-operand) -------------
__global__ __launch_bounds__(256, 2) void k_attn(const unsigned short* __restrict__ Qp,
                                                 const unsigned short* __restrict__ Kp,
                                                 const unsigned short* __restrict__ Vt,
                                                 unsigned short* __restrict__ Ar){
  const int L = blockIdx.x;
  int bh, qtile;
  if (L < 256){ bh = L >> 3; qtile = 8 + (L & 7); }
  else { int Ml = L - 256; bh = Ml >> 3; qtile = 7 - (Ml & 7); }
  const int b = bh >> 4, h = bh & 15;
  const int tid = threadIdx.x;
  const int w = tid >> 6, lane = tid & 63, g = lane >> 4, c = lane & 15;
  const int r0w = qtile*128 + w*32;

  const unsigned short* Qh = Qp + (size_t)bh * Sq * DHq;
  const unsigned short* Kh = Kp + (size_t)bh * Sq * DHq;
  const unsigned short* Vh = Vt + (size_t)bh * DHq * Sq;

  __shared__ __align__(16) unsigned short Ks[2][64*128];   // 32 KB
  __shared__ __align__(16) unsigned short Vs[2][128*64];   // 32 KB
  __shared__ __align__(16) unsigned short Pl[4][32*64];    // 16 KB  (per-wave [q][k])
  unsigned short* Pw = &Pl[w][0];

  s16x8 qf[2][4];
#pragma unroll
  for (int mi=0;mi<2;mi++)
#pragma unroll
    for (int kc=0;kc<4;kc++)
      qf[mi][kc] = *(const s16x8*)&Qh[(size_t)(r0w + mi*16 + c)*DHq + kc*32 + g*8];

  f32x4 acc[2][8];
#pragma unroll
  for (int mi=0;mi<2;mi++)
#pragma unroll
    for (int dt=0;dt<8;dt++)
#pragma unroll
      for (int r=0;r<4;r++) acc[mi][dt][r] = 0.f;
  float m_r[2] = { -INFINITY, -INFINITY };
  float l_p[2] = { 0.f, 0.f };             // per-lane PARTIAL sums

  const int nsteps = 2*qtile + 2;

  auto stage = [&](int j0s, int bufi){
#pragma unroll
    for (int i=0;i<4;i++){
      int pk = tid + i*256;              // K: 1024 chunks of 16B
      int row = pk>>4, pc = pk&15;
      gload_lds16(&Kh[(size_t)(j0s+row)*DHq + ((pc^(row&7))<<3)], &Ks[bufi][pk*8]);
    }
#pragma unroll
    for (int i=0;i<4;i++){
      int pk = tid + i*256;              // V: 1024 chunks of 16B
      int row = pk>>3, pc = pk&7;
      gload_lds16(&Vh[(size_t)row*Sq + j0s + ((pc^(row&7))<<3)], &Vs[bufi][pk*8]);
    }
  };

  stage(0, 0);
  __syncthreads();

  for (int t=0; t<nsteps; ++t){
    const int j0 = t*64;
    if (t+1 < nsteps) stage((t+1)*64, (t+1)&1);

    if (j0 <= r0w + 31){
      const unsigned short* Kc = &Ks[t&1][0];
      const unsigned short* Vc = &Vs[t&1][0];

      // ---- S^T = K.Q^T : sv[mi][js][r] = S[q=c+mi*16][k=j0+js*16+g*4+r] ----
      f32x4 sv[2][4];
#pragma unroll
      for (int mi=0;mi<2;mi++)
#pragma unroll
        for (int js=0;js<4;js++)
#pragma unroll
          for (int r=0;r<4;r++) sv[mi][js][r] = 0.f;

      __builtin_amdgcn_s_setprio(1);
#pragma unroll
      for (int js=0;js<4;js++){
        s16x8 kf[4];
#pragma unroll
        for (int kc=0;kc<4;kc++)
          kf[kc] = *(const s16x8*)&Kc[(js*16 + c)*128 + (((kc*4+g)^(c&7))<<3)];
#pragma unroll
        for (int mi=0;mi<2;mi++)
#pragma unroll
          for (int kc=0;kc<4;kc++)
            sv[mi][js] = __builtin_amdgcn_mfma_f32_16x16x32_bf16(kf[kc], qf[mi][kc], sv[mi][js], 0,0,0);
      }
      __builtin_amdgcn_s_setprio(0);

      // ---- causal mask (diag steps only) ----
      if (j0 + 63 > r0w){
#pragma unroll
        for (int mi=0;mi<2;mi++){
          const int q = r0w + mi*16 + c;
#pragma unroll
          for (int js=0;js<4;js++)
#pragma unroll
            for (int r=0;r<4;r++)
              if (j0 + js*16 + g*4 + r > q) sv[mi][js][r] = -INFINITY;
        }
      }

      // ---- lane-local max; cross-lane over g-groups only ----
      float pmx[2];
#pragma unroll
      for (int mi=0;mi<2;mi++){
        float mx = fmaxf(fmaxf(sv[mi][0][0],sv[mi][0][1]), fmaxf(sv[mi][0][2],sv[mi][0][3]));
#pragma unroll
        for (int js=1;js<4;js++){
          float a = fmaxf(fmaxf(sv[mi][js][0],sv[mi][js][1]), fmaxf(sv[mi][js][2],sv[mi][js][3]));
          mx = fmaxf(mx, a);
        }
        mx = fmaxf(mx, __shfl_xor(mx, 16));
        mx = fmaxf(mx, __shfl_xor(mx, 32));
        pmx[mi] = mx;
      }
      // ---- defer-max rescale ----
      int need = (pmx[0] > m_r[0] + 8.f) | (pmx[1] > m_r[1] + 8.f);
      if (__any(need)){
#pragma unroll
        for (int mi=0;mi<2;mi++){
          float mnew = fmaxf(m_r[mi], pmx[mi]);
          float corr = exp2f(m_r[mi] - mnew);
          l_p[mi] *= corr;
          m_r[mi] = mnew;
#pragma unroll
          for (int dt=0;dt<8;dt++)
#pragma unroll
            for (int r=0;r<4;r++) acc[mi][dt][r] *= corr;
        }
      }
      // ---- exp2, per-lane partial sum, packed P^T -> LDS [q][k] ----
#pragma unroll
      for (int mi=0;mi<2;mi++){
        const float mm = m_r[mi];
        const int rowoff = (mi*16 + c)*64;
#pragma unroll
        for (int js=0;js<4;js++){
          float e0 = exp2f(sv[mi][js][0] - mm);
          float e1 = exp2f(sv[mi][js][1] - mm);
          float e2 = exp2f(sv[mi][js][2] - mm);
          float e3 = exp2f(sv[mi][js][3] - mm);
          l_p[mi] += (e0+e1)+(e2+e3);
          uint2 pk2;
          pk2.x = cvtpk_bf16(e0, e1);
          pk2.y = cvtpk_bf16(e2, e3);
          const int kc8 = js*2 + (g>>1);
          *(uint2*)&Pw[rowoff + ((kc8 ^ (c&7))<<3) + (g&1)*4] = pk2;
        }
      }

      // ---- O^T += V^T (128x64) . P^T (64x32) ----
      s16x8 pfr[2][2];
#pragma unroll
      for (int mi=0;mi<2;mi++)
#pragma unroll
        for (int kc=0;kc<2;kc++)
          pfr[mi][kc] = *(const s16x8*)&Pw[(mi*16 + c)*64 + (((kc*4+g)^(c&7))<<3)];
      __builtin_amdgcn_s_setprio(1);
#pragma unroll
      for (int dt=0; dt<8; dt++){
#pragma unroll
        for (int kc=0;kc<2;kc++){
          s16x8 vfr = *(const s16x8*)&Vc[(dt*16 + c)*64 + (((kc*4+g)^(c&7))<<3)];
#pragma unroll
          for (int mi=0;mi<2;mi++)
            acc[mi][dt] = __builtin_amdgcn_mfma_f32_16x16x32_bf16(vfr, pfr[mi][kc], acc[mi][dt], 0,0,0);
        }
      }
      __builtin_amdgcn_s_setprio(0);
    }
    __syncthreads();
  }

  // ---- epilogue: reduce l across g-groups, normalize, write O^T ----
#pragma unroll
  for (int mi=0;mi<2;mi++){
    float l = l_p[mi];
    l += __shfl_xor(l, 16);
    l += __shfl_xor(l, 32);
    const float inv = 1.f / l;
    const int row = r0w + mi*16 + c;
    unsigned short* dst = &Ar[((size_t)(b*Sq + row))*Dq + h*DHq];
#pragma unroll
    for (int dt=0; dt<8; dt++){
      uint2 o2;
      o2.x = cvtpk_bf16(acc[mi][dt][0]*inv, acc[mi][dt][1]*inv);
      o2.y = cvtpk_bf16(acc[mi][dt][2]*inv, acc[mi][dt][3]*inv);
      *(uint2*)&dst[dt*16 + g*4] = o2;
    }
  }
}

// ---------------- row RMS-norm over D=2048, in place -----------------------
__global__ __launch_bounds__(256) void k_rmsnorm(unsigned short* __restrict__ A,
                                                 const float* __restrict__ w){
  const int row = blockIdx.x;
  const int tid = threadIdx.x;
  s16x8 v = *(const s16x8*)&A[(size_t)row*Dq + tid*8];
  float f[8]; float ss = 0.f;
#pragma unroll
  for (int i=0;i<8;i++){ f[i] = bf2f((unsigned short)v[i]); ss += f[i]*f[i]; }
#pragma unroll
  for (int m=1;m<64;m<<=1) ss += __shfl_xor(ss, m);
  __shared__ float red[4];
  if ((tid&63)==0) red[tid>>6] = ss;
  __syncthreads();
  ss = red[0]+red[1]+red[2]+red[3];
  float sc = rsqrtf(ss/2048.f + 1e-6f);
  unsigned short o[8];
#pragma unroll
  for (int i=0;i<8;i++) o[i] = f2bf(f[i]*sc*w[tid*8+i]);
  *(s16x8*)&A[(size_t)row*Dq + tid*8] = *(const s16x8*)o;
}

extern "C" void kernel_launch(void* const* d_in, const int* in_sizes, int n_in,
                              void* d_out, int out_size, void* d_ws, size_t ws_size,
                              hipStream_t stream){
  const float* x     = (const float*)d_in[0];
  const float* rp    = (const float*)d_in[1];
  const float* Win   = (const float*)d_in[2];
  const float* b_in  = (const float*)d_in[3];
  const float* Wout  = (const float*)d_in[4];
  const float* b_out = (const float*)d_in[5];
  const float* qk_w  = (const float*)d_in[6];
  const float* out_w = (const float*)d_in[7];
  float* outp = (float*)d_out;

  if (ws_size < (160ull<<20)) return;   // need 160 MiB scratch

  char* ws = (char*)d_ws;
  unsigned short* Xb    = (unsigned short*)(ws);                 // 16 MiB
  unsigned short* Wb    = (unsigned short*)(ws + (16ull<<20));   // 24 MiB
  unsigned short* Woutb = (unsigned short*)(ws + (40ull<<20));   //  8 MiB
  unsigned short* QKVb  = (unsigned short*)(ws + (48ull<<20));   // 48 MiB
  unsigned short* Qp    = (unsigned short*)(ws + (96ull<<20));   // 16 MiB
  unsigned short* Kp    = (unsigned short*)(ws + (112ull<<20));  // 16 MiB
  unsigned short* Vt    = (unsigned short*)(ws + (128ull<<20));  // 16 MiB
  unsigned short* Ar    = (unsigned short*)(ws + (144ull<<20));  // 16 MiB

  // 1) converts
  k_convert<<<2048, 256, 0, stream>>>(x,    Xb,    (Bq*Sq*Dq)/4);
  k_convert<<<2048, 256, 0, stream>>>(Win,  Wb,    (E3q*Dq)/4);
  k_convert<<<1024, 256, 0, stream>>>(Wout, Woutb, (Dq*Dq)/4);
  // 2) QKV = X . Win^T + b_in   (M=4096, N=6144, K=2048): grid 24x32 = 768
  k_gemm_bt<0><<<768, 512, 0, stream>>>(Xb, Wb, b_in, QKVb, Bq*Sq, E3q, Dq);
  // 3) RoPE + qk RMS-norm (Q pre-scaled to log2 units) ; V transpose
  k_rope_qk<<<dim3(Sq/4, Hq, Bq), dim3(64,4), 0, stream>>>(QKVb, rp, qk_w, Qp, Kp);
  k_transpose_v<<<dim3(Sq/128, Bq*Hq), 256, 0, stream>>>(QKVb, Vt);
  // 4) causal flash attention (pair-balanced 1D grid)
  k_attn<<<512, 256, 0, stream>>>(Qp, Kp, Vt, Ar);
  // 5) out RMS-norm (in place on Ar)
  k_rmsnorm<<<Bq*Sq, 256, 0, stream>>>(Ar, out_w);
  // 6) Out = A . Wout^T + b_out  (M=4096, N=2048, K=2048): grid 8x32 = 256
  k_gemm_bt<1><<<256, 512, 0, stream>>>(Ar, Woutb, b_out, outp, Bq*Sq, Dq, Dq);
}

// Round 7
// 299.737 us; speedup vs baseline: 2.5205x; 1.0011x over previous
//
#include <hip/hip_runtime.h>
#include <cstdint>
#include <cstddef>

// Problem constants (B,S,D,H) = (2,2048,2048,16), DH=128
#define Bq  2
#define Sq  2048
#define Dq  2048
#define Hq  16
#define DHq 128
#define E3q 6144   // 3*D

typedef __attribute__((ext_vector_type(8))) short s16x8;   // 8 bf16 (4 VGPRs)
typedef __attribute__((ext_vector_type(4))) float f32x4;   // MFMA accumulator

__device__ __forceinline__ unsigned short f2bf(float f){
  union { float f; unsigned u; } v; v.f = f;
  unsigned r = v.u + 0x7FFFu + ((v.u >> 16) & 1u);   // round-to-nearest-even
  return (unsigned short)(r >> 16);
}
__device__ __forceinline__ float bf2f(unsigned short b){
  union { unsigned u; float f; } v; v.u = ((unsigned)b) << 16;
  return v.f;
}
// pack two f32 -> two bf16 in one op (no builtin on gfx950; T12 recipe)
__device__ __forceinline__ unsigned cvtpk_bf16(float lo, float hi){
  unsigned r;
  asm("v_cvt_pk_bf16_f32 %0, %1, %2" : "=v"(r) : "v"(lo), "v"(hi));
  return r;
}

// async global->LDS, 16B per lane. LDS dest must be wave-uniform base + lane*16.
__device__ __forceinline__ void gload_lds16(const void* g, void* l){
  __builtin_amdgcn_global_load_lds(
      (const __attribute__((address_space(1))) void*)g,
      (__attribute__((address_space(3))) void*)l, 16, 0, 0);
}

// ---------------- fp32 -> bf16 convert (vectorized x4) ----------------
__global__ __launch_bounds__(256) void k_convert(const float* __restrict__ in,
                                                 unsigned short* __restrict__ out, int n4){
  int stride = gridDim.x * blockDim.x;
  for (int i = blockIdx.x*blockDim.x + threadIdx.x; i < n4; i += stride){
    float4 v = reinterpret_cast<const float4*>(in)[i];
    ushort4 o;
    o.x = f2bf(v.x); o.y = f2bf(v.y); o.z = f2bf(v.z); o.w = f2bf(v.w);
    reinterpret_cast<ushort4*>(out)[i] = o;
  }
}

// ---------------- bf16 B^T GEMM, fat-wave (128x64/wave) ring-3 pipeline -----
// C[m,n] = sum_k A[m,k]*Bt[n,k] + bias[n].
// Block 128x256, BK=32, 256 threads = 4 waves (1M x 4N), per-wave OUTPUT
// 128x64 (8 m-frags x 4 n-frags): 32 MFMA per 12 ds_read_b128 per K-step.
// Arithmetic-intensity fix: LDS/CU-step 48KB (~375cy) < MFMA 620cy floor.
// LDS ring-3 x 24KB = 72KB -> 2 blocks/CU; cross-block overlap hides barrier
// drain (m114). Counted vmcnt: 6 loads/thread/tile, steady vmcnt(6).
// XCD mapping: xcd=bid&7 owns 4 of the 32 M-row-tiles; col-major traversal
// within chunk => B-panels L2-shared by 4 row-blocks. (M must be 4096: true.)
template<int F32OUT>
__global__ __launch_bounds__(256, 2) void k_gemm_bt(const unsigned short* __restrict__ A,
                                                    const unsigned short* __restrict__ Bt,
                                                    const float* __restrict__ bias,
                                                    void* __restrict__ C,
                                                    int M, int N, int K){
  const int bid = blockIdx.x;
  const int xcd = bid & 7, u = bid >> 3;
  const int by = xcd*4 + (u & 3);          // 32 row-tiles of 128, 4 per XCD
  const int bx = u >> 2;                   // column index (col-major in chunk)
  const int m0 = by * 128, n0 = bx * 256;

  const int tid = threadIdx.x;
  const int w = tid >> 6, lane = tid & 63, g = lane >> 4, c = lane & 15;

  __shared__ __align__(16) unsigned short L[3 * 12288];   // 72 KB ring-3

  const int NT = K >> 5;                   // 64 K-tiles

  // staging bases: 6 chunks/thread (A:2, B:4); chunk p -> row p>>2, pc p&3,
  // global col pre-swizzled by (row>>1)&3 (involution matches read side)
  const int r0 = tid >> 2, pc = tid & 3;
  const unsigned short* Ab0 = &A [(size_t)(m0 + r0      )*K + (size_t)((pc ^ (((r0      )>>1)&3))*8)];
  const unsigned short* Ab1 = &A [(size_t)(m0 + r0 +  64)*K + (size_t)((pc ^ (((r0 + 64)>>1)&3))*8)];
  const unsigned short* Bb0 = &Bt[(size_t)(n0 + r0      )*K + (size_t)((pc ^ (((r0      )>>1)&3))*8)];
  const unsigned short* Bb1 = &Bt[(size_t)(n0 + r0 +  64)*K + (size_t)((pc ^ (((r0 + 64)>>1)&3))*8)];
  const unsigned short* Bb2 = &Bt[(size_t)(n0 + r0 + 128)*K + (size_t)((pc ^ (((r0 +128)>>1)&3))*8)];
  const unsigned short* Bb3 = &Bt[(size_t)(n0 + r0 + 192)*K + (size_t)((pc ^ (((r0 +192)>>1)&3))*8)];

  auto stage = [&](int tile, int slot){
    const int kt = tile << 5;
    unsigned short* Ls = &L[slot * 12288];
    gload_lds16(Ab0 + kt, &Ls[tid*8]);
    gload_lds16(Ab1 + kt, &Ls[(tid+256)*8]);
    gload_lds16(Bb0 + kt, &Ls[4096 + tid*8]);
    gload_lds16(Bb1 + kt, &Ls[4096 + (tid+256)*8]);
    gload_lds16(Bb2 + kt, &Ls[4096 + (tid+512)*8]);
    gload_lds16(Bb3 + kt, &Ls[4096 + (tid+768)*8]);
  };

  f32x4 acc[8][4];
#pragma unroll
  for (int i=0;i<8;i++)
#pragma unroll
    for (int j=0;j<4;j++)
#pragma unroll
      for (int r=0;r<4;r++) acc[i][j][r] = 0.f;

  // swizzled LDS element offsets for fragment reads
  int aoff[8], boff[4];
#pragma unroll
  for (int mi=0;mi<8;mi++){
    int row = mi*16 + c;
    aoff[mi] = row*32 + ((g ^ ((row>>1)&3)) << 3);
  }
#pragma unroll
  for (int ni=0;ni<4;ni++){
    int row = w*64 + ni*16 + c;
    boff[ni] = 4096 + row*32 + ((g ^ ((row>>1)&3)) << 3);
  }

  // prologue: fill 2 slots (12 loads in flight)
  stage(0,0); stage(1,1);

  int slot = 0;                            // t % 3
  for (int t = 0; t < NT; ++t){
    if (t < NT-1) asm volatile("s_waitcnt vmcnt(6)" ::: "memory");
    else          asm volatile("s_waitcnt vmcnt(0)" ::: "memory");
    __builtin_amdgcn_s_barrier();
    __builtin_amdgcn_sched_barrier(0);
    if (t+2 < NT) stage(t+2, slot == 0 ? 2 : slot-1);   // (t+2)%3 == (t-1)%3

    const unsigned short* Ls = &L[slot * 12288];
    s16x8 bfr[4];
#pragma unroll
    for (int ni=0;ni<4;ni++) bfr[ni] = *(const s16x8*)&Ls[boff[ni]];
    __builtin_amdgcn_s_setprio(1);
#pragma unroll
    for (int mi=0;mi<8;mi++){
      s16x8 af = *(const s16x8*)&Ls[aoff[mi]];
#pragma unroll
      for (int ni=0;ni<4;ni++)
        acc[mi][ni] = __builtin_amdgcn_mfma_f32_16x16x32_bf16(af, bfr[ni], acc[mi][ni], 0,0,0);
    }
    __builtin_amdgcn_s_setprio(0);
    slot = (slot == 2) ? 0 : slot+1;
  }

  // epilogue
#pragma unroll
  for (int ni=0;ni<4;ni++){
    const int col = n0 + w*64 + ni*16 + c;
    const float bv = bias[col];
#pragma unroll
    for (int mi=0;mi<8;mi++){
      const int row = m0 + mi*16 + g*4;
#pragma unroll
      for (int r=0;r<4;r++){
        float v = acc[mi][ni][r] + bv;
        if (F32OUT) ((float*)C)[(size_t)(row+r)*N + col] = v;
        else ((unsigned short*)C)[(size_t)(row+r)*N + col] = f2bf(v);
      }
    }
  }
}

// ---------------- RoPE + qk RMS-norm for Q,K only --------------------------
__global__ __launch_bounds__(256) void k_rope_qk(const unsigned short* __restrict__ QKV,
                                                 const float* __restrict__ rp,
                                                 const float* __restrict__ qk_w,
                                                 unsigned short* __restrict__ Qp,
                                                 unsigned short* __restrict__ Kp){
  const int p = threadIdx.x;
  const int s = blockIdx.x*4 + threadIdx.y;
  const int h = blockIdx.y;
  const int b = blockIdx.z;
  const size_t n = (size_t)b*Sq + s;
  const int bh = b*Hq + h;

  float ang = rp[s*64 + p];
  float sn, cs; sincosf(ang, &sn, &cs);
  float w0 = qk_w[2*p], w1 = qk_w[2*p+1];
  const float QSCALE = 0.08838834764831845f * 1.4426950408889634f; // 1/sqrt(128)*log2e

  {
    unsigned q01 = *(const unsigned*)&QKV[n*E3q + h*DHq + 2*p];
    float x0 = bf2f((unsigned short)(q01 & 0xFFFFu));
    float x1 = bf2f((unsigned short)(q01 >> 16));
    float r0 = x0*cs - x1*sn, r1 = x0*sn + x1*cs;
    float ss = r0*r0 + r1*r1;
#pragma unroll
    for (int m=1;m<64;m<<=1) ss += __shfl_xor(ss, m);
    float sc = rsqrtf(ss/128.f + 1e-6f) * QSCALE;
    unsigned short o0 = f2bf(r0*sc*w0), o1 = f2bf(r1*sc*w1);
    *(unsigned*)&Qp[((size_t)bh*Sq + s)*DHq + 2*p] = (unsigned)o0 | ((unsigned)o1<<16);
  }
  {
    unsigned k01 = *(const unsigned*)&QKV[n*E3q + Dq + h*DHq + 2*p];
    float x0 = bf2f((unsigned short)(k01 & 0xFFFFu));
    float x1 = bf2f((unsigned short)(k01 >> 16));
    float r0 = x0*cs - x1*sn, r1 = x0*sn + x1*cs;
    float ss = r0*r0 + r1*r1;
#pragma unroll
    for (int m=1;m<64;m<<=1) ss += __shfl_xor(ss, m);
    float sc = rsqrtf(ss/128.f + 1e-6f);
    unsigned short o0 = f2bf(r0*sc*w0), o1 = f2bf(r1*sc*w1);
    *(unsigned*)&Kp[((size_t)bh*Sq + s)*DHq + 2*p] = (unsigned)o0 | ((unsigned)o1<<16);
  }
}

// ---------------- V transpose via LDS: QKV[s][v-part] -> Vt[bh][dh][s] ------
__global__ __launch_bounds__(256) void k_transpose_v(const unsigned short* __restrict__ QKV,
                                                     unsigned short* __restrict__ Vt){
  const int sblk = blockIdx.x;
  const int bh = blockIdx.y;
  const int b = bh >> 4, h = bh & 15;
  const int tid = threadIdx.x;
  __shared__ unsigned short T[128][136];

  const size_t base = ((size_t)(b*Sq) + sblk*128) * E3q + 2*(size_t)Dq + h*DHq;
#pragma unroll
  for (int i=0;i<8;i++){
    int pk = tid + i*256;
    int row = pk >> 4, cc = (pk & 15) * 8;
    s16x8 v = *(const s16x8*)&QKV[base + (size_t)row*E3q + cc];
    *(s16x8*)&T[row][cc] = v;
  }
  __syncthreads();
  const int dh = tid >> 1, sh = (tid & 1) * 64;
  unsigned short buf[64];
#pragma unroll
  for (int s=0;s<64;s++) buf[s] = T[sh + s][dh];
  size_t obase = ((size_t)bh*DHq + dh)*Sq + sblk*128 + sh;
#pragma unroll
  for (int i=0;i<8;i++)
    *(s16x8*)&Vt[obase + i*8] = *(const s16x8*)&buf[i*8];
}

// ---------------- causal MFMA flash attention (swapped-operand) -------------
__global__ __launch_bounds__(256, 2) void k_attn(const unsigned short* __restrict__ Qp,
                                                 const unsigned short* __restrict__ Kp,
                                                 const unsigned short* __restrict__ Vt,
                                                 unsigned short* __restrict__ Ar){
  const int L = blockIdx.x;
  int bh, qtile;
  if (L < 256){ bh = L >> 3; qtile = 8 + (L & 7); }
  else { int Ml = L - 256; bh = Ml >> 3; qtile = 7 - (Ml & 7); }
  const int b = bh >> 4, h = bh & 15;
  const int tid = threadIdx.x;
  const int w = tid >> 6, lane = tid & 63, g = lane >> 4, c = lane & 15;
  const int r0w = qtile*128 + w*32;

  const unsigned short* Qh = Qp + (size_t)bh * Sq * DHq;
  const unsigned short* Kh = Kp + (size_t)bh * Sq * DHq;
  const unsigned short* Vh = Vt + (size_t)bh * DHq * Sq;

  __shared__ __align__(16) unsigned short Ks[2][64*128];   // 32 KB
  __shared__ __align__(16) unsigned short Vs[2][128*64];   // 32 KB
  __shared__ __align__(16) unsigned short Pl[4][32*64];    // 16 KB  (per-wave [q][k])
  unsigned short* Pw = &Pl[w][0];

  s16x8 qf[2][4];
#pragma unroll
  for (int mi=0;mi<2;mi++)
#pragma unroll
    for (int kc=0;kc<4;kc++)
      qf[mi][kc] = *(const s16x8*)&Qh[(size_t)(r0w + mi*16 + c)*DHq + kc*32 + g*8];

  f32x4 acc[2][8];
#pragma unroll
  for (int mi=0;mi<2;mi++)
#pragma unroll
    for (int dt=0;dt<8;dt++)
#pragma unroll
      for (int r=0;r<4;r++) acc[mi][dt][r] = 0.f;
  float m_r[2] = { -INFINITY, -INFINITY };
  float l_p[2] = { 0.f, 0.f };             // per-lane PARTIAL sums

  const int nsteps = 2*qtile + 2;

  auto stage = [&](int j0s, int bufi){
#pragma unroll
    for (int i=0;i<4;i++){
      int pk = tid + i*256;              // K: 1024 chunks of 16B
      int row = pk>>4, pcc = pk&15;
      gload_lds16(&Kh[(size_t)(j0s+row)*DHq + ((pcc^(row&7))<<3)], &Ks[bufi][pk*8]);
    }
#pragma unroll
    for (int i=0;i<4;i++){
      int pk = tid + i*256;              // V: 1024 chunks of 16B
      int row = pk>>3, pcc = pk&7;
      gload_lds16(&Vh[(size_t)row*Sq + j0s + ((pcc^(row&7))<<3)], &Vs[bufi][pk*8]);
    }
  };

  stage(0, 0);
  __syncthreads();

  for (int t=0; t<nsteps; ++t){
    const int j0 = t*64;
    if (t+1 < nsteps) stage((t+1)*64, (t+1)&1);

    if (j0 <= r0w + 31){
      const unsigned short* Kc = &Ks[t&1][0];
      const unsigned short* Vc = &Vs[t&1][0];

      // ---- S^T = K.Q^T : sv[mi][js][r] = S[q=c+mi*16][k=j0+js*16+g*4+r] ----
      f32x4 sv[2][4];
#pragma unroll
      for (int mi=0;mi<2;mi++)
#pragma unroll
        for (int js=0;js<4;js++)
#pragma unroll
          for (int r=0;r<4;r++) sv[mi][js][r] = 0.f;

      __builtin_amdgcn_s_setprio(1);
#pragma unroll
      for (int js=0;js<4;js++){
        s16x8 kf[4];
#pragma unroll
        for (int kc=0;kc<4;kc++)
          kf[kc] = *(const s16x8*)&Kc[(js*16 + c)*128 + (((kc*4+g)^(c&7))<<3)];
#pragma unroll
        for (int mi=0;mi<2;mi++)
#pragma unroll
          for (int kc=0;kc<4;kc++)
            sv[mi][js] = __builtin_amdgcn_mfma_f32_16x16x32_bf16(kf[kc], qf[mi][kc], sv[mi][js], 0,0,0);
      }
      __builtin_amdgcn_s_setprio(0);

      // ---- causal mask (diag steps only) ----
      if (j0 + 63 > r0w){
#pragma unroll
        for (int mi=0;mi<2;mi++){
          const int q = r0w + mi*16 + c;
#pragma unroll
          for (int js=0;js<4;js++)
#pragma unroll
            for (int r=0;r<4;r++)
              if (j0 + js*16 + g*4 + r > q) sv[mi][js][r] = -INFINITY;
        }
      }

      // ---- lane-local max; cross-lane over g-groups only ----
      float pmx[2];
#pragma unroll
      for (int mi=0;mi<2;mi++){
        float mx = fmaxf(fmaxf(sv[mi][0][0],sv[mi][0][1]), fmaxf(sv[mi][0][2],sv[mi][0][3]));
#pragma unroll
        for (int js=1;js<4;js++){
          float a = fmaxf(fmaxf(sv[mi][js][0],sv[mi][js][1]), fmaxf(sv[mi][js][2],sv[mi][js][3]));
          mx = fmaxf(mx, a);
        }
        mx = fmaxf(mx, __shfl_xor(mx, 16));
        mx = fmaxf(mx, __shfl_xor(mx, 32));
        pmx[mi] = mx;
      }
      // ---- defer-max rescale ----
      int need = (pmx[0] > m_r[0] + 8.f) | (pmx[1] > m_r[1] + 8.f);
      if (__any(need)){
#pragma unroll
        for (int mi=0;mi<2;mi++){
          float mnew = fmaxf(m_r[mi], pmx[mi]);
          float corr = exp2f(m_r[mi] - mnew);
          l_p[mi] *= corr;
          m_r[mi] = mnew;
#pragma unroll
          for (int dt=0;dt<8;dt++)
#pragma unroll
            for (int r=0;r<4;r++) acc[mi][dt][r] *= corr;
        }
      }
      // ---- exp2, per-lane partial sum, packed P^T -> LDS [q][k] ----
#pragma unroll
      for (int mi=0;mi<2;mi++){
        const float mm = m_r[mi];
        const int rowoff = (mi*16 + c)*64;
#pragma unroll
        for (int js=0;js<4;js++){
          float e0 = exp2f(sv[mi][js][0] - mm);
          float e1 = exp2f(sv[mi][js][1] - mm);
          float e2 = exp2f(sv[mi][js][2] - mm);
          float e3 = exp2f(sv[mi][js][3] - mm);
          l_p[mi] += (e0+e1)+(e2+e3);
          uint2 pk2;
          pk2.x = cvtpk_bf16(e0, e1);
          pk2.y = cvtpk_bf16(e2, e3);
          const int kc8 = js*2 + (g>>1);
          *(uint2*)&Pw[rowoff + ((kc8 ^ (c&7))<<3) + (g&1)*4] = pk2;
        }
      }

      // ---- O^T += V^T (128x64) . P^T (64x32) ----
      s16x8 pfr[2][2];
#pragma unroll
      for (int mi=0;mi<2;mi++)
#pragma unroll
        for (int kc=0;kc<2;kc++)
          pfr[mi][kc] = *(const s16x8*)&Pw[(mi*16 + c)*64 + (((kc*4+g)^(c&7))<<3)];
      __builtin_amdgcn_s_setprio(1);
#pragma unroll
      for (int dt=0; dt<8; dt++){
#pragma unroll
        for (int kc=0;kc<2;kc++){
          s16x8 vfr = *(const s16x8*)&Vc[(dt*16 + c)*64 + (((kc*4+g)^(c&7))<<3)];
#pragma unroll
          for (int mi=0;mi<2;mi++)
            acc[mi][dt] = __builtin_amdgcn_mfma_f32_16x16x32_bf16(vfr, pfr[mi][kc], acc[mi][dt], 0,0,0);
        }
      }
      __builtin_amdgcn_s_setprio(0);
    }
    __syncthreads();
  }

  // ---- epilogue: reduce l across g-groups, normalize, write O^T ----
#pragma unroll
  for (int mi=0;mi<2;mi++){
    float l = l_p[mi];
    l += __shfl_xor(l, 16);
    l += __shfl_xor(l, 32);
    const float inv = 1.f / l;
    const int row = r0w + mi*16 + c;
    unsigned short* dst = &Ar[((size_t)(b*Sq + row))*Dq + h*DHq];
#pragma unroll
    for (int dt=0; dt<8; dt++){
      uint2 o2;
      o2.x = cvtpk_bf16(acc[mi][dt][0]*inv, acc[mi][dt][1]*inv);
      o2.y = cvtpk_bf16(acc[mi][dt][2]*inv, acc[mi][dt][3]*inv);
      *(uint2*)&dst[dt*16 + g*4] = o2;
    }
  }
}

// ---------------- row RMS-norm over D=2048, in place -----------------------
__global__ __launch_bounds__(256) void k_rmsnorm(unsigned short* __restrict__ A,
                                                 const float* __restrict__ w){
  const int row = blockIdx.x;
  const int tid = threadIdx.x;
  s16x8 v = *(const s16x8*)&A[(size_t)row*Dq + tid*8];
  float f[8]; float ss = 0.f;
#pragma unroll
  for (int i=0;i<8;i++){ f[i] = bf2f((unsigned short)v[i]); ss += f[i]*f[i]; }
#pragma unroll
  for (int m=1;m<64;m<<=1) ss += __shfl_xor(ss, m);
  __shared__ float red[4];
  if ((tid&63)==0) red[tid>>6] = ss;
  __syncthreads();
  ss = red[0]+red[1]+red[2]+red[3];
  float sc = rsqrtf(ss/2048.f + 1e-6f);
  unsigned short o[8];
#pragma unroll
  for (int i=0;i<8;i++) o[i] = f2bf(f[i]*sc*w[tid*8+i]);
  *(s16x8*)&A[(size_t)row*Dq + tid*8] = *(const s16x8*)o;
}

extern "C" void kernel_launch(void* const* d_in, const int* in_sizes, int n_in,
                              void* d_out, int out_size, void* d_ws, size_t ws_size,
                              hipStream_t stream){
  const float* x     = (const float*)d_in[0];
  const float* rp    = (const float*)d_in[1];
  const float* Win   = (const float*)d_in[2];
  const float* b_in  = (const float*)d_in[3];
  const float* Wout  = (const float*)d_in[4];
  const float* b_out = (const float*)d_in[5];
  const float* qk_w  = (const float*)d_in[6];
  const float* out_w = (const float*)d_in[7];
  float* outp = (float*)d_out;

  if (ws_size < (160ull<<20)) return;   // need 160 MiB scratch

  char* ws = (char*)d_ws;
  unsigned short* Xb    = (unsigned short*)(ws);                 // 16 MiB
  unsigned short* Wb    = (unsigned short*)(ws + (16ull<<20));   // 24 MiB
  unsigned short* Woutb = (unsigned short*)(ws + (40ull<<20));   //  8 MiB
  unsigned short* QKVb  = (unsigned short*)(ws + (48ull<<20));   // 48 MiB
  unsigned short* Qp    = (unsigned short*)(ws + (96ull<<20));   // 16 MiB
  unsigned short* Kp    = (unsigned short*)(ws + (112ull<<20));  // 16 MiB
  unsigned short* Vt    = (unsigned short*)(ws + (128ull<<20));  // 16 MiB
  unsigned short* Ar    = (unsigned short*)(ws + (144ull<<20));  // 16 MiB

  // 1) converts
  k_convert<<<2048, 256, 0, stream>>>(x,    Xb,    (Bq*Sq*Dq)/4);
  k_convert<<<2048, 256, 0, stream>>>(Win,  Wb,    (E3q*Dq)/4);
  k_convert<<<1024, 256, 0, stream>>>(Wout, Woutb, (Dq*Dq)/4);
  // 2) QKV = X . Win^T + b_in   (M=4096, N=6144, K=2048): grid 32x24 = 768
  k_gemm_bt<0><<<768, 256, 0, stream>>>(Xb, Wb, b_in, QKVb, Bq*Sq, E3q, Dq);
  // 3) RoPE + qk RMS-norm (Q pre-scaled to log2 units) ; V transpose
  k_rope_qk<<<dim3(Sq/4, Hq, Bq), dim3(64,4), 0, stream>>>(QKVb, rp, qk_w, Qp, Kp);
  k_transpose_v<<<dim3(Sq/128, Bq*Hq), 256, 0, stream>>>(QKVb, Vt);
  // 4) causal flash attention (pair-balanced 1D grid)
  k_attn<<<512, 256, 0, stream>>>(Qp, Kp, Vt, Ar);
  // 5) out RMS-norm (in place on Ar)
  k_rmsnorm<<<Bq*Sq, 256, 0, stream>>>(Ar, out_w);
  // 6) Out = A . Wout^T + b_out  (M=4096, N=2048, K=2048): grid 32x8 = 256
  k_gemm_bt<1><<<256, 256, 0, stream>>>(Ar, Woutb, b_out, outp, Bq*Sq, Dq, Dq);
}

// Round 8
// 288.146 us; speedup vs baseline: 2.6219x; 1.0402x over previous
//
#include <hip/hip_runtime.h>
#include <cstdint>
#include <cstddef>

// Problem constants (B,S,D,H) = (2,2048,2048,16), DH=128
#define Bq  2
#define Sq  2048
#define Dq  2048
#define Hq  16
#define DHq 128
#define E3q 6144   // 3*D

typedef __attribute__((ext_vector_type(8))) short s16x8;   // 8 bf16 (4 VGPRs)
typedef __attribute__((ext_vector_type(4))) float f32x4;   // MFMA accumulator

__device__ __forceinline__ unsigned short f2bf(float f){
  union { float f; unsigned u; } v; v.f = f;
  unsigned r = v.u + 0x7FFFu + ((v.u >> 16) & 1u);   // round-to-nearest-even
  return (unsigned short)(r >> 16);
}
__device__ __forceinline__ float bf2f(unsigned short b){
  union { unsigned u; float f; } v; v.u = ((unsigned)b) << 16;
  return v.f;
}
// pack two f32 -> two bf16 in one op (no builtin on gfx950; T12 recipe)
__device__ __forceinline__ unsigned cvtpk_bf16(float lo, float hi){
  unsigned r;
  asm("v_cvt_pk_bf16_f32 %0, %1, %2" : "=v"(r) : "v"(lo), "v"(hi));
  return r;
}

// async global->LDS, 16B per lane. LDS dest must be wave-uniform base + lane*16.
__device__ __forceinline__ void gload_lds16(const void* g, void* l){
  __builtin_amdgcn_global_load_lds(
      (const __attribute__((address_space(1))) void*)g,
      (__attribute__((address_space(3))) void*)l, 16, 0, 0);
}

// ---------------- fp32 -> bf16 convert (vectorized x4) ----------------
__global__ __launch_bounds__(256) void k_convert(const float* __restrict__ in,
                                                 unsigned short* __restrict__ out, int n4){
  int stride = gridDim.x * blockDim.x;
  for (int i = blockIdx.x*blockDim.x + threadIdx.x; i < n4; i += stride){
    float4 v = reinterpret_cast<const float4*>(in)[i];
    ushort4 o;
    o.x = f2bf(v.x); o.y = f2bf(v.y); o.z = f2bf(v.z); o.w = f2bf(v.w);
    reinterpret_cast<ushort4*>(out)[i] = o;
  }
}

// ---------------- GEMM1: 8-phase 128x384 bf16 B^T GEMM ----------------------
// C[m,n] = sum_k A[m,k]*Bt[n,k] + bias[n], M=4096 N=6144 K=2048, bf16 out.
// 512 threads (8 waves 2m x 4n), per-wave 64x96 (4 mf x 6 nf), K-tile 64.
// LDS 128KB: 2 bufs x {A 128x64 (2 k-halves of 8KB), B 384x64 (2 k-halves of
// 24KB = 3 x 8KB units)}. 16 iters x 8 phases; per phase: ds_read frags +
// stage 2 x 8KB units (1 gload_lds/thread each) -> barrier -> 12 MFMA ->
// barrier. Stage schedule (derived race-free; each unit staged >=1 phase
// after its region's last ds_read):
//   P1: Ak1(T1), Bk1(T1)u0   P2: Bk1(T1)u1,u2
//   P3: Ak0(T0+2), Bk0(T0+2)u0   P4: Bk0(T0+2)u1,u2 + vmcnt(4)
//   P5: Ak1(T0+2), Bk1(T0+2)u0   P6: Bk1(T0+2)u1,u2
//   P7: Ak0(T1+2), Bk0(T1+2)u0   P8: Bk0(T1+2)u1,u2 + vmcnt(4)
// vmcnt(4) leaves only the 2 newest stage-pairs outstanding; every unit read
// in the next 4 phases is older => landed. Swizzle: chunk pc ^ ((row>>1)&3)
// (pre-swizzled global source, linear LDS dest, swizzled read; 2-way = free).
__global__ __launch_bounds__(512, 1) void k_gemm1_8ph(const unsigned short* __restrict__ A,
                                                      const unsigned short* __restrict__ Bt,
                                                      const float* __restrict__ bias,
                                                      unsigned short* __restrict__ C){
  const int K = 2048, N = 6144;
  const int bid = blockIdx.x;
  const int xcd = bid & 7, u = bid >> 3;          // 512 blocks, 64 per XCD
  const int m0 = (xcd*4 + (u & 3)) * 128;         // 32 M-tiles, 4 per XCD
  const int n0 = (u >> 2) * 384;                  // 16 N-tiles, col-major in chunk

  const int tid = threadIdx.x;
  const int lane = tid & 63, w = tid >> 6, g = lane >> 4, c = lane & 15;
  const int wm = w >> 2, wn = w & 3;              // 2 x 4 waves

  __shared__ __align__(16) unsigned short L[65536];   // 128 KB

  // ---- staging bases (1 chunk of 16B per thread per unit) ----
  const int srow = tid >> 2, spc = tid & 3;
  const int ssw = (spc ^ ((srow >> 1) & 3)) << 3;
  const unsigned short* aSrc  = A  + (size_t)(m0 + srow      )*K + ssw;
  const unsigned short* bSrc0 = Bt + (size_t)(n0 + srow      )*K + ssw;
  const unsigned short* bSrc1 = Bt + (size_t)(n0 + srow + 128)*K + ssw;
  const unsigned short* bSrc2 = Bt + (size_t)(n0 + srow + 256)*K + ssw;

  auto stA = [&](int t, int h){
    gload_lds16(aSrc + t*64 + h*32, &L[((t&1)*2 + h)*4096 + tid*8]);
  };
  auto stB = [&](int t, int h, int uu){
    const unsigned short* s = (uu==0) ? bSrc0 : (uu==1) ? bSrc1 : bSrc2;
    gload_lds16(s + t*64 + h*32, &L[16384 + ((t&1)*2 + h)*12288 + uu*4096 + tid*8]);
  };

  // ---- fragment read offsets (swizzled) ----
  int aoff[4], boff[6];
#pragma unroll
  for (int mf=0; mf<4; ++mf){
    int row = wm*64 + mf*16 + c;
    aoff[mf] = row*32 + ((g ^ ((row>>1)&3)) << 3);
  }
#pragma unroll
  for (int nf=0; nf<6; ++nf){
    int row = wn*96 + nf*16 + c;
    boff[nf] = row*32 + ((g ^ ((row>>1)&3)) << 3);
  }

  f32x4 acc[4][6];
#pragma unroll
  for (int i=0;i<4;i++)
#pragma unroll
    for (int j=0;j<6;j++)
#pragma unroll
      for (int r=0;r<4;r++) acc[i][j][r] = 0.f;

  auto RDA = [&](int b, int h, s16x8* af){
    const int ab = (b*2 + h)*4096;
#pragma unroll
    for (int mf=0; mf<4; ++mf) af[mf] = *(const s16x8*)&L[ab + aoff[mf]];
  };
  auto RDB = [&](int b, int h, int nh, s16x8* bf){
    const int bb = 16384 + (b*2 + h)*12288;
#pragma unroll
    for (int j=0; j<3; ++j) bf[j] = *(const s16x8*)&L[bb + boff[nh*3 + j]];
  };
  auto MM = [&](s16x8* af, s16x8* bf, int nh){
    __builtin_amdgcn_s_setprio(1);
#pragma unroll
    for (int mf=0; mf<4; ++mf)
#pragma unroll
      for (int j=0; j<3; ++j)
        acc[mf][nh*3+j] = __builtin_amdgcn_mfma_f32_16x16x32_bf16(af[mf], bf[j], acc[mf][nh*3+j], 0,0,0);
    __builtin_amdgcn_s_setprio(0);
  };
  auto BAR = [&](){
    __builtin_amdgcn_sched_barrier(0);
    __builtin_amdgcn_s_barrier();
    __builtin_amdgcn_sched_barrier(0);
  };

  // ---- prologue: tile0 (8 units) + tile1 k0 (4 units) ----
  stA(0,0); stB(0,0,0); stB(0,0,1); stB(0,0,2);
  stA(0,1); stB(0,1,0); stB(0,1,1); stB(0,1,2);
  stA(1,0); stB(1,0,0); stB(1,0,1); stB(1,0,2);
  asm volatile("s_waitcnt vmcnt(4)" ::: "memory");   // tile0 fully landed
  __builtin_amdgcn_s_barrier();

  for (int i=0; i<16; ++i){
    const int T0 = 2*i, T1 = 2*i + 1;
    const bool st = (i < 15);
    s16x8 af[4], bf[3];
    // P1: (buf0,k0,nh0)
    RDA(0,0,af); RDB(0,0,0,bf);
    stA(T1,1); stB(T1,1,0);
    BAR(); MM(af,bf,0); BAR();
    // P2: (buf0,k0,nh1) — A reused
    RDB(0,0,1,bf);
    stB(T1,1,1); stB(T1,1,2);
    BAR(); MM(af,bf,1); BAR();
    // P3: (buf0,k1,nh0)
    RDA(0,1,af); RDB(0,1,0,bf);
    if (st){ stA(T0+2,0); stB(T0+2,0,0); }
    BAR(); MM(af,bf,0); BAR();
    // P4: (buf0,k1,nh1) + checkpoint
    RDB(0,1,1,bf);
    if (st){ stB(T0+2,0,1); stB(T0+2,0,2); }
    __builtin_amdgcn_sched_barrier(0);
    if (st) asm volatile("s_waitcnt vmcnt(4)" ::: "memory");
    else    asm volatile("s_waitcnt vmcnt(0)" ::: "memory");
    BAR(); MM(af,bf,1); BAR();
    // P5: (buf1,k0,nh0)
    RDA(1,0,af); RDB(1,0,0,bf);
    if (st){ stA(T0+2,1); stB(T0+2,1,0); }
    BAR(); MM(af,bf,0); BAR();
    // P6: (buf1,k0,nh1)
    RDB(1,0,1,bf);
    if (st){ stB(T0+2,1,1); stB(T0+2,1,2); }
    BAR(); MM(af,bf,1); BAR();
    // P7: (buf1,k1,nh0)
    RDA(1,1,af); RDB(1,1,0,bf);
    if (st){ stA(T1+2,0); stB(T1+2,0,0); }
    BAR(); MM(af,bf,0); BAR();
    // P8: (buf1,k1,nh1) + checkpoint
    RDB(1,1,1,bf);
    if (st){ stB(T1+2,0,1); stB(T1+2,0,2); }
    __builtin_amdgcn_sched_barrier(0);
    if (st) asm volatile("s_waitcnt vmcnt(4)" ::: "memory");
    else    asm volatile("s_waitcnt vmcnt(0)" ::: "memory");
    BAR(); MM(af,bf,1); BAR();
  }

  // ---- epilogue ----
#pragma unroll
  for (int nf=0; nf<6; ++nf){
    const int col = n0 + wn*96 + nf*16 + c;
    const float bv = bias[col];
#pragma unroll
    for (int mf=0; mf<4; ++mf){
      const int row = m0 + wm*64 + mf*16 + g*4;
#pragma unroll
      for (int r=0; r<4; ++r)
        C[(size_t)(row+r)*N + col] = f2bf(acc[mf][nf][r] + bv);
    }
  }
}

// ---------------- bf16 B^T GEMM, fat-wave ring-3 (GEMM2) --------------------
template<int F32OUT>
__global__ __launch_bounds__(256, 2) void k_gemm_bt(const unsigned short* __restrict__ A,
                                                    const unsigned short* __restrict__ Bt,
                                                    const float* __restrict__ bias,
                                                    void* __restrict__ C,
                                                    int M, int N, int K){
  const int bid = blockIdx.x;
  const int xcd = bid & 7, u = bid >> 3;
  const int by = xcd*4 + (u & 3);
  const int bx = u >> 2;
  const int m0 = by * 128, n0 = bx * 256;

  const int tid = threadIdx.x;
  const int w = tid >> 6, lane = tid & 63, g = lane >> 4, c = lane & 15;

  __shared__ __align__(16) unsigned short L[3 * 12288];   // 72 KB ring-3

  const int NT = K >> 5;

  const int r0 = tid >> 2, pc = tid & 3;
  const unsigned short* Ab0 = &A [(size_t)(m0 + r0      )*K + (size_t)((pc ^ (((r0      )>>1)&3))*8)];
  const unsigned short* Ab1 = &A [(size_t)(m0 + r0 +  64)*K + (size_t)((pc ^ (((r0 + 64)>>1)&3))*8)];
  const unsigned short* Bb0 = &Bt[(size_t)(n0 + r0      )*K + (size_t)((pc ^ (((r0      )>>1)&3))*8)];
  const unsigned short* Bb1 = &Bt[(size_t)(n0 + r0 +  64)*K + (size_t)((pc ^ (((r0 + 64)>>1)&3))*8)];
  const unsigned short* Bb2 = &Bt[(size_t)(n0 + r0 + 128)*K + (size_t)((pc ^ (((r0 +128)>>1)&3))*8)];
  const unsigned short* Bb3 = &Bt[(size_t)(n0 + r0 + 192)*K + (size_t)((pc ^ (((r0 +192)>>1)&3))*8)];

  auto stage = [&](int tile, int slot){
    const int kt = tile << 5;
    unsigned short* Ls = &L[slot * 12288];
    gload_lds16(Ab0 + kt, &Ls[tid*8]);
    gload_lds16(Ab1 + kt, &Ls[(tid+256)*8]);
    gload_lds16(Bb0 + kt, &Ls[4096 + tid*8]);
    gload_lds16(Bb1 + kt, &Ls[4096 + (tid+256)*8]);
    gload_lds16(Bb2 + kt, &Ls[4096 + (tid+512)*8]);
    gload_lds16(Bb3 + kt, &Ls[4096 + (tid+768)*8]);
  };

  f32x4 acc[8][4];
#pragma unroll
  for (int i=0;i<8;i++)
#pragma unroll
    for (int j=0;j<4;j++)
#pragma unroll
      for (int r=0;r<4;r++) acc[i][j][r] = 0.f;

  int aoff[8], boff[4];
#pragma unroll
  for (int mi=0;mi<8;mi++){
    int row = mi*16 + c;
    aoff[mi] = row*32 + ((g ^ ((row>>1)&3)) << 3);
  }
#pragma unroll
  for (int ni=0;ni<4;ni++){
    int row = w*64 + ni*16 + c;
    boff[ni] = 4096 + row*32 + ((g ^ ((row>>1)&3)) << 3);
  }

  stage(0,0); stage(1,1);

  int slot = 0;
  for (int t = 0; t < NT; ++t){
    if (t < NT-1) asm volatile("s_waitcnt vmcnt(6)" ::: "memory");
    else          asm volatile("s_waitcnt vmcnt(0)" ::: "memory");
    __builtin_amdgcn_s_barrier();
    __builtin_amdgcn_sched_barrier(0);
    if (t+2 < NT) stage(t+2, slot == 0 ? 2 : slot-1);

    const unsigned short* Ls = &L[slot * 12288];
    s16x8 bfr[4];
#pragma unroll
    for (int ni=0;ni<4;ni++) bfr[ni] = *(const s16x8*)&Ls[boff[ni]];
    __builtin_amdgcn_s_setprio(1);
#pragma unroll
    for (int mi=0;mi<8;mi++){
      s16x8 af = *(const s16x8*)&Ls[aoff[mi]];
#pragma unroll
      for (int ni=0;ni<4;ni++)
        acc[mi][ni] = __builtin_amdgcn_mfma_f32_16x16x32_bf16(af, bfr[ni], acc[mi][ni], 0,0,0);
    }
    __builtin_amdgcn_s_setprio(0);
    slot = (slot == 2) ? 0 : slot+1;
  }

#pragma unroll
  for (int ni=0;ni<4;ni++){
    const int col = n0 + w*64 + ni*16 + c;
    const float bv = bias[col];
#pragma unroll
    for (int mi=0;mi<8;mi++){
      const int row = m0 + mi*16 + g*4;
#pragma unroll
      for (int r=0;r<4;r++){
        float v = acc[mi][ni][r] + bv;
        if (F32OUT) ((float*)C)[(size_t)(row+r)*N + col] = v;
        else ((unsigned short*)C)[(size_t)(row+r)*N + col] = f2bf(v);
      }
    }
  }
}

// ---------------- RoPE + qk RMS-norm for Q,K only --------------------------
__global__ __launch_bounds__(256) void k_rope_qk(const unsigned short* __restrict__ QKV,
                                                 const float* __restrict__ rp,
                                                 const float* __restrict__ qk_w,
                                                 unsigned short* __restrict__ Qp,
                                                 unsigned short* __restrict__ Kp){
  const int p = threadIdx.x;
  const int s = blockIdx.x*4 + threadIdx.y;
  const int h = blockIdx.y;
  const int b = blockIdx.z;
  const size_t n = (size_t)b*Sq + s;
  const int bh = b*Hq + h;

  float ang = rp[s*64 + p];
  float sn, cs; sincosf(ang, &sn, &cs);
  float w0 = qk_w[2*p], w1 = qk_w[2*p+1];
  const float QSCALE = 0.08838834764831845f * 1.4426950408889634f; // 1/sqrt(128)*log2e

  {
    unsigned q01 = *(const unsigned*)&QKV[n*E3q + h*DHq + 2*p];
    float x0 = bf2f((unsigned short)(q01 & 0xFFFFu));
    float x1 = bf2f((unsigned short)(q01 >> 16));
    float r0 = x0*cs - x1*sn, r1 = x0*sn + x1*cs;
    float ss = r0*r0 + r1*r1;
#pragma unroll
    for (int m=1;m<64;m<<=1) ss += __shfl_xor(ss, m);
    float sc = rsqrtf(ss/128.f + 1e-6f) * QSCALE;
    unsigned short o0 = f2bf(r0*sc*w0), o1 = f2bf(r1*sc*w1);
    *(unsigned*)&Qp[((size_t)bh*Sq + s)*DHq + 2*p] = (unsigned)o0 | ((unsigned)o1<<16);
  }
  {
    unsigned k01 = *(const unsigned*)&QKV[n*E3q + Dq + h*DHq + 2*p];
    float x0 = bf2f((unsigned short)(k01 & 0xFFFFu));
    float x1 = bf2f((unsigned short)(k01 >> 16));
    float r0 = x0*cs - x1*sn, r1 = x0*sn + x1*cs;
    float ss = r0*r0 + r1*r1;
#pragma unroll
    for (int m=1;m<64;m<<=1) ss += __shfl_xor(ss, m);
    float sc = rsqrtf(ss/128.f + 1e-6f);
    unsigned short o0 = f2bf(r0*sc*w0), o1 = f2bf(r1*sc*w1);
    *(unsigned*)&Kp[((size_t)bh*Sq + s)*DHq + 2*p] = (unsigned)o0 | ((unsigned)o1<<16);
  }
}

// ---------------- V transpose via LDS: QKV[s][v-part] -> Vt[bh][dh][s] ------
__global__ __launch_bounds__(256) void k_transpose_v(const unsigned short* __restrict__ QKV,
                                                     unsigned short* __restrict__ Vt){
  const int sblk = blockIdx.x;
  const int bh = blockIdx.y;
  const int b = bh >> 4, h = bh & 15;
  const int tid = threadIdx.x;
  __shared__ unsigned short T[128][136];

  const size_t base = ((size_t)(b*Sq) + sblk*128) * E3q + 2*(size_t)Dq + h*DHq;
#pragma unroll
  for (int i=0;i<8;i++){
    int pk = tid + i*256;
    int row = pk >> 4, cc = (pk & 15) * 8;
    s16x8 v = *(const s16x8*)&QKV[base + (size_t)row*E3q + cc];
    *(s16x8*)&T[row][cc] = v;
  }
  __syncthreads();
  const int dh = tid >> 1, sh = (tid & 1) * 64;
  unsigned short buf[64];
#pragma unroll
  for (int s=0;s<64;s++) buf[s] = T[sh + s][dh];
  size_t obase = ((size_t)bh*DHq + dh)*Sq + sblk*128 + sh;
#pragma unroll
  for (int i=0;i<8;i++)
    *(s16x8*)&Vt[obase + i*8] = *(const s16x8*)&buf[i*8];
}

// ---------------- causal MFMA flash attention (swapped-operand) -------------
__global__ __launch_bounds__(256, 2) void k_attn(const unsigned short* __restrict__ Qp,
                                                 const unsigned short* __restrict__ Kp,
                                                 const unsigned short* __restrict__ Vt,
                                                 unsigned short* __restrict__ Ar){
  const int L = blockIdx.x;
  int bh, qtile;
  if (L < 256){ bh = L >> 3; qtile = 8 + (L & 7); }
  else { int Ml = L - 256; bh = Ml >> 3; qtile = 7 - (Ml & 7); }
  const int b = bh >> 4, h = bh & 15;
  const int tid = threadIdx.x;
  const int w = tid >> 6, lane = tid & 63, g = lane >> 4, c = lane & 15;
  const int r0w = qtile*128 + w*32;

  const unsigned short* Qh = Qp + (size_t)bh * Sq * DHq;
  const unsigned short* Kh = Kp + (size_t)bh * Sq * DHq;
  const unsigned short* Vh = Vt + (size_t)bh * DHq * Sq;

  __shared__ __align__(16) unsigned short Ks[2][64*128];   // 32 KB
  __shared__ __align__(16) unsigned short Vs[2][128*64];   // 32 KB
  __shared__ __align__(16) unsigned short Pl[4][32*64];    // 16 KB  (per-wave [q][k])
  unsigned short* Pw = &Pl[w][0];

  s16x8 qf[2][4];
#pragma unroll
  for (int mi=0;mi<2;mi++)
#pragma unroll
    for (int kc=0;kc<4;kc++)
      qf[mi][kc] = *(const s16x8*)&Qh[(size_t)(r0w + mi*16 + c)*DHq + kc*32 + g*8];

  f32x4 acc[2][8];
#pragma unroll
  for (int mi=0;mi<2;mi++)
#pragma unroll
    for (int dt=0;dt<8;dt++)
#pragma unroll
      for (int r=0;r<4;r++) acc[mi][dt][r] = 0.f;
  float m_r[2] = { -INFINITY, -INFINITY };
  float l_p[2] = { 0.f, 0.f };             // per-lane PARTIAL sums

  const int nsteps = 2*qtile + 2;

  auto stage = [&](int j0s, int bufi){
#pragma unroll
    for (int i=0;i<4;i++){
      int pk = tid + i*256;              // K: 1024 chunks of 16B
      int row = pk>>4, pcc = pk&15;
      gload_lds16(&Kh[(size_t)(j0s+row)*DHq + ((pcc^(row&7))<<3)], &Ks[bufi][pk*8]);
    }
#pragma unroll
    for (int i=0;i<4;i++){
      int pk = tid + i*256;              // V: 1024 chunks of 16B
      int row = pk>>3, pcc = pk&7;
      gload_lds16(&Vh[(size_t)row*Sq + j0s + ((pcc^(row&7))<<3)], &Vs[bufi][pk*8]);
    }
  };

  stage(0, 0);
  __syncthreads();

  for (int t=0; t<nsteps; ++t){
    const int j0 = t*64;
    if (t+1 < nsteps) stage((t+1)*64, (t+1)&1);

    if (j0 <= r0w + 31){
      const unsigned short* Kc = &Ks[t&1][0];
      const unsigned short* Vc = &Vs[t&1][0];

      // ---- S^T = K.Q^T : sv[mi][js][r] = S[q=c+mi*16][k=j0+js*16+g*4+r] ----
      f32x4 sv[2][4];
#pragma unroll
      for (int mi=0;mi<2;mi++)
#pragma unroll
        for (int js=0;js<4;js++)
#pragma unroll
          for (int r=0;r<4;r++) sv[mi][js][r] = 0.f;

      __builtin_amdgcn_s_setprio(1);
#pragma unroll
      for (int js=0;js<4;js++){
        s16x8 kf[4];
#pragma unroll
        for (int kc=0;kc<4;kc++)
          kf[kc] = *(const s16x8*)&Kc[(js*16 + c)*128 + (((kc*4+g)^(c&7))<<3)];
#pragma unroll
        for (int mi=0;mi<2;mi++)
#pragma unroll
          for (int kc=0;kc<4;kc++)
            sv[mi][js] = __builtin_amdgcn_mfma_f32_16x16x32_bf16(kf[kc], qf[mi][kc], sv[mi][js], 0,0,0);
      }
      __builtin_amdgcn_s_setprio(0);

      // ---- causal mask (diag steps only) ----
      if (j0 + 63 > r0w){
#pragma unroll
        for (int mi=0;mi<2;mi++){
          const int q = r0w + mi*16 + c;
#pragma unroll
          for (int js=0;js<4;js++)
#pragma unroll
            for (int r=0;r<4;r++)
              if (j0 + js*16 + g*4 + r > q) sv[mi][js][r] = -INFINITY;
        }
      }

      // ---- lane-local max; cross-lane over g-groups only ----
      float pmx[2];
#pragma unroll
      for (int mi=0;mi<2;mi++){
        float mx = fmaxf(fmaxf(sv[mi][0][0],sv[mi][0][1]), fmaxf(sv[mi][0][2],sv[mi][0][3]));
#pragma unroll
        for (int js=1;js<4;js++){
          float a = fmaxf(fmaxf(sv[mi][js][0],sv[mi][js][1]), fmaxf(sv[mi][js][2],sv[mi][js][3]));
          mx = fmaxf(mx, a);
        }
        mx = fmaxf(mx, __shfl_xor(mx, 16));
        mx = fmaxf(mx, __shfl_xor(mx, 32));
        pmx[mi] = mx;
      }
      // ---- defer-max rescale ----
      int need = (pmx[0] > m_r[0] + 8.f) | (pmx[1] > m_r[1] + 8.f);
      if (__any(need)){
#pragma unroll
        for (int mi=0;mi<2;mi++){
          float mnew = fmaxf(m_r[mi], pmx[mi]);
          float corr = exp2f(m_r[mi] - mnew);
          l_p[mi] *= corr;
          m_r[mi] = mnew;
#pragma unroll
          for (int dt=0;dt<8;dt++)
#pragma unroll
            for (int r=0;r<4;r++) acc[mi][dt][r] *= corr;
        }
      }
      // ---- exp2, per-lane partial sum, packed P^T -> LDS [q][k] ----
#pragma unroll
      for (int mi=0;mi<2;mi++){
        const float mm = m_r[mi];
        const int rowoff = (mi*16 + c)*64;
#pragma unroll
        for (int js=0;js<4;js++){
          float e0 = exp2f(sv[mi][js][0] - mm);
          float e1 = exp2f(sv[mi][js][1] - mm);
          float e2 = exp2f(sv[mi][js][2] - mm);
          float e3 = exp2f(sv[mi][js][3] - mm);
          l_p[mi] += (e0+e1)+(e2+e3);
          uint2 pk2;
          pk2.x = cvtpk_bf16(e0, e1);
          pk2.y = cvtpk_bf16(e2, e3);
          const int kc8 = js*2 + (g>>1);
          *(uint2*)&Pw[rowoff + ((kc8 ^ (c&7))<<3) + (g&1)*4] = pk2;
        }
      }

      // ---- O^T += V^T (128x64) . P^T (64x32) ----
      s16x8 pfr[2][2];
#pragma unroll
      for (int mi=0;mi<2;mi++)
#pragma unroll
        for (int kc=0;kc<2;kc++)
          pfr[mi][kc] = *(const s16x8*)&Pw[(mi*16 + c)*64 + (((kc*4+g)^(c&7))<<3)];
      __builtin_amdgcn_s_setprio(1);
#pragma unroll
      for (int dt=0; dt<8; dt++){
#pragma unroll
        for (int kc=0;kc<2;kc++){
          s16x8 vfr = *(const s16x8*)&Vc[(dt*16 + c)*64 + (((kc*4+g)^(c&7))<<3)];
#pragma unroll
          for (int mi=0;mi<2;mi++)
            acc[mi][dt] = __builtin_amdgcn_mfma_f32_16x16x32_bf16(vfr, pfr[mi][kc], acc[mi][dt], 0,0,0);
        }
      }
      __builtin_amdgcn_s_setprio(0);
    }
    __syncthreads();
  }

  // ---- epilogue: reduce l across g-groups, normalize, write O^T ----
#pragma unroll
  for (int mi=0;mi<2;mi++){
    float l = l_p[mi];
    l += __shfl_xor(l, 16);
    l += __shfl_xor(l, 32);
    const float inv = 1.f / l;
    const int row = r0w + mi*16 + c;
    unsigned short* dst = &Ar[((size_t)(b*Sq + row))*Dq + h*DHq];
#pragma unroll
    for (int dt=0; dt<8; dt++){
      uint2 o2;
      o2.x = cvtpk_bf16(acc[mi][dt][0]*inv, acc[mi][dt][1]*inv);
      o2.y = cvtpk_bf16(acc[mi][dt][2]*inv, acc[mi][dt][3]*inv);
      *(uint2*)&dst[dt*16 + g*4] = o2;
    }
  }
}

// ---------------- row RMS-norm over D=2048, in place -----------------------
__global__ __launch_bounds__(256) void k_rmsnorm(unsigned short* __restrict__ A,
                                                 const float* __restrict__ w){
  const int row = blockIdx.x;
  const int tid = threadIdx.x;
  s16x8 v = *(const s16x8*)&A[(size_t)row*Dq + tid*8];
  float f[8]; float ss = 0.f;
#pragma unroll
  for (int i=0;i<8;i++){ f[i] = bf2f((unsigned short)v[i]); ss += f[i]*f[i]; }
#pragma unroll
  for (int m=1;m<64;m<<=1) ss += __shfl_xor(ss, m);
  __shared__ float red[4];
  if ((tid&63)==0) red[tid>>6] = ss;
  __syncthreads();
  ss = red[0]+red[1]+red[2]+red[3];
  float sc = rsqrtf(ss/2048.f + 1e-6f);
  unsigned short o[8];
#pragma unroll
  for (int i=0;i<8;i++) o[i] = f2bf(f[i]*sc*w[tid*8+i]);
  *(s16x8*)&A[(size_t)row*Dq + tid*8] = *(const s16x8*)o;
}

extern "C" void kernel_launch(void* const* d_in, const int* in_sizes, int n_in,
                              void* d_out, int out_size, void* d_ws, size_t ws_size,
                              hipStream_t stream){
  const float* x     = (const float*)d_in[0];
  const float* rp    = (const float*)d_in[1];
  const float* Win   = (const float*)d_in[2];
  const float* b_in  = (const float*)d_in[3];
  const float* Wout  = (const float*)d_in[4];
  const float* b_out = (const float*)d_in[5];
  const float* qk_w  = (const float*)d_in[6];
  const float* out_w = (const float*)d_in[7];
  float* outp = (float*)d_out;

  if (ws_size < (160ull<<20)) return;   // need 160 MiB scratch

  char* ws = (char*)d_ws;
  unsigned short* Xb    = (unsigned short*)(ws);                 // 16 MiB
  unsigned short* Wb    = (unsigned short*)(ws + (16ull<<20));   // 24 MiB
  unsigned short* Woutb = (unsigned short*)(ws + (40ull<<20));   //  8 MiB
  unsigned short* QKVb  = (unsigned short*)(ws + (48ull<<20));   // 48 MiB
  unsigned short* Qp    = (unsigned short*)(ws + (96ull<<20));   // 16 MiB
  unsigned short* Kp    = (unsigned short*)(ws + (112ull<<20));  // 16 MiB
  unsigned short* Vt    = (unsigned short*)(ws + (128ull<<20));  // 16 MiB
  unsigned short* Ar    = (unsigned short*)(ws + (144ull<<20));  // 16 MiB

  // 1) converts
  k_convert<<<2048, 256, 0, stream>>>(x,    Xb,    (Bq*Sq*Dq)/4);
  k_convert<<<2048, 256, 0, stream>>>(Win,  Wb,    (E3q*Dq)/4);
  k_convert<<<1024, 256, 0, stream>>>(Wout, Woutb, (Dq*Dq)/4);
  // 2) QKV = X . Win^T + b_in  (M=4096, N=6144, K=2048): 8-phase, 512 blocks
  k_gemm1_8ph<<<512, 512, 0, stream>>>(Xb, Wb, b_in, QKVb);
  // 3) RoPE + qk RMS-norm (Q pre-scaled to log2 units) ; V transpose
  k_rope_qk<<<dim3(Sq/4, Hq, Bq), dim3(64,4), 0, stream>>>(QKVb, rp, qk_w, Qp, Kp);
  k_transpose_v<<<dim3(Sq/128, Bq*Hq), 256, 0, stream>>>(QKVb, Vt);
  // 4) causal flash attention (pair-balanced 1D grid)
  k_attn<<<512, 256, 0, stream>>>(Qp, Kp, Vt, Ar);
  // 5) out RMS-norm (in place on Ar)
  k_rmsnorm<<<Bq*Sq, 256, 0, stream>>>(Ar, out_w);
  // 6) Out = A . Wout^T + b_out  (M=4096, N=2048, K=2048): grid 32x8 = 256
  k_gemm_bt<1><<<256, 256, 0, stream>>>(Ar, Woutb, b_out, outp, Bq*Sq, Dq, Dq);
}

// Round 9
// 284.251 us; speedup vs baseline: 2.6578x; 1.0137x over previous
//
#include <hip/hip_runtime.h>
#include <cstdint>
#include <cstddef>

// Problem constants (B,S,D,H) = (2,2048,2048,16), DH=128
#define Bq  2
#define Sq  2048
#define Dq  2048
#define Hq  16
#define DHq 128
#define E3q 6144   // 3*D

typedef __attribute__((ext_vector_type(8))) short s16x8;   // 8 bf16 (4 VGPRs)
typedef __attribute__((ext_vector_type(4))) float f32x4;   // MFMA accumulator

__device__ __forceinline__ unsigned short f2bf(float f){
  union { float f; unsigned u; } v; v.f = f;
  unsigned r = v.u + 0x7FFFu + ((v.u >> 16) & 1u);   // round-to-nearest-even
  return (unsigned short)(r >> 16);
}
__device__ __forceinline__ float bf2f(unsigned short b){
  union { unsigned u; float f; } v; v.u = ((unsigned)b) << 16;
  return v.f;
}
// pack two f32 -> two bf16 in one op (no builtin on gfx950; T12 recipe)
__device__ __forceinline__ unsigned cvtpk_bf16(float lo, float hi){
  unsigned r;
  asm("v_cvt_pk_bf16_f32 %0, %1, %2" : "=v"(r) : "v"(lo), "v"(hi));
  return r;
}

// async global->LDS, 16B per lane. LDS dest must be wave-uniform base + lane*16.
__device__ __forceinline__ void gload_lds16(const void* g, void* l){
  __builtin_amdgcn_global_load_lds(
      (const __attribute__((address_space(1))) void*)g,
      (__attribute__((address_space(3))) void*)l, 16, 0, 0);
}

// ---------------- fp32 -> bf16 convert (vectorized x4) ----------------
__global__ __launch_bounds__(256) void k_convert(const float* __restrict__ in,
                                                 unsigned short* __restrict__ out, int n4){
  int stride = gridDim.x * blockDim.x;
  for (int i = blockIdx.x*blockDim.x + threadIdx.x; i < n4; i += stride){
    float4 v = reinterpret_cast<const float4*>(in)[i];
    ushort4 o;
    o.x = f2bf(v.x); o.y = f2bf(v.y); o.z = f2bf(v.z); o.w = f2bf(v.w);
    reinterpret_cast<ushort4*>(out)[i] = o;
  }
}

// ---------------- GEMM1 v2: 256x384 tile, 2-phase/K-32-tile, ring-3 ---------
// C[m,n] = sum_k A[m,k]*Bt[n,k] + bias[n], M=4096 N=6144 K=2048, bf16 out.
// Grid 256 (16 Mtiles x 16 Ntiles) = exactly 1 block/CU. 512 threads,
// 8 waves (2m x 4n), per-wave 128x96 = 8mf x 6nf (acc 192 VGPR; lb(512,2)
// caps allocation at 256). K-tile 32; LDS ring-3 x 40KB = 120KB (per buf:
// A 256x32 @0, B 384x32 @8192). Stage = 5 units/tile (1 gload/thread each).
// Per tile two phases:
//  P0: read B x6 + A(mf0-3) x4, stage 3 units of t+2, bar, 24 MFMA, bar
//  P1: read A(mf4-7) x4,        stage 2 units of t+2, bar, 24 MFMA,
//      vmcnt(5) [t<62; else 0], bar
// Ring-3 race-freedom: buf(t+2)%3 last read in tile t-1 P1 (before its end
// barrier); stage of t+2 issues in tile t (after that barrier). vmcnt(5) at
// tile t end waits tile t+1's 5 units (only t+2's 5 newer outstanding);
// lead ~2 phases (~1500cy) > HBM latency. Swizzle as before (0 conflicts).
__global__ __launch_bounds__(512, 2) void k_gemm1_8ph(const unsigned short* __restrict__ A,
                                                      const unsigned short* __restrict__ Bt,
                                                      const float* __restrict__ bias,
                                                      unsigned short* __restrict__ C){
  const int K = 2048, N = 6144, NT = 64;
  const int bid = blockIdx.x;
  const int xcd = bid & 7, u = bid >> 3;          // 32 blocks per XCD
  const int m0 = (xcd*2 + (u & 1)) * 256;         // 16 M-tiles, 2 per XCD
  const int n0 = (u >> 1) * 384;                  // 16 N-tiles, col-major in chunk

  const int tid = threadIdx.x;
  const int lane = tid & 63, w = tid >> 6, g = lane >> 4, c = lane & 15;
  const int wm = w >> 2, wn = w & 3;              // 2m x 4n

  __shared__ __align__(16) unsigned short L[3 * 20480];   // 120 KB

  // staging bases (1 chunk of 16B per thread per unit); swizzle invariant
  // under row+128/+256 since 128>>1 = 64 ≡ 0 (mod 4)
  const int srow = tid >> 2;
  const int ssw = ((tid & 3) ^ ((srow >> 1) & 3)) * 8;
  const unsigned short* aS0 = A  + (size_t)(m0 + srow      )*K + ssw;
  const unsigned short* aS1 = A  + (size_t)(m0 + srow + 128)*K + ssw;
  const unsigned short* bS0 = Bt + (size_t)(n0 + srow      )*K + ssw;
  const unsigned short* bS1 = Bt + (size_t)(n0 + srow + 128)*K + ssw;
  const unsigned short* bS2 = Bt + (size_t)(n0 + srow + 256)*K + ssw;

  auto stX = [&](int t, int s){               // A unit0, A unit1, B unit0
    const int kt = t*32;
    unsigned short* Ls = &L[s*20480];
    gload_lds16(aS0 + kt, &Ls[tid*8]);
    gload_lds16(aS1 + kt, &Ls[4096 + tid*8]);
    gload_lds16(bS0 + kt, &Ls[8192 + tid*8]);
  };
  auto stY = [&](int t, int s){               // B unit1, B unit2
    const int kt = t*32;
    unsigned short* Ls = &L[s*20480];
    gload_lds16(bS1 + kt, &Ls[12288 + tid*8]);
    gload_lds16(bS2 + kt, &Ls[16384 + tid*8]);
  };

  // fragment read offsets (swizzled)
  int aoff[8], boff[6];
#pragma unroll
  for (int mf=0; mf<8; ++mf){
    int row = wm*128 + mf*16 + c;
    aoff[mf] = row*32 + ((g ^ ((row>>1)&3)) << 3);
  }
#pragma unroll
  for (int nf=0; nf<6; ++nf){
    int row = wn*96 + nf*16 + c;
    boff[nf] = 8192 + row*32 + ((g ^ ((row>>1)&3)) << 3);
  }

  f32x4 acc[8][6];
#pragma unroll
  for (int i=0;i<8;i++)
#pragma unroll
    for (int j=0;j<6;j++)
#pragma unroll
      for (int r=0;r<4;r++) acc[i][j][r] = 0.f;

  // prologue: stage tiles 0 and 1
  stX(0,0); stY(0,0); stX(1,1); stY(1,1);
  asm volatile("s_waitcnt vmcnt(5)" ::: "memory");   // tile 0 landed
  __builtin_amdgcn_s_barrier();

  int slot = 0;
  for (int t = 0; t < NT; ++t){
    const unsigned short* Ls = &L[slot * 20480];
    const bool st = (t+2 < NT);
    const int s2 = (slot == 0) ? 2 : slot-1;        // (t+2)%3

    // ---- phase 0 ----
    s16x8 bf[6], af[4];
#pragma unroll
    for (int nf=0;nf<6;nf++) bf[nf] = *(const s16x8*)&Ls[boff[nf]];
#pragma unroll
    for (int mf=0;mf<4;mf++) af[mf] = *(const s16x8*)&Ls[aoff[mf]];
    if (st) stX(t+2, s2);
    __builtin_amdgcn_s_barrier();
    __builtin_amdgcn_s_setprio(1);
#pragma unroll
    for (int mf=0;mf<4;mf++)
#pragma unroll
      for (int nf=0;nf<6;nf++)
        acc[mf][nf] = __builtin_amdgcn_mfma_f32_16x16x32_bf16(af[mf], bf[nf], acc[mf][nf], 0,0,0);
    __builtin_amdgcn_s_setprio(0);
    __builtin_amdgcn_s_barrier();

    // ---- phase 1 ----
#pragma unroll
    for (int mf=0;mf<4;mf++) af[mf] = *(const s16x8*)&Ls[aoff[4+mf]];
    if (st) stY(t+2, s2);
    __builtin_amdgcn_s_barrier();
    __builtin_amdgcn_s_setprio(1);
#pragma unroll
    for (int mf=0;mf<4;mf++)
#pragma unroll
      for (int nf=0;nf<6;nf++)
        acc[4+mf][nf] = __builtin_amdgcn_mfma_f32_16x16x32_bf16(af[mf], bf[nf], acc[4+mf][nf], 0,0,0);
    __builtin_amdgcn_s_setprio(0);
    if (t < NT-2) asm volatile("s_waitcnt vmcnt(5)" ::: "memory");
    else          asm volatile("s_waitcnt vmcnt(0)" ::: "memory");
    __builtin_amdgcn_s_barrier();
    slot = (slot == 2) ? 0 : slot+1;
  }

  // ---- epilogue ----
#pragma unroll
  for (int nf=0; nf<6; ++nf){
    const int col = n0 + wn*96 + nf*16 + c;
    const float bv = bias[col];
#pragma unroll
    for (int mf=0; mf<8; ++mf){
      const int row = m0 + wm*128 + mf*16 + g*4;
#pragma unroll
      for (int r=0; r<4; ++r)
        C[(size_t)(row+r)*N + col] = f2bf(acc[mf][nf][r] + bv);
    }
  }
}

// ---------------- bf16 B^T GEMM, fat-wave ring-3 (GEMM2) --------------------
template<int F32OUT>
__global__ __launch_bounds__(256, 2) void k_gemm_bt(const unsigned short* __restrict__ A,
                                                    const unsigned short* __restrict__ Bt,
                                                    const float* __restrict__ bias,
                                                    void* __restrict__ C,
                                                    int M, int N, int K){
  const int bid = blockIdx.x;
  const int xcd = bid & 7, u = bid >> 3;
  const int by = xcd*4 + (u & 3);
  const int bx = u >> 2;
  const int m0 = by * 128, n0 = bx * 256;

  const int tid = threadIdx.x;
  const int w = tid >> 6, lane = tid & 63, g = lane >> 4, c = lane & 15;

  __shared__ __align__(16) unsigned short L[3 * 12288];   // 72 KB ring-3

  const int NT = K >> 5;

  const int r0 = tid >> 2, pc = tid & 3;
  const unsigned short* Ab0 = &A [(size_t)(m0 + r0      )*K + (size_t)((pc ^ (((r0      )>>1)&3))*8)];
  const unsigned short* Ab1 = &A [(size_t)(m0 + r0 +  64)*K + (size_t)((pc ^ (((r0 + 64)>>1)&3))*8)];
  const unsigned short* Bb0 = &Bt[(size_t)(n0 + r0      )*K + (size_t)((pc ^ (((r0      )>>1)&3))*8)];
  const unsigned short* Bb1 = &Bt[(size_t)(n0 + r0 +  64)*K + (size_t)((pc ^ (((r0 + 64)>>1)&3))*8)];
  const unsigned short* Bb2 = &Bt[(size_t)(n0 + r0 + 128)*K + (size_t)((pc ^ (((r0 +128)>>1)&3))*8)];
  const unsigned short* Bb3 = &Bt[(size_t)(n0 + r0 + 192)*K + (size_t)((pc ^ (((r0 +192)>>1)&3))*8)];

  auto stage = [&](int tile, int slot){
    const int kt = tile << 5;
    unsigned short* Ls = &L[slot * 12288];
    gload_lds16(Ab0 + kt, &Ls[tid*8]);
    gload_lds16(Ab1 + kt, &Ls[(tid+256)*8]);
    gload_lds16(Bb0 + kt, &Ls[4096 + tid*8]);
    gload_lds16(Bb1 + kt, &Ls[4096 + (tid+256)*8]);
    gload_lds16(Bb2 + kt, &Ls[4096 + (tid+512)*8]);
    gload_lds16(Bb3 + kt, &Ls[4096 + (tid+768)*8]);
  };

  f32x4 acc[8][4];
#pragma unroll
  for (int i=0;i<8;i++)
#pragma unroll
    for (int j=0;j<4;j++)
#pragma unroll
      for (int r=0;r<4;r++) acc[i][j][r] = 0.f;

  int aoff[8], boff[4];
#pragma unroll
  for (int mi=0;mi<8;mi++){
    int row = mi*16 + c;
    aoff[mi] = row*32 + ((g ^ ((row>>1)&3)) << 3);
  }
#pragma unroll
  for (int ni=0;ni<4;ni++){
    int row = w*64 + ni*16 + c;
    boff[ni] = 4096 + row*32 + ((g ^ ((row>>1)&3)) << 3);
  }

  stage(0,0); stage(1,1);

  int slot = 0;
  for (int t = 0; t < NT; ++t){
    if (t < NT-1) asm volatile("s_waitcnt vmcnt(6)" ::: "memory");
    else          asm volatile("s_waitcnt vmcnt(0)" ::: "memory");
    __builtin_amdgcn_s_barrier();
    __builtin_amdgcn_sched_barrier(0);
    if (t+2 < NT) stage(t+2, slot == 0 ? 2 : slot-1);

    const unsigned short* Ls = &L[slot * 12288];
    s16x8 bfr[4];
#pragma unroll
    for (int ni=0;ni<4;ni++) bfr[ni] = *(const s16x8*)&Ls[boff[ni]];
    __builtin_amdgcn_s_setprio(1);
#pragma unroll
    for (int mi=0;mi<8;mi++){
      s16x8 af = *(const s16x8*)&Ls[aoff[mi]];
#pragma unroll
      for (int ni=0;ni<4;ni++)
        acc[mi][ni] = __builtin_amdgcn_mfma_f32_16x16x32_bf16(af, bfr[ni], acc[mi][ni], 0,0,0);
    }
    __builtin_amdgcn_s_setprio(0);
    slot = (slot == 2) ? 0 : slot+1;
  }

#pragma unroll
  for (int ni=0;ni<4;ni++){
    const int col = n0 + w*64 + ni*16 + c;
    const float bv = bias[col];
#pragma unroll
    for (int mi=0;mi<8;mi++){
      const int row = m0 + mi*16 + g*4;
#pragma unroll
      for (int r=0;r<4;r++){
        float v = acc[mi][ni][r] + bv;
        if (F32OUT) ((float*)C)[(size_t)(row+r)*N + col] = v;
        else ((unsigned short*)C)[(size_t)(row+r)*N + col] = f2bf(v);
      }
    }
  }
}

// ---------------- RoPE + qk RMS-norm for Q,K only --------------------------
__global__ __launch_bounds__(256) void k_rope_qk(const unsigned short* __restrict__ QKV,
                                                 const float* __restrict__ rp,
                                                 const float* __restrict__ qk_w,
                                                 unsigned short* __restrict__ Qp,
                                                 unsigned short* __restrict__ Kp){
  const int p = threadIdx.x;
  const int s = blockIdx.x*4 + threadIdx.y;
  const int h = blockIdx.y;
  const int b = blockIdx.z;
  const size_t n = (size_t)b*Sq + s;
  const int bh = b*Hq + h;

  float ang = rp[s*64 + p];
  float sn, cs; sincosf(ang, &sn, &cs);
  float w0 = qk_w[2*p], w1 = qk_w[2*p+1];
  const float QSCALE = 0.08838834764831845f * 1.4426950408889634f; // 1/sqrt(128)*log2e

  {
    unsigned q01 = *(const unsigned*)&QKV[n*E3q + h*DHq + 2*p];
    float x0 = bf2f((unsigned short)(q01 & 0xFFFFu));
    float x1 = bf2f((unsigned short)(q01 >> 16));
    float r0 = x0*cs - x1*sn, r1 = x0*sn + x1*cs;
    float ss = r0*r0 + r1*r1;
#pragma unroll
    for (int m=1;m<64;m<<=1) ss += __shfl_xor(ss, m);
    float sc = rsqrtf(ss/128.f + 1e-6f) * QSCALE;
    unsigned short o0 = f2bf(r0*sc*w0), o1 = f2bf(r1*sc*w1);
    *(unsigned*)&Qp[((size_t)bh*Sq + s)*DHq + 2*p] = (unsigned)o0 | ((unsigned)o1<<16);
  }
  {
    unsigned k01 = *(const unsigned*)&QKV[n*E3q + Dq + h*DHq + 2*p];
    float x0 = bf2f((unsigned short)(k01 & 0xFFFFu));
    float x1 = bf2f((unsigned short)(k01 >> 16));
    float r0 = x0*cs - x1*sn, r1 = x0*sn + x1*cs;
    float ss = r0*r0 + r1*r1;
#pragma unroll
    for (int m=1;m<64;m<<=1) ss += __shfl_xor(ss, m);
    float sc = rsqrtf(ss/128.f + 1e-6f);
    unsigned short o0 = f2bf(r0*sc*w0), o1 = f2bf(r1*sc*w1);
    *(unsigned*)&Kp[((size_t)bh*Sq + s)*DHq + 2*p] = (unsigned)o0 | ((unsigned)o1<<16);
  }
}

// ---------------- V transpose via LDS: QKV[s][v-part] -> Vt[bh][dh][s] ------
__global__ __launch_bounds__(256) void k_transpose_v(const unsigned short* __restrict__ QKV,
                                                     unsigned short* __restrict__ Vt){
  const int sblk = blockIdx.x;
  const int bh = blockIdx.y;
  const int b = bh >> 4, h = bh & 15;
  const int tid = threadIdx.x;
  __shared__ unsigned short T[128][136];

  const size_t base = ((size_t)(b*Sq) + sblk*128) * E3q + 2*(size_t)Dq + h*DHq;
#pragma unroll
  for (int i=0;i<8;i++){
    int pk = tid + i*256;
    int row = pk >> 4, cc = (pk & 15) * 8;
    s16x8 v = *(const s16x8*)&QKV[base + (size_t)row*E3q + cc];
    *(s16x8*)&T[row][cc] = v;
  }
  __syncthreads();
  const int dh = tid >> 1, sh = (tid & 1) * 64;
  unsigned short buf[64];
#pragma unroll
  for (int s=0;s<64;s++) buf[s] = T[sh + s][dh];
  size_t obase = ((size_t)bh*DHq + dh)*Sq + sblk*128 + sh;
#pragma unroll
  for (int i=0;i<8;i++)
    *(s16x8*)&Vt[obase + i*8] = *(const s16x8*)&buf[i*8];
}

// ---------------- causal MFMA flash attention (swapped-operand) -------------
__global__ __launch_bounds__(256, 2) void k_attn(const unsigned short* __restrict__ Qp,
                                                 const unsigned short* __restrict__ Kp,
                                                 const unsigned short* __restrict__ Vt,
                                                 unsigned short* __restrict__ Ar){
  const int L = blockIdx.x;
  int bh, qtile;
  if (L < 256){ bh = L >> 3; qtile = 8 + (L & 7); }
  else { int Ml = L - 256; bh = Ml >> 3; qtile = 7 - (Ml & 7); }
  const int b = bh >> 4, h = bh & 15;
  const int tid = threadIdx.x;
  const int w = tid >> 6, lane = tid & 63, g = lane >> 4, c = lane & 15;
  const int r0w = qtile*128 + w*32;

  const unsigned short* Qh = Qp + (size_t)bh * Sq * DHq;
  const unsigned short* Kh = Kp + (size_t)bh * Sq * DHq;
  const unsigned short* Vh = Vt + (size_t)bh * DHq * Sq;

  __shared__ __align__(16) unsigned short Ks[2][64*128];   // 32 KB
  __shared__ __align__(16) unsigned short Vs[2][128*64];   // 32 KB
  __shared__ __align__(16) unsigned short Pl[4][32*64];    // 16 KB  (per-wave [q][k])
  unsigned short* Pw = &Pl[w][0];

  s16x8 qf[2][4];
#pragma unroll
  for (int mi=0;mi<2;mi++)
#pragma unroll
    for (int kc=0;kc<4;kc++)
      qf[mi][kc] = *(const s16x8*)&Qh[(size_t)(r0w + mi*16 + c)*DHq + kc*32 + g*8];

  f32x4 acc[2][8];
#pragma unroll
  for (int mi=0;mi<2;mi++)
#pragma unroll
    for (int dt=0;dt<8;dt++)
#pragma unroll
      for (int r=0;r<4;r++) acc[mi][dt][r] = 0.f;
  float m_r[2] = { -INFINITY, -INFINITY };
  float l_p[2] = { 0.f, 0.f };             // per-lane PARTIAL sums

  const int nsteps = 2*qtile + 2;

  auto stage = [&](int j0s, int bufi){
#pragma unroll
    for (int i=0;i<4;i++){
      int pk = tid + i*256;              // K: 1024 chunks of 16B
      int row = pk>>4, pcc = pk&15;
      gload_lds16(&Kh[(size_t)(j0s+row)*DHq + ((pcc^(row&7))<<3)], &Ks[bufi][pk*8]);
    }
#pragma unroll
    for (int i=0;i<4;i++){
      int pk = tid + i*256;              // V: 1024 chunks of 16B
      int row = pk>>3, pcc = pk&7;
      gload_lds16(&Vh[(size_t)row*Sq + j0s + ((pcc^(row&7))<<3)], &Vs[bufi][pk*8]);
    }
  };

  stage(0, 0);
  __syncthreads();

  for (int t=0; t<nsteps; ++t){
    const int j0 = t*64;
    if (t+1 < nsteps) stage((t+1)*64, (t+1)&1);

    if (j0 <= r0w + 31){
      const unsigned short* Kc = &Ks[t&1][0];
      const unsigned short* Vc = &Vs[t&1][0];

      // ---- S^T = K.Q^T : sv[mi][js][r] = S[q=c+mi*16][k=j0+js*16+g*4+r] ----
      f32x4 sv[2][4];
#pragma unroll
      for (int mi=0;mi<2;mi++)
#pragma unroll
        for (int js=0;js<4;js++)
#pragma unroll
          for (int r=0;r<4;r++) sv[mi][js][r] = 0.f;

      __builtin_amdgcn_s_setprio(1);
#pragma unroll
      for (int js=0;js<4;js++){
        s16x8 kf[4];
#pragma unroll
        for (int kc=0;kc<4;kc++)
          kf[kc] = *(const s16x8*)&Kc[(js*16 + c)*128 + (((kc*4+g)^(c&7))<<3)];
#pragma unroll
        for (int mi=0;mi<2;mi++)
#pragma unroll
          for (int kc=0;kc<4;kc++)
            sv[mi][js] = __builtin_amdgcn_mfma_f32_16x16x32_bf16(kf[kc], qf[mi][kc], sv[mi][js], 0,0,0);
      }
      __builtin_amdgcn_s_setprio(0);

      // ---- causal mask (diag steps only) ----
      if (j0 + 63 > r0w){
#pragma unroll
        for (int mi=0;mi<2;mi++){
          const int q = r0w + mi*16 + c;
#pragma unroll
          for (int js=0;js<4;js++)
#pragma unroll
            for (int r=0;r<4;r++)
              if (j0 + js*16 + g*4 + r > q) sv[mi][js][r] = -INFINITY;
        }
      }

      // ---- lane-local max; cross-lane over g-groups only ----
      float pmx[2];
#pragma unroll
      for (int mi=0;mi<2;mi++){
        float mx = fmaxf(fmaxf(sv[mi][0][0],sv[mi][0][1]), fmaxf(sv[mi][0][2],sv[mi][0][3]));
#pragma unroll
        for (int js=1;js<4;js++){
          float a = fmaxf(fmaxf(sv[mi][js][0],sv[mi][js][1]), fmaxf(sv[mi][js][2],sv[mi][js][3]));
          mx = fmaxf(mx, a);
        }
        mx = fmaxf(mx, __shfl_xor(mx, 16));
        mx = fmaxf(mx, __shfl_xor(mx, 32));
        pmx[mi] = mx;
      }
      // ---- defer-max rescale ----
      int need = (pmx[0] > m_r[0] + 8.f) | (pmx[1] > m_r[1] + 8.f);
      if (__any(need)){
#pragma unroll
        for (int mi=0;mi<2;mi++){
          float mnew = fmaxf(m_r[mi], pmx[mi]);
          float corr = exp2f(m_r[mi] - mnew);
          l_p[mi] *= corr;
          m_r[mi] = mnew;
#pragma unroll
          for (int dt=0;dt<8;dt++)
#pragma unroll
            for (int r=0;r<4;r++) acc[mi][dt][r] *= corr;
        }
      }
      // ---- exp2, per-lane partial sum, packed P^T -> LDS [q][k] ----
#pragma unroll
      for (int mi=0;mi<2;mi++){
        const float mm = m_r[mi];
        const int rowoff = (mi*16 + c)*64;
#pragma unroll
        for (int js=0;js<4;js++){
          float e0 = exp2f(sv[mi][js][0] - mm);
          float e1 = exp2f(sv[mi][js][1] - mm);
          float e2 = exp2f(sv[mi][js][2] - mm);
          float e3 = exp2f(sv[mi][js][3] - mm);
          l_p[mi] += (e0+e1)+(e2+e3);
          uint2 pk2;
          pk2.x = cvtpk_bf16(e0, e1);
          pk2.y = cvtpk_bf16(e2, e3);
          const int kc8 = js*2 + (g>>1);
          *(uint2*)&Pw[rowoff + ((kc8 ^ (c&7))<<3) + (g&1)*4] = pk2;
        }
      }

      // ---- O^T += V^T (128x64) . P^T (64x32) ----
      s16x8 pfr[2][2];
#pragma unroll
      for (int mi=0;mi<2;mi++)
#pragma unroll
        for (int kc=0;kc<2;kc++)
          pfr[mi][kc] = *(const s16x8*)&Pw[(mi*16 + c)*64 + (((kc*4+g)^(c&7))<<3)];
      __builtin_amdgcn_s_setprio(1);
#pragma unroll
      for (int dt=0; dt<8; dt++){
#pragma unroll
        for (int kc=0;kc<2;kc++){
          s16x8 vfr = *(const s16x8*)&Vc[(dt*16 + c)*64 + (((kc*4+g)^(c&7))<<3)];
#pragma unroll
          for (int mi=0;mi<2;mi++)
            acc[mi][dt] = __builtin_amdgcn_mfma_f32_16x16x32_bf16(vfr, pfr[mi][kc], acc[mi][dt], 0,0,0);
        }
      }
      __builtin_amdgcn_s_setprio(0);
    }
    __syncthreads();
  }

  // ---- epilogue: reduce l across g-groups, normalize, write O^T ----
#pragma unroll
  for (int mi=0;mi<2;mi++){
    float l = l_p[mi];
    l += __shfl_xor(l, 16);
    l += __shfl_xor(l, 32);
    const float inv = 1.f / l;
    const int row = r0w + mi*16 + c;
    unsigned short* dst = &Ar[((size_t)(b*Sq + row))*Dq + h*DHq];
#pragma unroll
    for (int dt=0; dt<8; dt++){
      uint2 o2;
      o2.x = cvtpk_bf16(acc[mi][dt][0]*inv, acc[mi][dt][1]*inv);
      o2.y = cvtpk_bf16(acc[mi][dt][2]*inv, acc[mi][dt][3]*inv);
      *(uint2*)&dst[dt*16 + g*4] = o2;
    }
  }
}

// ---------------- row RMS-norm over D=2048, in place -----------------------
__global__ __launch_bounds__(256) void k_rmsnorm(unsigned short* __restrict__ A,
                                                 const float* __restrict__ w){
  const int row = blockIdx.x;
  const int tid = threadIdx.x;
  s16x8 v = *(const s16x8*)&A[(size_t)row*Dq + tid*8];
  float f[8]; float ss = 0.f;
#pragma unroll
  for (int i=0;i<8;i++){ f[i] = bf2f((unsigned short)v[i]); ss += f[i]*f[i]; }
#pragma unroll
  for (int m=1;m<64;m<<=1) ss += __shfl_xor(ss, m);
  __shared__ float red[4];
  if ((tid&63)==0) red[tid>>6] = ss;
  __syncthreads();
  ss = red[0]+red[1]+red[2]+red[3];
  float sc = rsqrtf(ss/2048.f + 1e-6f);
  unsigned short o[8];
#pragma unroll
  for (int i=0;i<8;i++) o[i] = f2bf(f[i]*sc*w[tid*8+i]);
  *(s16x8*)&A[(size_t)row*Dq + tid*8] = *(const s16x8*)o;
}

extern "C" void kernel_launch(void* const* d_in, const int* in_sizes, int n_in,
                              void* d_out, int out_size, void* d_ws, size_t ws_size,
                              hipStream_t stream){
  const float* x     = (const float*)d_in[0];
  const float* rp    = (const float*)d_in[1];
  const float* Win   = (const float*)d_in[2];
  const float* b_in  = (const float*)d_in[3];
  const float* Wout  = (const float*)d_in[4];
  const float* b_out = (const float*)d_in[5];
  const float* qk_w  = (const float*)d_in[6];
  const float* out_w = (const float*)d_in[7];
  float* outp = (float*)d_out;

  if (ws_size < (160ull<<20)) return;   // need 160 MiB scratch

  char* ws = (char*)d_ws;
  unsigned short* Xb    = (unsigned short*)(ws);                 // 16 MiB
  unsigned short* Wb    = (unsigned short*)(ws + (16ull<<20));   // 24 MiB
  unsigned short* Woutb = (unsigned short*)(ws + (40ull<<20));   //  8 MiB
  unsigned short* QKVb  = (unsigned short*)(ws + (48ull<<20));   // 48 MiB
  unsigned short* Qp    = (unsigned short*)(ws + (96ull<<20));   // 16 MiB
  unsigned short* Kp    = (unsigned short*)(ws + (112ull<<20));  // 16 MiB
  unsigned short* Vt    = (unsigned short*)(ws + (128ull<<20));  // 16 MiB
  unsigned short* Ar    = (unsigned short*)(ws + (144ull<<20));  // 16 MiB

  // 1) converts
  k_convert<<<2048, 256, 0, stream>>>(x,    Xb,    (Bq*Sq*Dq)/4);
  k_convert<<<2048, 256, 0, stream>>>(Win,  Wb,    (E3q*Dq)/4);
  k_convert<<<1024, 256, 0, stream>>>(Wout, Woutb, (Dq*Dq)/4);
  // 2) QKV = X . Win^T + b_in  (M=4096, N=6144, K=2048): 256x384, grid 256
  k_gemm1_8ph<<<256, 512, 0, stream>>>(Xb, Wb, b_in, QKVb);
  // 3) RoPE + qk RMS-norm (Q pre-scaled to log2 units) ; V transpose
  k_rope_qk<<<dim3(Sq/4, Hq, Bq), dim3(64,4), 0, stream>>>(QKVb, rp, qk_w, Qp, Kp);
  k_transpose_v<<<dim3(Sq/128, Bq*Hq), 256, 0, stream>>>(QKVb, Vt);
  // 4) causal flash attention (pair-balanced 1D grid)
  k_attn<<<512, 256, 0, stream>>>(Qp, Kp, Vt, Ar);
  // 5) out RMS-norm (in place on Ar)
  k_rmsnorm<<<Bq*Sq, 256, 0, stream>>>(Ar, out_w);
  // 6) Out = A . Wout^T + b_out  (M=4096, N=2048, K=2048): grid 32x8 = 256
  k_gemm_bt<1><<<256, 256, 0, stream>>>(Ar, Woutb, b_out, outp, Bq*Sq, Dq, Dq);
}

// Round 10
// 278.046 us; speedup vs baseline: 2.7171x; 1.0223x over previous
//
#include <hip/hip_runtime.h>
#include <cstdint>
#include <cstddef>

// Problem constants (B,S,D,H) = (2,2048,2048,16), DH=128
#define Bq  2
#define Sq  2048
#define Dq  2048
#define Hq  16
#define DHq 128
#define E3q 6144   // 3*D

typedef __attribute__((ext_vector_type(8))) short s16x8;   // 8 bf16 (4 VGPRs)
typedef __attribute__((ext_vector_type(4))) float f32x4;   // MFMA accumulator

__device__ __forceinline__ unsigned short f2bf(float f){
  union { float f; unsigned u; } v; v.f = f;
  unsigned r = v.u + 0x7FFFu + ((v.u >> 16) & 1u);   // round-to-nearest-even
  return (unsigned short)(r >> 16);
}
__device__ __forceinline__ float bf2f(unsigned short b){
  union { unsigned u; float f; } v; v.u = ((unsigned)b) << 16;
  return v.f;
}
// pack two f32 -> two bf16 in one op (no builtin on gfx950; T12 recipe)
__device__ __forceinline__ unsigned cvtpk_bf16(float lo, float hi){
  unsigned r;
  asm("v_cvt_pk_bf16_f32 %0, %1, %2" : "=v"(r) : "v"(lo), "v"(hi));
  return r;
}

// async global->LDS, 16B per lane. LDS dest must be wave-uniform base + lane*16.
__device__ __forceinline__ void gload_lds16(const void* g, void* l){
  __builtin_amdgcn_global_load_lds(
      (const __attribute__((address_space(1))) void*)g,
      (__attribute__((address_space(3))) void*)l, 16, 0, 0);
}

// ---------------- fused fp32 -> bf16 converts (x, Win, Wout) ----------------
__global__ __launch_bounds__(256) void k_convert3(const float* __restrict__ x,
                                                  const float* __restrict__ win,
                                                  const float* __restrict__ wout,
                                                  unsigned short* __restrict__ xb,
                                                  unsigned short* __restrict__ wb,
                                                  unsigned short* __restrict__ woutb){
  const int NX = (Bq*Sq*Dq)/4;            // 2,097,152 float4
  const int NW = (E3q*Dq)/4;              // 3,145,728
  const int NO = (Dq*Dq)/4;               // 1,048,576
  const int total = NX + NW + NO;
  int stride = gridDim.x * blockDim.x;
  for (int i = blockIdx.x*blockDim.x + threadIdx.x; i < total; i += stride){
    const float* src; unsigned short* dst; int j;
    if (i < NX){ src = x; dst = xb; j = i; }
    else if (i < NX+NW){ src = win; dst = wb; j = i - NX; }
    else { src = wout; dst = woutb; j = i - NX - NW; }
    float4 v = reinterpret_cast<const float4*>(src)[j];
    ushort4 o;
    o.x = f2bf(v.x); o.y = f2bf(v.y); o.z = f2bf(v.z); o.w = f2bf(v.w);
    reinterpret_cast<ushort4*>(dst)[j] = o;
  }
}

// ---------------- GEMM1: 8-phase 128x384 bf16 B^T GEMM (round-8 proven) -----
// C[m,n] = sum_k A[m,k]*Bt[n,k] + bias[n], M=4096 N=6144 K=2048, bf16 out.
// 512 threads (8 waves 2m x 4n), per-wave 64x96 (4 mf x 6 nf), K-tile 64.
// LDS 128KB: 2 bufs x {A 128x64 (2 k-halves of 8KB), B 384x64 (2 k-halves of
// 3 x 8KB units)}. 16 iters x 8 phases; vmcnt(4) at phases 4 and 8 only.
__global__ __launch_bounds__(512, 1) void k_gemm1_8ph(const unsigned short* __restrict__ A,
                                                      const unsigned short* __restrict__ Bt,
                                                      const float* __restrict__ bias,
                                                      unsigned short* __restrict__ C){
  const int K = 2048, N = 6144;
  const int bid = blockIdx.x;
  const int xcd = bid & 7, u = bid >> 3;          // 512 blocks, 64 per XCD
  const int m0 = (xcd*4 + (u & 3)) * 128;         // 32 M-tiles, 4 per XCD
  const int n0 = (u >> 2) * 384;                  // 16 N-tiles, col-major in chunk

  const int tid = threadIdx.x;
  const int lane = tid & 63, w = tid >> 6, g = lane >> 4, c = lane & 15;
  const int wm = w >> 2, wn = w & 3;              // 2 x 4 waves

  __shared__ __align__(16) unsigned short L[65536];   // 128 KB

  const int srow = tid >> 2, spc = tid & 3;
  const int ssw = (spc ^ ((srow >> 1) & 3)) << 3;
  const unsigned short* aSrc  = A  + (size_t)(m0 + srow      )*K + ssw;
  const unsigned short* bSrc0 = Bt + (size_t)(n0 + srow      )*K + ssw;
  const unsigned short* bSrc1 = Bt + (size_t)(n0 + srow + 128)*K + ssw;
  const unsigned short* bSrc2 = Bt + (size_t)(n0 + srow + 256)*K + ssw;

  auto stA = [&](int t, int h){
    gload_lds16(aSrc + t*64 + h*32, &L[((t&1)*2 + h)*4096 + tid*8]);
  };
  auto stB = [&](int t, int h, int uu){
    const unsigned short* s = (uu==0) ? bSrc0 : (uu==1) ? bSrc1 : bSrc2;
    gload_lds16(s + t*64 + h*32, &L[16384 + ((t&1)*2 + h)*12288 + uu*4096 + tid*8]);
  };

  int aoff[4], boff[6];
#pragma unroll
  for (int mf=0; mf<4; ++mf){
    int row = wm*64 + mf*16 + c;
    aoff[mf] = row*32 + ((g ^ ((row>>1)&3)) << 3);
  }
#pragma unroll
  for (int nf=0; nf<6; ++nf){
    int row = wn*96 + nf*16 + c;
    boff[nf] = row*32 + ((g ^ ((row>>1)&3)) << 3);
  }

  f32x4 acc[4][6];
#pragma unroll
  for (int i=0;i<4;i++)
#pragma unroll
    for (int j=0;j<6;j++)
#pragma unroll
      for (int r=0;r<4;r++) acc[i][j][r] = 0.f;

  auto RDA = [&](int b, int h, s16x8* af){
    const int ab = (b*2 + h)*4096;
#pragma unroll
    for (int mf=0; mf<4; ++mf) af[mf] = *(const s16x8*)&L[ab + aoff[mf]];
  };
  auto RDB = [&](int b, int h, int nh, s16x8* bf){
    const int bb = 16384 + (b*2 + h)*12288;
#pragma unroll
    for (int j=0; j<3; ++j) bf[j] = *(const s16x8*)&L[bb + boff[nh*3 + j]];
  };
  auto MM = [&](s16x8* af, s16x8* bf, int nh){
    __builtin_amdgcn_s_setprio(1);
#pragma unroll
    for (int mf=0; mf<4; ++mf)
#pragma unroll
      for (int j=0; j<3; ++j)
        acc[mf][nh*3+j] = __builtin_amdgcn_mfma_f32_16x16x32_bf16(af[mf], bf[j], acc[mf][nh*3+j], 0,0,0);
    __builtin_amdgcn_s_setprio(0);
  };
  auto BAR = [&](){
    __builtin_amdgcn_sched_barrier(0);
    __builtin_amdgcn_s_barrier();
    __builtin_amdgcn_sched_barrier(0);
  };

  // prologue: tile0 (8 units) + tile1 k0 (4 units)
  stA(0,0); stB(0,0,0); stB(0,0,1); stB(0,0,2);
  stA(0,1); stB(0,1,0); stB(0,1,1); stB(0,1,2);
  stA(1,0); stB(1,0,0); stB(1,0,1); stB(1,0,2);
  asm volatile("s_waitcnt vmcnt(4)" ::: "memory");
  __builtin_amdgcn_s_barrier();

  for (int i=0; i<16; ++i){
    const int T0 = 2*i, T1 = 2*i + 1;
    const bool st = (i < 15);
    s16x8 af[4], bf[3];
    // P1
    RDA(0,0,af); RDB(0,0,0,bf);
    stA(T1,1); stB(T1,1,0);
    BAR(); MM(af,bf,0); BAR();
    // P2
    RDB(0,0,1,bf);
    stB(T1,1,1); stB(T1,1,2);
    BAR(); MM(af,bf,1); BAR();
    // P3
    RDA(0,1,af); RDB(0,1,0,bf);
    if (st){ stA(T0+2,0); stB(T0+2,0,0); }
    BAR(); MM(af,bf,0); BAR();
    // P4 + checkpoint
    RDB(0,1,1,bf);
    if (st){ stB(T0+2,0,1); stB(T0+2,0,2); }
    __builtin_amdgcn_sched_barrier(0);
    if (st) asm volatile("s_waitcnt vmcnt(4)" ::: "memory");
    else    asm volatile("s_waitcnt vmcnt(0)" ::: "memory");
    BAR(); MM(af,bf,1); BAR();
    // P5
    RDA(1,0,af); RDB(1,0,0,bf);
    if (st){ stA(T0+2,1); stB(T0+2,1,0); }
    BAR(); MM(af,bf,0); BAR();
    // P6
    RDB(1,0,1,bf);
    if (st){ stB(T0+2,1,1); stB(T0+2,1,2); }
    BAR(); MM(af,bf,1); BAR();
    // P7
    RDA(1,1,af); RDB(1,1,0,bf);
    if (st){ stA(T1+2,0); stB(T1+2,0,0); }
    BAR(); MM(af,bf,0); BAR();
    // P8 + checkpoint
    RDB(1,1,1,bf);
    if (st){ stB(T1+2,0,1); stB(T1+2,0,2); }
    __builtin_amdgcn_sched_barrier(0);
    if (st) asm volatile("s_waitcnt vmcnt(4)" ::: "memory");
    else    asm volatile("s_waitcnt vmcnt(0)" ::: "memory");
    BAR(); MM(af,bf,1); BAR();
  }

#pragma unroll
  for (int nf=0; nf<6; ++nf){
    const int col = n0 + wn*96 + nf*16 + c;
    const float bv = bias[col];
#pragma unroll
    for (int mf=0; mf<4; ++mf){
      const int row = m0 + wm*64 + mf*16 + g*4;
#pragma unroll
      for (int r=0; r<4; ++r)
        C[(size_t)(row+r)*N + col] = f2bf(acc[mf][nf][r] + bv);
    }
  }
}

// ---------------- GEMM2: 8-phase 128x256 bf16 B^T GEMM, f32 out -------------
// M=4096 N=2048 K=2048. Grid 32x8 = 256 = 1 block/CU. 512 threads (8 waves
// 2m x 4n), per-wave 64x64 (4mf x 4nf, acc 64). K-tile 64; LDS 96KB:
// 2 bufs x {A 128x64 (2 halves of 8KB), B 256x64 (2 halves of 2x8KB units)}.
// Stage group per (tile,half) = A + B u0,u1 (3 loads/thread). vmcnt(3) at
// P4/P8: leaves only newest 2 phases' 3 loads outstanding; every region read
// in the next 4 phases is older => landed (re-derived like round-8's vmcnt(4)).
__global__ __launch_bounds__(512, 1) void k_gemm2_8ph(const unsigned short* __restrict__ A,
                                                      const unsigned short* __restrict__ Bt,
                                                      const float* __restrict__ bias,
                                                      float* __restrict__ C){
  const int K = 2048, N = 2048, NI = 16;          // 32 K-tiles = 16 iters
  const int bid = blockIdx.x;
  const int xcd = bid & 7, u = bid >> 3;          // 256 blocks, 32 per XCD
  const int m0 = (xcd*4 + (u & 3)) * 128;         // 32 M-tiles, 4 per XCD
  const int n0 = (u >> 2) * 256;                  // 8 N-tiles, col-major in chunk

  const int tid = threadIdx.x;
  const int lane = tid & 63, w = tid >> 6, g = lane >> 4, c = lane & 15;
  const int wm = w >> 2, wn = w & 3;              // 2 x 4 waves

  __shared__ __align__(16) unsigned short L[49152];   // 96 KB

  const int srow = tid >> 2, spc = tid & 3;
  const int ssw = (spc ^ ((srow >> 1) & 3)) << 3;
  const unsigned short* aSrc  = A  + (size_t)(m0 + srow      )*K + ssw;
  const unsigned short* bSrc0 = Bt + (size_t)(n0 + srow      )*K + ssw;
  const unsigned short* bSrc1 = Bt + (size_t)(n0 + srow + 128)*K + ssw;

  auto stA = [&](int t, int h){
    gload_lds16(aSrc + t*64 + h*32, &L[((t&1)*2 + h)*4096 + tid*8]);
  };
  auto stB = [&](int t, int h, int uu){
    const unsigned short* s = (uu==0) ? bSrc0 : bSrc1;
    gload_lds16(s + t*64 + h*32, &L[16384 + ((t&1)*2 + h)*8192 + uu*4096 + tid*8]);
  };

  int aoff[4], boff[4];
#pragma unroll
  for (int mf=0; mf<4; ++mf){
    int row = wm*64 + mf*16 + c;
    aoff[mf] = row*32 + ((g ^ ((row>>1)&3)) << 3);
  }
#pragma unroll
  for (int nf=0; nf<4; ++nf){
    int row = wn*64 + nf*16 + c;
    boff[nf] = row*32 + ((g ^ ((row>>1)&3)) << 3);
  }

  f32x4 acc[4][4];
#pragma unroll
  for (int i=0;i<4;i++)
#pragma unroll
    for (int j=0;j<4;j++)
#pragma unroll
      for (int r=0;r<4;r++) acc[i][j][r] = 0.f;

  auto RDA = [&](int b, int h, s16x8* af){
    const int ab = (b*2 + h)*4096;
#pragma unroll
    for (int mf=0; mf<4; ++mf) af[mf] = *(const s16x8*)&L[ab + aoff[mf]];
  };
  auto RDB = [&](int b, int h, int nh, s16x8* bf){
    const int bb = 16384 + (b*2 + h)*8192;
#pragma unroll
    for (int j=0; j<2; ++j) bf[j] = *(const s16x8*)&L[bb + boff[nh*2 + j]];
  };
  auto MM = [&](s16x8* af, s16x8* bf, int nh){
    __builtin_amdgcn_s_setprio(1);
#pragma unroll
    for (int mf=0; mf<4; ++mf)
#pragma unroll
      for (int j=0; j<2; ++j)
        acc[mf][nh*2+j] = __builtin_amdgcn_mfma_f32_16x16x32_bf16(af[mf], bf[j], acc[mf][nh*2+j], 0,0,0);
    __builtin_amdgcn_s_setprio(0);
  };
  auto BAR = [&](){
    __builtin_amdgcn_sched_barrier(0);
    __builtin_amdgcn_s_barrier();
    __builtin_amdgcn_sched_barrier(0);
  };

  // prologue: tile0 k0,k1 + tile1 k0 (9 loads); leave tile1-k0's 3 outstanding
  stA(0,0); stB(0,0,0); stB(0,0,1);
  stA(0,1); stB(0,1,0); stB(0,1,1);
  stA(1,0); stB(1,0,0); stB(1,0,1);
  asm volatile("s_waitcnt vmcnt(3)" ::: "memory");
  __builtin_amdgcn_s_barrier();

  for (int i=0; i<NI; ++i){
    const int T0 = 2*i, T1 = 2*i + 1;
    const bool st = (i < NI-1);
    s16x8 af[4], bf[2];
    // P1: buf0 k0 nh0 ; stage (T1,k1) A+u0
    RDA(0,0,af); RDB(0,0,0,bf);
    stA(T1,1); stB(T1,1,0);
    BAR(); MM(af,bf,0); BAR();
    // P2: buf0 k0 nh1 ; stage (T1,k1) u1
    RDB(0,0,1,bf);
    stB(T1,1,1);
    BAR(); MM(af,bf,1); BAR();
    // P3: buf0 k1 nh0 ; stage (T0+2,k0) A+u0
    RDA(0,1,af); RDB(0,1,0,bf);
    if (st){ stA(T0+2,0); stB(T0+2,0,0); }
    BAR(); MM(af,bf,0); BAR();
    // P4: buf0 k1 nh1 ; stage (T0+2,k0) u1 ; checkpoint
    RDB(0,1,1,bf);
    if (st){ stB(T0+2,0,1); }
    __builtin_amdgcn_sched_barrier(0);
    if (st) asm volatile("s_waitcnt vmcnt(3)" ::: "memory");
    else    asm volatile("s_waitcnt vmcnt(0)" ::: "memory");
    BAR(); MM(af,bf,1); BAR();
    // P5: buf1 k0 nh0 ; stage (T0+2,k1) A+u0
    RDA(1,0,af); RDB(1,0,0,bf);
    if (st){ stA(T0+2,1); stB(T0+2,1,0); }
    BAR(); MM(af,bf,0); BAR();
    // P6: buf1 k0 nh1 ; stage (T0+2,k1) u1
    RDB(1,0,1,bf);
    if (st){ stB(T0+2,1,1); }
    BAR(); MM(af,bf,1); BAR();
    // P7: buf1 k1 nh0 ; stage (T1+2,k0) A+u0
    RDA(1,1,af); RDB(1,1,0,bf);
    if (st){ stA(T1+2,0); stB(T1+2,0,0); }
    BAR(); MM(af,bf,0); BAR();
    // P8: buf1 k1 nh1 ; stage (T1+2,k0) u1 ; checkpoint
    RDB(1,1,1,bf);
    if (st){ stB(T1+2,0,1); }
    __builtin_amdgcn_sched_barrier(0);
    if (st) asm volatile("s_waitcnt vmcnt(3)" ::: "memory");
    else    asm volatile("s_waitcnt vmcnt(0)" ::: "memory");
    BAR(); MM(af,bf,1); BAR();
  }

#pragma unroll
  for (int nf=0; nf<4; ++nf){
    const int col = n0 + wn*64 + nf*16 + c;
    const float bv = bias[col];
#pragma unroll
    for (int mf=0; mf<4; ++mf){
      const int row = m0 + wm*64 + mf*16 + g*4;
#pragma unroll
      for (int r=0; r<4; ++r)
        C[(size_t)(row+r)*N + col] = acc[mf][nf][r] + bv;
    }
  }
}

// ---------------- RoPE + qk RMS-norm for Q,K only --------------------------
__global__ __launch_bounds__(256) void k_rope_qk(const unsigned short* __restrict__ QKV,
                                                 const float* __restrict__ rp,
                                                 const float* __restrict__ qk_w,
                                                 unsigned short* __restrict__ Qp,
                                                 unsigned short* __restrict__ Kp){
  const int p = threadIdx.x;
  const int s = blockIdx.x*4 + threadIdx.y;
  const int h = blockIdx.y;
  const int b = blockIdx.z;
  const size_t n = (size_t)b*Sq + s;
  const int bh = b*Hq + h;

  float ang = rp[s*64 + p];
  float sn, cs; sincosf(ang, &sn, &cs);
  float w0 = qk_w[2*p], w1 = qk_w[2*p+1];
  const float QSCALE = 0.08838834764831845f * 1.4426950408889634f; // 1/sqrt(128)*log2e

  {
    unsigned q01 = *(const unsigned*)&QKV[n*E3q + h*DHq + 2*p];
    float x0 = bf2f((unsigned short)(q01 & 0xFFFFu));
    float x1 = bf2f((unsigned short)(q01 >> 16));
    float r0 = x0*cs - x1*sn, r1 = x0*sn + x1*cs;
    float ss = r0*r0 + r1*r1;
#pragma unroll
    for (int m=1;m<64;m<<=1) ss += __shfl_xor(ss, m);
    float sc = rsqrtf(ss/128.f + 1e-6f) * QSCALE;
    unsigned short o0 = f2bf(r0*sc*w0), o1 = f2bf(r1*sc*w1);
    *(unsigned*)&Qp[((size_t)bh*Sq + s)*DHq + 2*p] = (unsigned)o0 | ((unsigned)o1<<16);
  }
  {
    unsigned k01 = *(const unsigned*)&QKV[n*E3q + Dq + h*DHq + 2*p];
    float x0 = bf2f((unsigned short)(k01 & 0xFFFFu));
    float x1 = bf2f((unsigned short)(k01 >> 16));
    float r0 = x0*cs - x1*sn, r1 = x0*sn + x1*cs;
    float ss = r0*r0 + r1*r1;
#pragma unroll
    for (int m=1;m<64;m<<=1) ss += __shfl_xor(ss, m);
    float sc = rsqrtf(ss/128.f + 1e-6f);
    unsigned short o0 = f2bf(r0*sc*w0), o1 = f2bf(r1*sc*w1);
    *(unsigned*)&Kp[((size_t)bh*Sq + s)*DHq + 2*p] = (unsigned)o0 | ((unsigned)o1<<16);
  }
}

// ---------------- V transpose via LDS: QKV[s][v-part] -> Vt[bh][dh][s] ------
__global__ __launch_bounds__(256) void k_transpose_v(const unsigned short* __restrict__ QKV,
                                                     unsigned short* __restrict__ Vt){
  const int sblk = blockIdx.x;
  const int bh = blockIdx.y;
  const int b = bh >> 4, h = bh & 15;
  const int tid = threadIdx.x;
  __shared__ unsigned short T[128][136];

  const size_t base = ((size_t)(b*Sq) + sblk*128) * E3q + 2*(size_t)Dq + h*DHq;
#pragma unroll
  for (int i=0;i<8;i++){
    int pk = tid + i*256;
    int row = pk >> 4, cc = (pk & 15) * 8;
    s16x8 v = *(const s16x8*)&QKV[base + (size_t)row*E3q + cc];
    *(s16x8*)&T[row][cc] = v;
  }
  __syncthreads();
  const int dh = tid >> 1, sh = (tid & 1) * 64;
  unsigned short buf[64];
#pragma unroll
  for (int s=0;s<64;s++) buf[s] = T[sh + s][dh];
  size_t obase = ((size_t)bh*DHq + dh)*Sq + sblk*128 + sh;
#pragma unroll
  for (int i=0;i<8;i++)
    *(s16x8*)&Vt[obase + i*8] = *(const s16x8*)&buf[i*8];
}

// ---------------- causal MFMA flash attention (swapped-operand) -------------
__global__ __launch_bounds__(256, 2) void k_attn(const unsigned short* __restrict__ Qp,
                                                 const unsigned short* __restrict__ Kp,
                                                 const unsigned short* __restrict__ Vt,
                                                 unsigned short* __restrict__ Ar){
  const int L = blockIdx.x;
  int bh, qtile;
  if (L < 256){ bh = L >> 3; qtile = 8 + (L & 7); }
  else { int Ml = L - 256; bh = Ml >> 3; qtile = 7 - (Ml & 7); }
  const int b = bh >> 4, h = bh & 15;
  const int tid = threadIdx.x;
  const int w = tid >> 6, lane = tid & 63, g = lane >> 4, c = lane & 15;
  const int r0w = qtile*128 + w*32;

  const unsigned short* Qh = Qp + (size_t)bh * Sq * DHq;
  const unsigned short* Kh = Kp + (size_t)bh * Sq * DHq;
  const unsigned short* Vh = Vt + (size_t)bh * DHq * Sq;

  __shared__ __align__(16) unsigned short Ks[2][64*128];   // 32 KB
  __shared__ __align__(16) unsigned short Vs[2][128*64];   // 32 KB
  __shared__ __align__(16) unsigned short Pl[4][32*64];    // 16 KB  (per-wave [q][k])
  unsigned short* Pw = &Pl[w][0];

  s16x8 qf[2][4];
#pragma unroll
  for (int mi=0;mi<2;mi++)
#pragma unroll
    for (int kc=0;kc<4;kc++)
      qf[mi][kc] = *(const s16x8*)&Qh[(size_t)(r0w + mi*16 + c)*DHq + kc*32 + g*8];

  f32x4 acc[2][8];
#pragma unroll
  for (int mi=0;mi<2;mi++)
#pragma unroll
    for (int dt=0;dt<8;dt++)
#pragma unroll
      for (int r=0;r<4;r++) acc[mi][dt][r] = 0.f;
  float m_r[2] = { -INFINITY, -INFINITY };
  float l_p[2] = { 0.f, 0.f };             // per-lane PARTIAL sums

  const int nsteps = 2*qtile + 2;

  auto stage = [&](int j0s, int bufi){
#pragma unroll
    for (int i=0;i<4;i++){
      int pk = tid + i*256;              // K: 1024 chunks of 16B
      int row = pk>>4, pcc = pk&15;
      gload_lds16(&Kh[(size_t)(j0s+row)*DHq + ((pcc^(row&7))<<3)], &Ks[bufi][pk*8]);
    }
#pragma unroll
    for (int i=0;i<4;i++){
      int pk = tid + i*256;              // V: 1024 chunks of 16B
      int row = pk>>3, pcc = pk&7;
      gload_lds16(&Vh[(size_t)row*Sq + j0s + ((pcc^(row&7))<<3)], &Vs[bufi][pk*8]);
    }
  };

  stage(0, 0);
  __syncthreads();

  for (int t=0; t<nsteps; ++t){
    const int j0 = t*64;
    if (t+1 < nsteps) stage((t+1)*64, (t+1)&1);

    if (j0 <= r0w + 31){
      const unsigned short* Kc = &Ks[t&1][0];
      const unsigned short* Vc = &Vs[t&1][0];

      // ---- S^T = K.Q^T : sv[mi][js][r] = S[q=c+mi*16][k=j0+js*16+g*4+r] ----
      f32x4 sv[2][4];
#pragma unroll
      for (int mi=0;mi<2;mi++)
#pragma unroll
        for (int js=0;js<4;js++)
#pragma unroll
          for (int r=0;r<4;r++) sv[mi][js][r] = 0.f;

      __builtin_amdgcn_s_setprio(1);
#pragma unroll
      for (int js=0;js<4;js++){
        s16x8 kf[4];
#pragma unroll
        for (int kc=0;kc<4;kc++)
          kf[kc] = *(const s16x8*)&Kc[(js*16 + c)*128 + (((kc*4+g)^(c&7))<<3)];
#pragma unroll
        for (int mi=0;mi<2;mi++)
#pragma unroll
          for (int kc=0;kc<4;kc++)
            sv[mi][js] = __builtin_amdgcn_mfma_f32_16x16x32_bf16(kf[kc], qf[mi][kc], sv[mi][js], 0,0,0);
      }
      __builtin_amdgcn_s_setprio(0);

      // ---- causal mask (diag steps only) ----
      if (j0 + 63 > r0w){
#pragma unroll
        for (int mi=0;mi<2;mi++){
          const int q = r0w + mi*16 + c;
#pragma unroll
          for (int js=0;js<4;js++)
#pragma unroll
            for (int r=0;r<4;r++)
              if (j0 + js*16 + g*4 + r > q) sv[mi][js][r] = -INFINITY;
        }
      }

      // ---- lane-local max; cross-lane over g-groups only ----
      float pmx[2];
#pragma unroll
      for (int mi=0;mi<2;mi++){
        float mx = fmaxf(fmaxf(sv[mi][0][0],sv[mi][0][1]), fmaxf(sv[mi][0][2],sv[mi][0][3]));
#pragma unroll
        for (int js=1;js<4;js++){
          float a = fmaxf(fmaxf(sv[mi][js][0],sv[mi][js][1]), fmaxf(sv[mi][js][2],sv[mi][js][3]));
          mx = fmaxf(mx, a);
        }
        mx = fmaxf(mx, __shfl_xor(mx, 16));
        mx = fmaxf(mx, __shfl_xor(mx, 32));
        pmx[mi] = mx;
      }
      // ---- defer-max rescale ----
      int need = (pmx[0] > m_r[0] + 8.f) | (pmx[1] > m_r[1] + 8.f);
      if (__any(need)){
#pragma unroll
        for (int mi=0;mi<2;mi++){
          float mnew = fmaxf(m_r[mi], pmx[mi]);
          float corr = exp2f(m_r[mi] - mnew);
          l_p[mi] *= corr;
          m_r[mi] = mnew;
#pragma unroll
          for (int dt=0;dt<8;dt++)
#pragma unroll
            for (int r=0;r<4;r++) acc[mi][dt][r] *= corr;
        }
      }
      // ---- exp2, per-lane partial sum, packed P^T -> LDS [q][k] ----
#pragma unroll
      for (int mi=0;mi<2;mi++){
        const float mm = m_r[mi];
        const int rowoff = (mi*16 + c)*64;
#pragma unroll
        for (int js=0;js<4;js++){
          float e0 = exp2f(sv[mi][js][0] - mm);
          float e1 = exp2f(sv[mi][js][1] - mm);
          float e2 = exp2f(sv[mi][js][2] - mm);
          float e3 = exp2f(sv[mi][js][3] - mm);
          l_p[mi] += (e0+e1)+(e2+e3);
          uint2 pk2;
          pk2.x = cvtpk_bf16(e0, e1);
          pk2.y = cvtpk_bf16(e2, e3);
          const int kc8 = js*2 + (g>>1);
          *(uint2*)&Pw[rowoff + ((kc8 ^ (c&7))<<3) + (g&1)*4] = pk2;
        }
      }

      // ---- O^T += V^T (128x64) . P^T (64x32) ----
      s16x8 pfr[2][2];
#pragma unroll
      for (int mi=0;mi<2;mi++)
#pragma unroll
        for (int kc=0;kc<2;kc++)
          pfr[mi][kc] = *(const s16x8*)&Pw[(mi*16 + c)*64 + (((kc*4+g)^(c&7))<<3)];
      __builtin_amdgcn_s_setprio(1);
#pragma unroll
      for (int dt=0; dt<8; dt++){
#pragma unroll
        for (int kc=0;kc<2;kc++){
          s16x8 vfr = *(const s16x8*)&Vc[(dt*16 + c)*64 + (((kc*4+g)^(c&7))<<3)];
#pragma unroll
          for (int mi=0;mi<2;mi++)
            acc[mi][dt] = __builtin_amdgcn_mfma_f32_16x16x32_bf16(vfr, pfr[mi][kc], acc[mi][dt], 0,0,0);
        }
      }
      __builtin_amdgcn_s_setprio(0);
    }
    __syncthreads();
  }

  // ---- epilogue: reduce l across g-groups, normalize, write O^T ----
#pragma unroll
  for (int mi=0;mi<2;mi++){
    float l = l_p[mi];
    l += __shfl_xor(l, 16);
    l += __shfl_xor(l, 32);
    const float inv = 1.f / l;
    const int row = r0w + mi*16 + c;
    unsigned short* dst = &Ar[((size_t)(b*Sq + row))*Dq + h*DHq];
#pragma unroll
    for (int dt=0; dt<8; dt++){
      uint2 o2;
      o2.x = cvtpk_bf16(acc[mi][dt][0]*inv, acc[mi][dt][1]*inv);
      o2.y = cvtpk_bf16(acc[mi][dt][2]*inv, acc[mi][dt][3]*inv);
      *(uint2*)&dst[dt*16 + g*4] = o2;
    }
  }
}

// ---------------- row RMS-norm over D=2048, in place -----------------------
__global__ __launch_bounds__(256) void k_rmsnorm(unsigned short* __restrict__ A,
                                                 const float* __restrict__ w){
  const int row = blockIdx.x;
  const int tid = threadIdx.x;
  s16x8 v = *(const s16x8*)&A[(size_t)row*Dq + tid*8];
  float f[8]; float ss = 0.f;
#pragma unroll
  for (int i=0;i<8;i++){ f[i] = bf2f((unsigned short)v[i]); ss += f[i]*f[i]; }
#pragma unroll
  for (int m=1;m<64;m<<=1) ss += __shfl_xor(ss, m);
  __shared__ float red[4];
  if ((tid&63)==0) red[tid>>6] = ss;
  __syncthreads();
  ss = red[0]+red[1]+red[2]+red[3];
  float sc = rsqrtf(ss/2048.f + 1e-6f);
  unsigned short o[8];
#pragma unroll
  for (int i=0;i<8;i++) o[i] = f2bf(f[i]*sc*w[tid*8+i]);
  *(s16x8*)&A[(size_t)row*Dq + tid*8] = *(const s16x8*)o;
}

extern "C" void kernel_launch(void* const* d_in, const int* in_sizes, int n_in,
                              void* d_out, int out_size, void* d_ws, size_t ws_size,
                              hipStream_t stream){
  const float* x     = (const float*)d_in[0];
  const float* rp    = (const float*)d_in[1];
  const float* Win   = (const float*)d_in[2];
  const float* b_in  = (const float*)d_in[3];
  const float* Wout  = (const float*)d_in[4];
  const float* b_out = (const float*)d_in[5];
  const float* qk_w  = (const float*)d_in[6];
  const float* out_w = (const float*)d_in[7];
  float* outp = (float*)d_out;

  if (ws_size < (160ull<<20)) return;   // need 160 MiB scratch

  char* ws = (char*)d_ws;
  unsigned short* Xb    = (unsigned short*)(ws);                 // 16 MiB
  unsigned short* Wb    = (unsigned short*)(ws + (16ull<<20));   // 24 MiB
  unsigned short* Woutb = (unsigned short*)(ws + (40ull<<20));   //  8 MiB
  unsigned short* QKVb  = (unsigned short*)(ws + (48ull<<20));   // 48 MiB
  unsigned short* Qp    = (unsigned short*)(ws + (96ull<<20));   // 16 MiB
  unsigned short* Kp    = (unsigned short*)(ws + (112ull<<20));  // 16 MiB
  unsigned short* Vt    = (unsigned short*)(ws + (128ull<<20));  // 16 MiB
  unsigned short* Ar    = (unsigned short*)(ws + (144ull<<20));  // 16 MiB

  // 1) fused converts
  k_convert3<<<2048, 256, 0, stream>>>(x, Win, Wout, Xb, Wb, Woutb);
  // 2) QKV = X . Win^T + b_in  (M=4096, N=6144, K=2048): 8-phase, 512 blocks
  k_gemm1_8ph<<<512, 512, 0, stream>>>(Xb, Wb, b_in, QKVb);
  // 3) RoPE + qk RMS-norm (Q pre-scaled to log2 units) ; V transpose
  k_rope_qk<<<dim3(Sq/4, Hq, Bq), dim3(64,4), 0, stream>>>(QKVb, rp, qk_w, Qp, Kp);
  k_transpose_v<<<dim3(Sq/128, Bq*Hq), 256, 0, stream>>>(QKVb, Vt);
  // 4) causal flash attention (pair-balanced 1D grid)
  k_attn<<<512, 256, 0, stream>>>(Qp, Kp, Vt, Ar);
  // 5) out RMS-norm (in place on Ar)
  k_rmsnorm<<<Bq*Sq, 256, 0, stream>>>(Ar, out_w);
  // 6) Out = A . Wout^T + b_out  (M=4096, N=2048, K=2048): 8-phase, 256 blocks
  k_gemm2_8ph<<<256, 512, 0, stream>>>(Ar, Woutb, b_out, outp);
}

// Round 11
// 269.742 us; speedup vs baseline: 2.8008x; 1.0308x over previous
//
#include <hip/hip_runtime.h>
#include <cstdint>
#include <cstddef>

// Problem constants (B,S,D,H) = (2,2048,2048,16), DH=128
#define Bq  2
#define Sq  2048
#define Dq  2048
#define Hq  16
#define DHq 128
#define E3q 6144   // 3*D

typedef __attribute__((ext_vector_type(8))) short s16x8;   // 8 bf16 (4 VGPRs)
typedef __attribute__((ext_vector_type(4))) float f32x4;   // MFMA accumulator

__device__ __forceinline__ unsigned short f2bf(float f){
  union { float f; unsigned u; } v; v.f = f;
  unsigned r = v.u + 0x7FFFu + ((v.u >> 16) & 1u);   // round-to-nearest-even
  return (unsigned short)(r >> 16);
}
__device__ __forceinline__ float bf2f(unsigned short b){
  union { unsigned u; float f; } v; v.u = ((unsigned)b) << 16;
  return v.f;
}
// pack two f32 -> two bf16 in one op (no builtin on gfx950; T12 recipe)
__device__ __forceinline__ unsigned cvtpk_bf16(float lo, float hi){
  unsigned r;
  asm("v_cvt_pk_bf16_f32 %0, %1, %2" : "=v"(r) : "v"(lo), "v"(hi));
  return r;
}

// async global->LDS, 16B per lane. LDS dest must be wave-uniform base + lane*16.
__device__ __forceinline__ void gload_lds16(const void* g, void* l){
  __builtin_amdgcn_global_load_lds(
      (const __attribute__((address_space(1))) void*)g,
      (__attribute__((address_space(3))) void*)l, 16, 0, 0);
}

// ---------------- fused fp32 -> bf16 converts; Wout gets out_w folded in ----
__global__ __launch_bounds__(256) void k_convert3(const float* __restrict__ x,
                                                  const float* __restrict__ win,
                                                  const float* __restrict__ wout,
                                                  const float* __restrict__ out_w,
                                                  unsigned short* __restrict__ xb,
                                                  unsigned short* __restrict__ wb,
                                                  unsigned short* __restrict__ woutb){
  const int NX = (Bq*Sq*Dq)/4;
  const int NW = (E3q*Dq)/4;
  const int NO = (Dq*Dq)/4;
  const int total = NX + NW + NO;
  int stride = gridDim.x * blockDim.x;
  for (int i = blockIdx.x*blockDim.x + threadIdx.x; i < total; i += stride){
    if (i < NX + NW){
      const float* src; unsigned short* dst; int j;
      if (i < NX){ src = x; dst = xb; j = i; }
      else { src = win; dst = wb; j = i - NX; }
      float4 v = reinterpret_cast<const float4*>(src)[j];
      ushort4 o;
      o.x = f2bf(v.x); o.y = f2bf(v.y); o.z = f2bf(v.z); o.w = f2bf(v.w);
      reinterpret_cast<ushort4*>(dst)[j] = o;
    } else {
      int j = i - NX - NW;
      float4 v = reinterpret_cast<const float4*>(wout)[j];
      float4 w = reinterpret_cast<const float4*>(out_w)[j & 511];   // (j*4)%2048 /4
      ushort4 o;
      o.x = f2bf(v.x*w.x); o.y = f2bf(v.y*w.y); o.z = f2bf(v.z*w.z); o.w = f2bf(v.w*w.w);
      reinterpret_cast<ushort4*>(woutb)[j] = o;
    }
  }
}

// ---------------- GEMM1 fused: 8-phase 128x256 + RoPE/RMS/transpose epilogue
// QKV[m, n] = sum_k X[m,k]*Win[n,k] + b_in[n], M=4096, N=6144, K=2048.
// 768 blocks (32 Mtiles x 24 Ntiles) = 3 exact rounds over 256 CUs.
// Main loop = proven GEMM2 8-phase structure (vmcnt(3) @ P4/P8).
// 256-col tiles align with head/region boundaries: n0<2048 Q, <4096 K, else V.
// Epilogue: Q/K -> bias + sumsq (rotation-orthogonal => pre-rope sumsq valid)
//   + cross-lane/cross-wave reduce + __sincosf RoPE + scale*qk_w (*QSCALE for Q)
//   -> LDS-staged coalesced write to Qp/Kp[bh][s][dh].
//   V -> bias -> LDS transpose -> Vt[bh][dh][s].
__global__ __launch_bounds__(512, 1) void k_gemm1f(const unsigned short* __restrict__ A,
                                                   const unsigned short* __restrict__ Bt,
                                                   const float* __restrict__ bias,
                                                   const float* __restrict__ rp,
                                                   const float* __restrict__ qk_w,
                                                   unsigned short* __restrict__ Qp,
                                                   unsigned short* __restrict__ Kp,
                                                   unsigned short* __restrict__ Vt){
  const int K = 2048, NI = 16;
  const int bid = blockIdx.x;
  const int xcd = bid & 7, u = bid >> 3;          // 96 per XCD
  const int m0 = (xcd*4 + (u & 3)) * 128;         // 32 M-tiles, 4 per XCD
  const int n0 = (u >> 2) * 256;                  // 24 N-tiles, col-major in chunk

  const int tid = threadIdx.x;
  const int lane = tid & 63, w = tid >> 6, g = lane >> 4, c = lane & 15;
  const int wm = w >> 2, wn = w & 3;              // 2 x 4 waves

  __shared__ __align__(16) unsigned short L[49152];   // 96 KB

  const int srow = tid >> 2, spc = tid & 3;
  const int ssw = (spc ^ ((srow >> 1) & 3)) << 3;
  const unsigned short* aSrc  = A  + (size_t)(m0 + srow      )*K + ssw;
  const unsigned short* bSrc0 = Bt + (size_t)(n0 + srow      )*K + ssw;
  const unsigned short* bSrc1 = Bt + (size_t)(n0 + srow + 128)*K + ssw;

  auto stA = [&](int t, int h){
    gload_lds16(aSrc + t*64 + h*32, &L[((t&1)*2 + h)*4096 + tid*8]);
  };
  auto stB = [&](int t, int h, int uu){
    const unsigned short* s = (uu==0) ? bSrc0 : bSrc1;
    gload_lds16(s + t*64 + h*32, &L[16384 + ((t&1)*2 + h)*8192 + uu*4096 + tid*8]);
  };

  int aoff[4], boff[4];
#pragma unroll
  for (int mf=0; mf<4; ++mf){
    int row = wm*64 + mf*16 + c;
    aoff[mf] = row*32 + ((g ^ ((row>>1)&3)) << 3);
  }
#pragma unroll
  for (int nf=0; nf<4; ++nf){
    int row = wn*64 + nf*16 + c;
    boff[nf] = row*32 + ((g ^ ((row>>1)&3)) << 3);
  }

  f32x4 acc[4][4];
#pragma unroll
  for (int i=0;i<4;i++)
#pragma unroll
    for (int j=0;j<4;j++)
#pragma unroll
      for (int r=0;r<4;r++) acc[i][j][r] = 0.f;

  auto RDA = [&](int b, int h, s16x8* af){
    const int ab = (b*2 + h)*4096;
#pragma unroll
    for (int mf=0; mf<4; ++mf) af[mf] = *(const s16x8*)&L[ab + aoff[mf]];
  };
  auto RDB = [&](int b, int h, int nh, s16x8* bf){
    const int bb = 16384 + (b*2 + h)*8192;
#pragma unroll
    for (int j=0; j<2; ++j) bf[j] = *(const s16x8*)&L[bb + boff[nh*2 + j]];
  };
  auto MM = [&](s16x8* af, s16x8* bf, int nh){
    __builtin_amdgcn_s_setprio(1);
#pragma unroll
    for (int mf=0; mf<4; ++mf)
#pragma unroll
      for (int j=0; j<2; ++j)
        acc[mf][nh*2+j] = __builtin_amdgcn_mfma_f32_16x16x32_bf16(af[mf], bf[j], acc[mf][nh*2+j], 0,0,0);
    __builtin_amdgcn_s_setprio(0);
  };
  auto BAR = [&](){
    __builtin_amdgcn_sched_barrier(0);
    __builtin_amdgcn_s_barrier();
    __builtin_amdgcn_sched_barrier(0);
  };

  stA(0,0); stB(0,0,0); stB(0,0,1);
  stA(0,1); stB(0,1,0); stB(0,1,1);
  stA(1,0); stB(1,0,0); stB(1,0,1);
  asm volatile("s_waitcnt vmcnt(3)" ::: "memory");
  __builtin_amdgcn_s_barrier();

  for (int i=0; i<NI; ++i){
    const int T0 = 2*i, T1 = 2*i + 1;
    const bool st = (i < NI-1);
    s16x8 af[4], bf[2];
    RDA(0,0,af); RDB(0,0,0,bf);
    stA(T1,1); stB(T1,1,0);
    BAR(); MM(af,bf,0); BAR();
    RDB(0,0,1,bf);
    stB(T1,1,1);
    BAR(); MM(af,bf,1); BAR();
    RDA(0,1,af); RDB(0,1,0,bf);
    if (st){ stA(T0+2,0); stB(T0+2,0,0); }
    BAR(); MM(af,bf,0); BAR();
    RDB(0,1,1,bf);
    if (st){ stB(T0+2,0,1); }
    __builtin_amdgcn_sched_barrier(0);
    if (st) asm volatile("s_waitcnt vmcnt(3)" ::: "memory");
    else    asm volatile("s_waitcnt vmcnt(0)" ::: "memory");
    BAR(); MM(af,bf,1); BAR();
    RDA(1,0,af); RDB(1,0,0,bf);
    if (st){ stA(T0+2,1); stB(T0+2,1,0); }
    BAR(); MM(af,bf,0); BAR();
    RDB(1,0,1,bf);
    if (st){ stB(T0+2,1,1); }
    BAR(); MM(af,bf,1); BAR();
    RDA(1,1,af); RDB(1,1,0,bf);
    if (st){ stA(T1+2,0); stB(T1+2,0,0); }
    BAR(); MM(af,bf,0); BAR();
    RDB(1,1,1,bf);
    if (st){ stB(T1+2,0,1); }
    __builtin_amdgcn_sched_barrier(0);
    if (st) asm volatile("s_waitcnt vmcnt(3)" ::: "memory");
    else    asm volatile("s_waitcnt vmcnt(0)" ::: "memory");
    BAR(); MM(af,bf,1); BAR();
  }

  // ================= fused epilogue =================
  const int btype = (n0 < 2048) ? 0 : (n0 < 4096) ? 1 : 2;   // Q, K, V
  const int b  = m0 >> 11;                 // batch
  const int sb = m0 & 2047;                // token base
  const int h0 = (n0 & 2047) >> 7;         // base head of this 256-col tile
  const int LTS = 264;                     // padded bf16 row stride
  const float QSCALE = 0.08838834764831845f * 1.4426950408889634f;

  // bias add (b_in) into acc
#pragma unroll
  for (int nf=0; nf<4; ++nf){
    const float bv = bias[n0 + wn*64 + nf*16 + c];
#pragma unroll
    for (int mf=0; mf<4; ++mf)
#pragma unroll
      for (int r=0; r<4; ++r) acc[mf][nf][r] += bv;
  }

  __syncthreads();   // main-loop LDS use finished; L free

  if (btype < 2){
    // ---- per-row sumsq over this wave's 64 cols ----
    float s2[4][4];
#pragma unroll
    for (int mf=0;mf<4;mf++)
#pragma unroll
      for (int r=0;r<4;r++){
        float s = 0.f;
#pragma unroll
        for (int nf=0;nf<4;nf++){ float v = acc[mf][nf][r]; s += v*v; }
        s2[mf][r] = s;
      }
#pragma unroll
    for (int m=1;m<16;m<<=1)
#pragma unroll
      for (int mf=0;mf<4;mf++)
#pragma unroll
        for (int r=0;r<4;r++) s2[mf][r] += __shfl_xor(s2[mf][r], m);
    // cross-wave (two waves per head) via LDS [128 rows][2 heads]
    float* Ssum = (float*)&L[0];
    if (c==0 && (wn&1)==0){
#pragma unroll
      for (int mf=0;mf<4;mf++)
#pragma unroll
        for (int r=0;r<4;r++)
          Ssum[(wm*64+mf*16+g*4+r)*2 + (wn>>1)] = s2[mf][r];
    }
    __syncthreads();
    if (c==0 && (wn&1)==1){
#pragma unroll
      for (int mf=0;mf<4;mf++)
#pragma unroll
        for (int r=0;r<4;r++)
          Ssum[(wm*64+mf*16+g*4+r)*2 + (wn>>1)] += s2[mf][r];
    }
    __syncthreads();
    float rsc[4][4];
#pragma unroll
    for (int mf=0;mf<4;mf++)
#pragma unroll
      for (int r=0;r<4;r++)
        rsc[mf][r] = rsqrtf(Ssum[(wm*64+mf*16+g*4+r)*2 + (wn>>1)]*(1.f/128.f) + 1e-6f);
    __syncthreads();   // done with Ssum; L reused as output tile

    const float qmul = (btype==0) ? QSCALE : 1.f;
    float wq[4];
#pragma unroll
    for (int nf=0;nf<4;nf++) wq[nf] = qk_w[(wn*64+nf*16+c)&127];

    // RoPE + scale -> LDS tile [128][LTS]
#pragma unroll
    for (int mf=0;mf<4;mf++)
#pragma unroll
      for (int r=0;r<4;r++){
        const int rowl = wm*64+mf*16+g*4+r;
        const int s = sb + rowl;
        const float sc = rsc[mf][r] * qmul;
#pragma unroll
        for (int nf=0;nf<4;nf++){
          const int p = ((wn*64+nf*16+c)&127) >> 1;
          float sn, cs; __sincosf(rp[s*64+p], &sn, &cs);
          float v  = acc[mf][nf][r];
          float pv = __shfl_xor(v, 1);
          float rot = ((c&1)==0) ? (v*cs - pv*sn) : (pv*sn + v*cs);
          L[rowl*LTS + wn*64+nf*16+c] = f2bf(rot * sc * wq[nf]);
        }
      }
    __syncthreads();
    // coalesced write: thread -> (row, head, half), 64 bf16 each
    {
      const int rw = tid >> 2, hd = (tid>>1)&1, hf = tid&1;
      const int bh = b*Hq + h0 + hd;
      unsigned short* dst = ((btype==0) ? Qp : Kp)
                          + ((size_t)bh*Sq + sb + rw)*DHq + hf*64;
      const unsigned short* srcl = &L[rw*LTS + hd*128 + hf*64];
#pragma unroll
      for (int i2=0;i2<8;i2++)
        *(s16x8*)&dst[i2*8] = *(const s16x8*)&srcl[i2*8];
    }
  } else {
    // ---- V: dump to LDS, transposed write to Vt[bh][dh][s] ----
#pragma unroll
    for (int mf=0;mf<4;mf++)
#pragma unroll
      for (int r=0;r<4;r++){
        const int rowl = wm*64+mf*16+g*4+r;
#pragma unroll
        for (int nf=0;nf<4;nf++)
          L[rowl*LTS + wn*64+nf*16+c] = f2bf(acc[mf][nf][r]);
      }
    __syncthreads();
    {
      const int dh2 = tid >> 1, hfr = (tid & 1) * 64;
      const int hd = dh2 >> 7, dh = dh2 & 127;
      const int bh = b*Hq + h0 + hd;
      unsigned short buf[64];
#pragma unroll
      for (int i2=0;i2<64;i2++) buf[i2] = L[(hfr+i2)*LTS + dh2];
      unsigned short* dst = Vt + ((size_t)bh*DHq + dh)*Sq + sb + hfr;
#pragma unroll
      for (int i2=0;i2<8;i2++)
        *(s16x8*)&dst[i2*8] = *(const s16x8*)&buf[i2*8];
    }
  }
}

// ---------------- GEMM2: 8-phase 128x256, f32 out, row-scale folded --------
__global__ __launch_bounds__(512, 1) void k_gemm2_8ph(const unsigned short* __restrict__ A,
                                                      const unsigned short* __restrict__ Bt,
                                                      const float* __restrict__ bias,
                                                      const float* __restrict__ rscale,
                                                      float* __restrict__ C){
  const int K = 2048, N = 2048, NI = 16;
  const int bid = blockIdx.x;
  const int xcd = bid & 7, u = bid >> 3;
  const int m0 = (xcd*4 + (u & 3)) * 128;
  const int n0 = (u >> 2) * 256;

  const int tid = threadIdx.x;
  const int lane = tid & 63, w = tid >> 6, g = lane >> 4, c = lane & 15;
  const int wm = w >> 2, wn = w & 3;

  __shared__ __align__(16) unsigned short L[49152];   // 96 KB

  const int srow = tid >> 2, spc = tid & 3;
  const int ssw = (spc ^ ((srow >> 1) & 3)) << 3;
  const unsigned short* aSrc  = A  + (size_t)(m0 + srow      )*K + ssw;
  const unsigned short* bSrc0 = Bt + (size_t)(n0 + srow      )*K + ssw;
  const unsigned short* bSrc1 = Bt + (size_t)(n0 + srow + 128)*K + ssw;

  auto stA = [&](int t, int h){
    gload_lds16(aSrc + t*64 + h*32, &L[((t&1)*2 + h)*4096 + tid*8]);
  };
  auto stB = [&](int t, int h, int uu){
    const unsigned short* s = (uu==0) ? bSrc0 : bSrc1;
    gload_lds16(s + t*64 + h*32, &L[16384 + ((t&1)*2 + h)*8192 + uu*4096 + tid*8]);
  };

  int aoff[4], boff[4];
#pragma unroll
  for (int mf=0; mf<4; ++mf){
    int row = wm*64 + mf*16 + c;
    aoff[mf] = row*32 + ((g ^ ((row>>1)&3)) << 3);
  }
#pragma unroll
  for (int nf=0; nf<4; ++nf){
    int row = wn*64 + nf*16 + c;
    boff[nf] = row*32 + ((g ^ ((row>>1)&3)) << 3);
  }

  f32x4 acc[4][4];
#pragma unroll
  for (int i=0;i<4;i++)
#pragma unroll
    for (int j=0;j<4;j++)
#pragma unroll
      for (int r=0;r<4;r++) acc[i][j][r] = 0.f;

  auto RDA = [&](int b, int h, s16x8* af){
    const int ab = (b*2 + h)*4096;
#pragma unroll
    for (int mf=0; mf<4; ++mf) af[mf] = *(const s16x8*)&L[ab + aoff[mf]];
  };
  auto RDB = [&](int b, int h, int nh, s16x8* bf){
    const int bb = 16384 + (b*2 + h)*8192;
#pragma unroll
    for (int j=0; j<2; ++j) bf[j] = *(const s16x8*)&L[bb + boff[nh*2 + j]];
  };
  auto MM = [&](s16x8* af, s16x8* bf, int nh){
    __builtin_amdgcn_s_setprio(1);
#pragma unroll
    for (int mf=0; mf<4; ++mf)
#pragma unroll
      for (int j=0; j<2; ++j)
        acc[mf][nh*2+j] = __builtin_amdgcn_mfma_f32_16x16x32_bf16(af[mf], bf[j], acc[mf][nh*2+j], 0,0,0);
    __builtin_amdgcn_s_setprio(0);
  };
  auto BAR = [&](){
    __builtin_amdgcn_sched_barrier(0);
    __builtin_amdgcn_s_barrier();
    __builtin_amdgcn_sched_barrier(0);
  };

  stA(0,0); stB(0,0,0); stB(0,0,1);
  stA(0,1); stB(0,1,0); stB(0,1,1);
  stA(1,0); stB(1,0,0); stB(1,0,1);
  asm volatile("s_waitcnt vmcnt(3)" ::: "memory");
  __builtin_amdgcn_s_barrier();

  for (int i=0; i<NI; ++i){
    const int T0 = 2*i, T1 = 2*i + 1;
    const bool st = (i < NI-1);
    s16x8 af[4], bf[2];
    RDA(0,0,af); RDB(0,0,0,bf);
    stA(T1,1); stB(T1,1,0);
    BAR(); MM(af,bf,0); BAR();
    RDB(0,0,1,bf);
    stB(T1,1,1);
    BAR(); MM(af,bf,1); BAR();
    RDA(0,1,af); RDB(0,1,0,bf);
    if (st){ stA(T0+2,0); stB(T0+2,0,0); }
    BAR(); MM(af,bf,0); BAR();
    RDB(0,1,1,bf);
    if (st){ stB(T0+2,0,1); }
    __builtin_amdgcn_sched_barrier(0);
    if (st) asm volatile("s_waitcnt vmcnt(3)" ::: "memory");
    else    asm volatile("s_waitcnt vmcnt(0)" ::: "memory");
    BAR(); MM(af,bf,1); BAR();
    RDA(1,0,af); RDB(1,0,0,bf);
    if (st){ stA(T0+2,1); stB(T0+2,1,0); }
    BAR(); MM(af,bf,0); BAR();
    RDB(1,0,1,bf);
    if (st){ stB(T0+2,1,1); }
    BAR(); MM(af,bf,1); BAR();
    RDA(1,1,af); RDB(1,1,0,bf);
    if (st){ stA(T1+2,0); stB(T1+2,0,0); }
    BAR(); MM(af,bf,0); BAR();
    RDB(1,1,1,bf);
    if (st){ stB(T1+2,0,1); }
    __builtin_amdgcn_sched_barrier(0);
    if (st) asm volatile("s_waitcnt vmcnt(3)" ::: "memory");
    else    asm volatile("s_waitcnt vmcnt(0)" ::: "memory");
    BAR(); MM(af,bf,1); BAR();
  }

#pragma unroll
  for (int nf=0; nf<4; ++nf){
    const int col = n0 + wn*64 + nf*16 + c;
    const float bv = bias[col];
#pragma unroll
    for (int mf=0; mf<4; ++mf){
      const int row = m0 + wm*64 + mf*16 + g*4;
#pragma unroll
      for (int r=0; r<4; ++r)
        C[(size_t)(row+r)*N + col] = acc[mf][nf][r]*rscale[row+r] + bv;
    }
  }
}

// ---------------- row scale for out RMS-norm (folded into GEMM2) -----------
__global__ __launch_bounds__(256) void k_rowscale(const unsigned short* __restrict__ A,
                                                  float* __restrict__ sc){
  const int row = blockIdx.x;
  const int tid = threadIdx.x;
  s16x8 v = *(const s16x8*)&A[(size_t)row*Dq + tid*8];
  float ss = 0.f;
#pragma unroll
  for (int i=0;i<8;i++){ float f = bf2f((unsigned short)v[i]); ss += f*f; }
#pragma unroll
  for (int m=1;m<64;m<<=1) ss += __shfl_xor(ss, m);
  __shared__ float red[4];
  if ((tid&63)==0) red[tid>>6] = ss;
  __syncthreads();
  if (tid==0){
    float t = red[0]+red[1]+red[2]+red[3];
    sc[row] = rsqrtf(t*(1.f/2048.f) + 1e-6f);
  }
}

// ---------------- causal MFMA flash attention (swapped-operand) -------------
__global__ __launch_bounds__(256, 2) void k_attn(const unsigned short* __restrict__ Qp,
                                                 const unsigned short* __restrict__ Kp,
                                                 const unsigned short* __restrict__ Vt,
                                                 unsigned short* __restrict__ Ar){
  const int L = blockIdx.x;
  int bh, qtile;
  if (L < 256){ bh = L >> 3; qtile = 8 + (L & 7); }
  else { int Ml = L - 256; bh = Ml >> 3; qtile = 7 - (Ml & 7); }
  const int b = bh >> 4, h = bh & 15;
  const int tid = threadIdx.x;
  const int w = tid >> 6, lane = tid & 63, g = lane >> 4, c = lane & 15;
  const int r0w = qtile*128 + w*32;

  const unsigned short* Qh = Qp + (size_t)bh * Sq * DHq;
  const unsigned short* Kh = Kp + (size_t)bh * Sq * DHq;
  const unsigned short* Vh = Vt + (size_t)bh * DHq * Sq;

  __shared__ __align__(16) unsigned short Ks[2][64*128];   // 32 KB
  __shared__ __align__(16) unsigned short Vs[2][128*64];   // 32 KB
  __shared__ __align__(16) unsigned short Pl[4][32*64];    // 16 KB  (per-wave [q][k])
  unsigned short* Pw = &Pl[w][0];

  s16x8 qf[2][4];
#pragma unroll
  for (int mi=0;mi<2;mi++)
#pragma unroll
    for (int kc=0;kc<4;kc++)
      qf[mi][kc] = *(const s16x8*)&Qh[(size_t)(r0w + mi*16 + c)*DHq + kc*32 + g*8];

  f32x4 acc[2][8];
#pragma unroll
  for (int mi=0;mi<2;mi++)
#pragma unroll
    for (int dt=0;dt<8;dt++)
#pragma unroll
      for (int r=0;r<4;r++) acc[mi][dt][r] = 0.f;
  float m_r[2] = { -INFINITY, -INFINITY };
  float l_p[2] = { 0.f, 0.f };             // per-lane PARTIAL sums

  const int nsteps = 2*qtile + 2;

  auto stage = [&](int j0s, int bufi){
#pragma unroll
    for (int i=0;i<4;i++){
      int pk = tid + i*256;              // K: 1024 chunks of 16B
      int row = pk>>4, pcc = pk&15;
      gload_lds16(&Kh[(size_t)(j0s+row)*DHq + ((pcc^(row&7))<<3)], &Ks[bufi][pk*8]);
    }
#pragma unroll
    for (int i=0;i<4;i++){
      int pk = tid + i*256;              // V: 1024 chunks of 16B
      int row = pk>>3, pcc = pk&7;
      gload_lds16(&Vh[(size_t)row*Sq + j0s + ((pcc^(row&7))<<3)], &Vs[bufi][pk*8]);
    }
  };

  stage(0, 0);
  __syncthreads();

  for (int t=0; t<nsteps; ++t){
    const int j0 = t*64;
    if (t+1 < nsteps) stage((t+1)*64, (t+1)&1);

    if (j0 <= r0w + 31){
      const unsigned short* Kc = &Ks[t&1][0];
      const unsigned short* Vc = &Vs[t&1][0];

      // ---- S^T = K.Q^T ----
      f32x4 sv[2][4];
#pragma unroll
      for (int mi=0;mi<2;mi++)
#pragma unroll
        for (int js=0;js<4;js++)
#pragma unroll
          for (int r=0;r<4;r++) sv[mi][js][r] = 0.f;

      __builtin_amdgcn_s_setprio(1);
#pragma unroll
      for (int js=0;js<4;js++){
        s16x8 kf[4];
#pragma unroll
        for (int kc=0;kc<4;kc++)
          kf[kc] = *(const s16x8*)&Kc[(js*16 + c)*128 + (((kc*4+g)^(c&7))<<3)];
#pragma unroll
        for (int mi=0;mi<2;mi++)
#pragma unroll
          for (int kc=0;kc<4;kc++)
            sv[mi][js] = __builtin_amdgcn_mfma_f32_16x16x32_bf16(kf[kc], qf[mi][kc], sv[mi][js], 0,0,0);
      }
      __builtin_amdgcn_s_setprio(0);

      if (j0 + 63 > r0w){
#pragma unroll
        for (int mi=0;mi<2;mi++){
          const int q = r0w + mi*16 + c;
#pragma unroll
          for (int js=0;js<4;js++)
#pragma unroll
            for (int r=0;r<4;r++)
              if (j0 + js*16 + g*4 + r > q) sv[mi][js][r] = -INFINITY;
        }
      }

      float pmx[2];
#pragma unroll
      for (int mi=0;mi<2;mi++){
        float mx = fmaxf(fmaxf(sv[mi][0][0],sv[mi][0][1]), fmaxf(sv[mi][0][2],sv[mi][0][3]));
#pragma unroll
        for (int js=1;js<4;js++){
          float a = fmaxf(fmaxf(sv[mi][js][0],sv[mi][js][1]), fmaxf(sv[mi][js][2],sv[mi][js][3]));
          mx = fmaxf(mx, a);
        }
        mx = fmaxf(mx, __shfl_xor(mx, 16));
        mx = fmaxf(mx, __shfl_xor(mx, 32));
        pmx[mi] = mx;
      }
      int need = (pmx[0] > m_r[0] + 8.f) | (pmx[1] > m_r[1] + 8.f);
      if (__any(need)){
#pragma unroll
        for (int mi=0;mi<2;mi++){
          float mnew = fmaxf(m_r[mi], pmx[mi]);
          float corr = exp2f(m_r[mi] - mnew);
          l_p[mi] *= corr;
          m_r[mi] = mnew;
#pragma unroll
          for (int dt=0;dt<8;dt++)
#pragma unroll
            for (int r=0;r<4;r++) acc[mi][dt][r] *= corr;
        }
      }
#pragma unroll
      for (int mi=0;mi<2;mi++){
        const float mm = m_r[mi];
        const int rowoff = (mi*16 + c)*64;
#pragma unroll
        for (int js=0;js<4;js++){
          float e0 = exp2f(sv[mi][js][0] - mm);
          float e1 = exp2f(sv[mi][js][1] - mm);
          float e2 = exp2f(sv[mi][js][2] - mm);
          float e3 = exp2f(sv[mi][js][3] - mm);
          l_p[mi] += (e0+e1)+(e2+e3);
          uint2 pk2;
          pk2.x = cvtpk_bf16(e0, e1);
          pk2.y = cvtpk_bf16(e2, e3);
          const int kc8 = js*2 + (g>>1);
          *(uint2*)&Pw[rowoff + ((kc8 ^ (c&7))<<3) + (g&1)*4] = pk2;
        }
      }

      s16x8 pfr[2][2];
#pragma unroll
      for (int mi=0;mi<2;mi++)
#pragma unroll
        for (int kc=0;kc<2;kc++)
          pfr[mi][kc] = *(const s16x8*)&Pw[(mi*16 + c)*64 + (((kc*4+g)^(c&7))<<3)];
      __builtin_amdgcn_s_setprio(1);
#pragma unroll
      for (int dt=0; dt<8; dt++){
#pragma unroll
        for (int kc=0;kc<2;kc++){
          s16x8 vfr = *(const s16x8*)&Vc[(dt*16 + c)*64 + (((kc*4+g)^(c&7))<<3)];
#pragma unroll
          for (int mi=0;mi<2;mi++)
            acc[mi][dt] = __builtin_amdgcn_mfma_f32_16x16x32_bf16(vfr, pfr[mi][kc], acc[mi][dt], 0,0,0);
        }
      }
      __builtin_amdgcn_s_setprio(0);
    }
    __syncthreads();
  }

#pragma unroll
  for (int mi=0;mi<2;mi++){
    float l = l_p[mi];
    l += __shfl_xor(l, 16);
    l += __shfl_xor(l, 32);
    const float inv = 1.f / l;
    const int row = r0w + mi*16 + c;
    unsigned short* dst = &Ar[((size_t)(b*Sq + row))*Dq + h*DHq];
#pragma unroll
    for (int dt=0; dt<8; dt++){
      uint2 o2;
      o2.x = cvtpk_bf16(acc[mi][dt][0]*inv, acc[mi][dt][1]*inv);
      o2.y = cvtpk_bf16(acc[mi][dt][2]*inv, acc[mi][dt][3]*inv);
      *(uint2*)&dst[dt*16 + g*4] = o2;
    }
  }
}

extern "C" void kernel_launch(void* const* d_in, const int* in_sizes, int n_in,
                              void* d_out, int out_size, void* d_ws, size_t ws_size,
                              hipStream_t stream){
  const float* x     = (const float*)d_in[0];
  const float* rp    = (const float*)d_in[1];
  const float* Win   = (const float*)d_in[2];
  const float* b_in  = (const float*)d_in[3];
  const float* Wout  = (const float*)d_in[4];
  const float* b_out = (const float*)d_in[5];
  const float* qk_w  = (const float*)d_in[6];
  const float* out_w = (const float*)d_in[7];
  float* outp = (float*)d_out;

  if (ws_size < (160ull<<20)) return;   // need 160 MiB scratch

  char* ws = (char*)d_ws;
  unsigned short* Xb    = (unsigned short*)(ws);                 // 16 MiB
  unsigned short* Wb    = (unsigned short*)(ws + (16ull<<20));   // 24 MiB
  unsigned short* Woutb = (unsigned short*)(ws + (40ull<<20));   //  8 MiB
  float*          rsc   = (float*)         (ws + (48ull<<20));   // 16 KiB
  unsigned short* Qp    = (unsigned short*)(ws + (96ull<<20));   // 16 MiB
  unsigned short* Kp    = (unsigned short*)(ws + (112ull<<20));  // 16 MiB
  unsigned short* Vt    = (unsigned short*)(ws + (128ull<<20));  // 16 MiB
  unsigned short* Ar    = (unsigned short*)(ws + (144ull<<20));  // 16 MiB

  // 1) fused converts (out_w folded into Woutb)
  k_convert3<<<2048, 256, 0, stream>>>(x, Win, Wout, out_w, Xb, Wb, Woutb);
  // 2) QKV GEMM + fused RoPE/RMS-norm/V-transpose epilogue
  k_gemm1f<<<768, 512, 0, stream>>>(Xb, Wb, b_in, rp, qk_w, Qp, Kp, Vt);
  // 3) causal flash attention (pair-balanced 1D grid)
  k_attn<<<512, 256, 0, stream>>>(Qp, Kp, Vt, Ar);
  // 4) row scales for out RMS-norm
  k_rowscale<<<Bq*Sq, 256, 0, stream>>>(Ar, rsc);
  // 5) Out = (Ar . (out_w*Wout)^T) * rscale + b_out
  k_gemm2_8ph<<<256, 512, 0, stream>>>(Ar, Woutb, b_out, rsc, outp);
}

// Round 12
// 269.390 us; speedup vs baseline: 2.8045x; 1.0013x over previous
//
#include <hip/hip_runtime.h>
#include <cstdint>
#include <cstddef>

// Problem constants (B,S,D,H) = (2,2048,2048,16), DH=128
#define Bq  2
#define Sq  2048
#define Dq  2048
#define Hq  16
#define DHq 128
#define E3q 6144   // 3*D

typedef __attribute__((ext_vector_type(8))) short s16x8;   // 8 bf16 (4 VGPRs)
typedef __attribute__((ext_vector_type(4))) float f32x4;   // MFMA accumulator

__device__ __forceinline__ unsigned short f2bf(float f){
  union { float f; unsigned u; } v; v.f = f;
  unsigned r = v.u + 0x7FFFu + ((v.u >> 16) & 1u);   // round-to-nearest-even
  return (unsigned short)(r >> 16);
}
__device__ __forceinline__ float bf2f(unsigned short b){
  union { unsigned u; float f; } v; v.u = ((unsigned)b) << 16;
  return v.f;
}
// pack two f32 -> two bf16 in one op (no builtin on gfx950; T12 recipe)
__device__ __forceinline__ unsigned cvtpk_bf16(float lo, float hi){
  unsigned r;
  asm("v_cvt_pk_bf16_f32 %0, %1, %2" : "=v"(r) : "v"(lo), "v"(hi));
  return r;
}

// async global->LDS, 16B per lane. LDS dest must be wave-uniform base + lane*16.
__device__ __forceinline__ void gload_lds16(const void* g, void* l){
  __builtin_amdgcn_global_load_lds(
      (const __attribute__((address_space(1))) void*)g,
      (__attribute__((address_space(3))) void*)l, 16, 0, 0);
}

// ------ fused fp32->bf16 converts + RoPE (cos,sin) table ------
// Wout gets out_w folded in. rpcs[s*64+p] = (cos, sin) of rp[s][p].
__global__ __launch_bounds__(256) void k_convert3(const float* __restrict__ x,
                                                  const float* __restrict__ win,
                                                  const float* __restrict__ wout,
                                                  const float* __restrict__ out_w,
                                                  const float* __restrict__ rp,
                                                  unsigned short* __restrict__ xb,
                                                  unsigned short* __restrict__ wb,
                                                  unsigned short* __restrict__ woutb,
                                                  float2* __restrict__ rpcs){
  const int NX = (Bq*Sq*Dq)/4;
  const int NW = (E3q*Dq)/4;
  const int NO = (Dq*Dq)/4;
  const int NR = (Sq*64)/4;
  const int total = NX + NW + NO + NR;
  int stride = gridDim.x * blockDim.x;
  for (int i = blockIdx.x*blockDim.x + threadIdx.x; i < total; i += stride){
    if (i < NX + NW){
      const float* src; unsigned short* dst; int j;
      if (i < NX){ src = x; dst = xb; j = i; }
      else { src = win; dst = wb; j = i - NX; }
      float4 v = reinterpret_cast<const float4*>(src)[j];
      ushort4 o;
      o.x = f2bf(v.x); o.y = f2bf(v.y); o.z = f2bf(v.z); o.w = f2bf(v.w);
      reinterpret_cast<ushort4*>(dst)[j] = o;
    } else if (i < NX + NW + NO){
      int j = i - NX - NW;
      float4 v = reinterpret_cast<const float4*>(wout)[j];
      float4 w = reinterpret_cast<const float4*>(out_w)[j & 511];
      ushort4 o;
      o.x = f2bf(v.x*w.x); o.y = f2bf(v.y*w.y); o.z = f2bf(v.z*w.z); o.w = f2bf(v.w*w.w);
      reinterpret_cast<ushort4*>(woutb)[j] = o;
    } else {
      int j = i - NX - NW - NO;
      float4 a = reinterpret_cast<const float4*>(rp)[j];
      float sn0,cs0,sn1,cs1,sn2,cs2,sn3,cs3;
      sincosf(a.x,&sn0,&cs0); sincosf(a.y,&sn1,&cs1);
      sincosf(a.z,&sn2,&cs2); sincosf(a.w,&sn3,&cs3);
      float4 p0 = make_float4(cs0,sn0,cs1,sn1);
      float4 p1 = make_float4(cs2,sn2,cs3,sn3);
      reinterpret_cast<float4*>(rpcs)[j*2  ] = p0;
      reinterpret_cast<float4*>(rpcs)[j*2+1] = p1;
    }
  }
}

// ---------------- GEMM1 fused: 8-phase 128x256 + RoPE/RMS/transpose epilogue
// QKV[m, n] = sum_k X[m,k]*Win[n,k] + b_in[n], M=4096, N=6144, K=2048.
// Epilogue uses the precomputed (cos,sin) table instead of per-element sincosf
// (was 64 sincosf/thread ~= 29us of the kernel; table is 1MB, L2-resident).
__global__ __launch_bounds__(512, 1) void k_gemm1f(const unsigned short* __restrict__ A,
                                                   const unsigned short* __restrict__ Bt,
                                                   const float* __restrict__ bias,
                                                   const float2* __restrict__ rpcs,
                                                   const float* __restrict__ qk_w,
                                                   unsigned short* __restrict__ Qp,
                                                   unsigned short* __restrict__ Kp,
                                                   unsigned short* __restrict__ Vt){
  const int K = 2048, NI = 16;
  const int bid = blockIdx.x;
  const int xcd = bid & 7, u = bid >> 3;          // 96 per XCD
  const int m0 = (xcd*4 + (u & 3)) * 128;         // 32 M-tiles, 4 per XCD
  const int n0 = (u >> 2) * 256;                  // 24 N-tiles, col-major in chunk

  const int tid = threadIdx.x;
  const int lane = tid & 63, w = tid >> 6, g = lane >> 4, c = lane & 15;
  const int wm = w >> 2, wn = w & 3;              // 2 x 4 waves

  __shared__ __align__(16) unsigned short L[49152];   // 96 KB

  const int srow = tid >> 2, spc = tid & 3;
  const int ssw = (spc ^ ((srow >> 1) & 3)) << 3;
  const unsigned short* aSrc  = A  + (size_t)(m0 + srow      )*K + ssw;
  const unsigned short* bSrc0 = Bt + (size_t)(n0 + srow      )*K + ssw;
  const unsigned short* bSrc1 = Bt + (size_t)(n0 + srow + 128)*K + ssw;

  auto stA = [&](int t, int h){
    gload_lds16(aSrc + t*64 + h*32, &L[((t&1)*2 + h)*4096 + tid*8]);
  };
  auto stB = [&](int t, int h, int uu){
    const unsigned short* s = (uu==0) ? bSrc0 : bSrc1;
    gload_lds16(s + t*64 + h*32, &L[16384 + ((t&1)*2 + h)*8192 + uu*4096 + tid*8]);
  };

  int aoff[4], boff[4];
#pragma unroll
  for (int mf=0; mf<4; ++mf){
    int row = wm*64 + mf*16 + c;
    aoff[mf] = row*32 + ((g ^ ((row>>1)&3)) << 3);
  }
#pragma unroll
  for (int nf=0; nf<4; ++nf){
    int row = wn*64 + nf*16 + c;
    boff[nf] = row*32 + ((g ^ ((row>>1)&3)) << 3);
  }

  f32x4 acc[4][4];
#pragma unroll
  for (int i=0;i<4;i++)
#pragma unroll
    for (int j=0;j<4;j++)
#pragma unroll
      for (int r=0;r<4;r++) acc[i][j][r] = 0.f;

  auto RDA = [&](int b, int h, s16x8* af){
    const int ab = (b*2 + h)*4096;
#pragma unroll
    for (int mf=0; mf<4; ++mf) af[mf] = *(const s16x8*)&L[ab + aoff[mf]];
  };
  auto RDB = [&](int b, int h, int nh, s16x8* bf){
    const int bb = 16384 + (b*2 + h)*8192;
#pragma unroll
    for (int j=0; j<2; ++j) bf[j] = *(const s16x8*)&L[bb + boff[nh*2 + j]];
  };
  auto MM = [&](s16x8* af, s16x8* bf, int nh){
    __builtin_amdgcn_s_setprio(1);
#pragma unroll
    for (int mf=0; mf<4; ++mf)
#pragma unroll
      for (int j=0; j<2; ++j)
        acc[mf][nh*2+j] = __builtin_amdgcn_mfma_f32_16x16x32_bf16(af[mf], bf[j], acc[mf][nh*2+j], 0,0,0);
    __builtin_amdgcn_s_setprio(0);
  };
  auto BAR = [&](){
    __builtin_amdgcn_sched_barrier(0);
    __builtin_amdgcn_s_barrier();
    __builtin_amdgcn_sched_barrier(0);
  };

  stA(0,0); stB(0,0,0); stB(0,0,1);
  stA(0,1); stB(0,1,0); stB(0,1,1);
  stA(1,0); stB(1,0,0); stB(1,0,1);
  asm volatile("s_waitcnt vmcnt(3)" ::: "memory");
  __builtin_amdgcn_s_barrier();

  for (int i=0; i<NI; ++i){
    const int T0 = 2*i, T1 = 2*i + 1;
    const bool st = (i < NI-1);
    s16x8 af[4], bf[2];
    RDA(0,0,af); RDB(0,0,0,bf);
    stA(T1,1); stB(T1,1,0);
    BAR(); MM(af,bf,0); BAR();
    RDB(0,0,1,bf);
    stB(T1,1,1);
    BAR(); MM(af,bf,1); BAR();
    RDA(0,1,af); RDB(0,1,0,bf);
    if (st){ stA(T0+2,0); stB(T0+2,0,0); }
    BAR(); MM(af,bf,0); BAR();
    RDB(0,1,1,bf);
    if (st){ stB(T0+2,0,1); }
    __builtin_amdgcn_sched_barrier(0);
    if (st) asm volatile("s_waitcnt vmcnt(3)" ::: "memory");
    else    asm volatile("s_waitcnt vmcnt(0)" ::: "memory");
    BAR(); MM(af,bf,1); BAR();
    RDA(1,0,af); RDB(1,0,0,bf);
    if (st){ stA(T0+2,1); stB(T0+2,1,0); }
    BAR(); MM(af,bf,0); BAR();
    RDB(1,0,1,bf);
    if (st){ stB(T0+2,1,1); }
    BAR(); MM(af,bf,1); BAR();
    RDA(1,1,af); RDB(1,1,0,bf);
    if (st){ stA(T1+2,0); stB(T1+2,0,0); }
    BAR(); MM(af,bf,0); BAR();
    RDB(1,1,1,bf);
    if (st){ stB(T1+2,0,1); }
    __builtin_amdgcn_sched_barrier(0);
    if (st) asm volatile("s_waitcnt vmcnt(3)" ::: "memory");
    else    asm volatile("s_waitcnt vmcnt(0)" ::: "memory");
    BAR(); MM(af,bf,1); BAR();
  }

  // ================= fused epilogue =================
  const int btype = (n0 < 2048) ? 0 : (n0 < 4096) ? 1 : 2;   // Q, K, V
  const int b  = m0 >> 11;                 // batch
  const int sb = m0 & 2047;                // token base
  const int h0 = (n0 & 2047) >> 7;         // base head of this 256-col tile
  const int LTS = 264;                     // padded bf16 row stride
  const float QSCALE = 0.08838834764831845f * 1.4426950408889634f;

  // bias add (b_in) into acc
#pragma unroll
  for (int nf=0; nf<4; ++nf){
    const float bv = bias[n0 + wn*64 + nf*16 + c];
#pragma unroll
    for (int mf=0; mf<4; ++mf)
#pragma unroll
      for (int r=0; r<4; ++r) acc[mf][nf][r] += bv;
  }

  __syncthreads();   // main-loop LDS use finished; L free

  if (btype < 2){
    // ---- per-row sumsq over this wave's 64 cols ----
    float s2[4][4];
#pragma unroll
    for (int mf=0;mf<4;mf++)
#pragma unroll
      for (int r=0;r<4;r++){
        float s = 0.f;
#pragma unroll
        for (int nf=0;nf<4;nf++){ float v = acc[mf][nf][r]; s += v*v; }
        s2[mf][r] = s;
      }
#pragma unroll
    for (int m=1;m<16;m<<=1)
#pragma unroll
      for (int mf=0;mf<4;mf++)
#pragma unroll
        for (int r=0;r<4;r++) s2[mf][r] += __shfl_xor(s2[mf][r], m);
    // cross-wave (two waves per head) via LDS [128 rows][2 heads]
    float* Ssum = (float*)&L[0];
    if (c==0 && (wn&1)==0){
#pragma unroll
      for (int mf=0;mf<4;mf++)
#pragma unroll
        for (int r=0;r<4;r++)
          Ssum[(wm*64+mf*16+g*4+r)*2 + (wn>>1)] = s2[mf][r];
    }
    __syncthreads();
    if (c==0 && (wn&1)==1){
#pragma unroll
      for (int mf=0;mf<4;mf++)
#pragma unroll
        for (int r=0;r<4;r++)
          Ssum[(wm*64+mf*16+g*4+r)*2 + (wn>>1)] += s2[mf][r];
    }
    __syncthreads();
    float rsc[4][4];
#pragma unroll
    for (int mf=0;mf<4;mf++)
#pragma unroll
      for (int r=0;r<4;r++)
        rsc[mf][r] = rsqrtf(Ssum[(wm*64+mf*16+g*4+r)*2 + (wn>>1)]*(1.f/128.f) + 1e-6f);
    __syncthreads();   // done with Ssum; L reused as output tile

    const float qmul = (btype==0) ? QSCALE : 1.f;
    float wq[4];
    int pp[4];
#pragma unroll
    for (int nf=0;nf<4;nf++){
      wq[nf] = qk_w[(wn*64+nf*16+c)&127];
      pp[nf] = ((wn*64+nf*16+c)&127) >> 1;
    }

    // RoPE (table) + scale -> LDS tile [128][LTS]
#pragma unroll
    for (int mf=0;mf<4;mf++)
#pragma unroll
      for (int r=0;r<4;r++){
        const int rowl = wm*64+mf*16+g*4+r;
        const int s = sb + rowl;
        const float sc = rsc[mf][r] * qmul;
#pragma unroll
        for (int nf=0;nf<4;nf++){
          float2 t = rpcs[s*64 + pp[nf]];
          float v  = acc[mf][nf][r];
          float pv = __shfl_xor(v, 1);
          float rot = ((c&1)==0) ? (v*t.x - pv*t.y) : (pv*t.y + v*t.x);
          L[rowl*LTS + wn*64+nf*16+c] = f2bf(rot * sc * wq[nf]);
        }
      }
    __syncthreads();
    // coalesced write: thread -> (row, head, half), 64 bf16 each
    {
      const int rw = tid >> 2, hd = (tid>>1)&1, hf = tid&1;
      const int bh = b*Hq + h0 + hd;
      unsigned short* dst = ((btype==0) ? Qp : Kp)
                          + ((size_t)bh*Sq + sb + rw)*DHq + hf*64;
      const unsigned short* srcl = &L[rw*LTS + hd*128 + hf*64];
#pragma unroll
      for (int i2=0;i2<8;i2++)
        *(s16x8*)&dst[i2*8] = *(const s16x8*)&srcl[i2*8];
    }
  } else {
    // ---- V: dump to LDS, transposed write to Vt[bh][dh][s] ----
#pragma unroll
    for (int mf=0;mf<4;mf++)
#pragma unroll
      for (int r=0;r<4;r++){
        const int rowl = wm*64+mf*16+g*4+r;
#pragma unroll
        for (int nf=0;nf<4;nf++)
          L[rowl*LTS + wn*64+nf*16+c] = f2bf(acc[mf][nf][r]);
      }
    __syncthreads();
    {
      const int dh2 = tid >> 1, hfr = (tid & 1) * 64;
      const int hd = dh2 >> 7, dh = dh2 & 127;
      const int bh = b*Hq + h0 + hd;
      unsigned short buf[64];
#pragma unroll
      for (int i2=0;i2<64;i2++) buf[i2] = L[(hfr+i2)*LTS + dh2];
      unsigned short* dst = Vt + ((size_t)bh*DHq + dh)*Sq + sb + hfr;
#pragma unroll
      for (int i2=0;i2<8;i2++)
        *(s16x8*)&dst[i2*8] = *(const s16x8*)&buf[i2*8];
    }
  }
}

// ---------------- GEMM2: 8-phase 128x256, f32 out, row-scale folded --------
__global__ __launch_bounds__(512, 1) void k_gemm2_8ph(const unsigned short* __restrict__ A,
                                                      const unsigned short* __restrict__ Bt,
                                                      const float* __restrict__ bias,
                                                      const float* __restrict__ rscale,
                                                      float* __restrict__ C){
  const int K = 2048, N = 2048, NI = 16;
  const int bid = blockIdx.x;
  const int xcd = bid & 7, u = bid >> 3;
  const int m0 = (xcd*4 + (u & 3)) * 128;
  const int n0 = (u >> 2) * 256;

  const int tid = threadIdx.x;
  const int lane = tid & 63, w = tid >> 6, g = lane >> 4, c = lane & 15;
  const int wm = w >> 2, wn = w & 3;

  __shared__ __align__(16) unsigned short L[49152];   // 96 KB

  const int srow = tid >> 2, spc = tid & 3;
  const int ssw = (spc ^ ((srow >> 1) & 3)) << 3;
  const unsigned short* aSrc  = A  + (size_t)(m0 + srow      )*K + ssw;
  const unsigned short* bSrc0 = Bt + (size_t)(n0 + srow      )*K + ssw;
  const unsigned short* bSrc1 = Bt + (size_t)(n0 + srow + 128)*K + ssw;

  auto stA = [&](int t, int h){
    gload_lds16(aSrc + t*64 + h*32, &L[((t&1)*2 + h)*4096 + tid*8]);
  };
  auto stB = [&](int t, int h, int uu){
    const unsigned short* s = (uu==0) ? bSrc0 : bSrc1;
    gload_lds16(s + t*64 + h*32, &L[16384 + ((t&1)*2 + h)*8192 + uu*4096 + tid*8]);
  };

  int aoff[4], boff[4];
#pragma unroll
  for (int mf=0; mf<4; ++mf){
    int row = wm*64 + mf*16 + c;
    aoff[mf] = row*32 + ((g ^ ((row>>1)&3)) << 3);
  }
#pragma unroll
  for (int nf=0; nf<4; ++nf){
    int row = wn*64 + nf*16 + c;
    boff[nf] = row*32 + ((g ^ ((row>>1)&3)) << 3);
  }

  f32x4 acc[4][4];
#pragma unroll
  for (int i=0;i<4;i++)
#pragma unroll
    for (int j=0;j<4;j++)
#pragma unroll
      for (int r=0;r<4;r++) acc[i][j][r] = 0.f;

  auto RDA = [&](int b, int h, s16x8* af){
    const int ab = (b*2 + h)*4096;
#pragma unroll
    for (int mf=0; mf<4; ++mf) af[mf] = *(const s16x8*)&L[ab + aoff[mf]];
  };
  auto RDB = [&](int b, int h, int nh, s16x8* bf){
    const int bb = 16384 + (b*2 + h)*8192;
#pragma unroll
    for (int j=0; j<2; ++j) bf[j] = *(const s16x8*)&L[bb + boff[nh*2 + j]];
  };
  auto MM = [&](s16x8* af, s16x8* bf, int nh){
    __builtin_amdgcn_s_setprio(1);
#pragma unroll
    for (int mf=0; mf<4; ++mf)
#pragma unroll
      for (int j=0; j<2; ++j)
        acc[mf][nh*2+j] = __builtin_amdgcn_mfma_f32_16x16x32_bf16(af[mf], bf[j], acc[mf][nh*2+j], 0,0,0);
    __builtin_amdgcn_s_setprio(0);
  };
  auto BAR = [&](){
    __builtin_amdgcn_sched_barrier(0);
    __builtin_amdgcn_s_barrier();
    __builtin_amdgcn_sched_barrier(0);
  };

  stA(0,0); stB(0,0,0); stB(0,0,1);
  stA(0,1); stB(0,1,0); stB(0,1,1);
  stA(1,0); stB(1,0,0); stB(1,0,1);
  asm volatile("s_waitcnt vmcnt(3)" ::: "memory");
  __builtin_amdgcn_s_barrier();

  for (int i=0; i<NI; ++i){
    const int T0 = 2*i, T1 = 2*i + 1;
    const bool st = (i < NI-1);
    s16x8 af[4], bf[2];
    RDA(0,0,af); RDB(0,0,0,bf);
    stA(T1,1); stB(T1,1,0);
    BAR(); MM(af,bf,0); BAR();
    RDB(0,0,1,bf);
    stB(T1,1,1);
    BAR(); MM(af,bf,1); BAR();
    RDA(0,1,af); RDB(0,1,0,bf);
    if (st){ stA(T0+2,0); stB(T0+2,0,0); }
    BAR(); MM(af,bf,0); BAR();
    RDB(0,1,1,bf);
    if (st){ stB(T0+2,0,1); }
    __builtin_amdgcn_sched_barrier(0);
    if (st) asm volatile("s_waitcnt vmcnt(3)" ::: "memory");
    else    asm volatile("s_waitcnt vmcnt(0)" ::: "memory");
    BAR(); MM(af,bf,1); BAR();
    RDA(1,0,af); RDB(1,0,0,bf);
    if (st){ stA(T0+2,1); stB(T0+2,1,0); }
    BAR(); MM(af,bf,0); BAR();
    RDB(1,0,1,bf);
    if (st){ stB(T0+2,1,1); }
    BAR(); MM(af,bf,1); BAR();
    RDA(1,1,af); RDB(1,1,0,bf);
    if (st){ stA(T1+2,0); stB(T1+2,0,0); }
    BAR(); MM(af,bf,0); BAR();
    RDB(1,1,1,bf);
    if (st){ stB(T1+2,0,1); }
    __builtin_amdgcn_sched_barrier(0);
    if (st) asm volatile("s_waitcnt vmcnt(3)" ::: "memory");
    else    asm volatile("s_waitcnt vmcnt(0)" ::: "memory");
    BAR(); MM(af,bf,1); BAR();
  }

#pragma unroll
  for (int nf=0; nf<4; ++nf){
    const int col = n0 + wn*64 + nf*16 + c;
    const float bv = bias[col];
#pragma unroll
    for (int mf=0; mf<4; ++mf){
      const int row = m0 + wm*64 + mf*16 + g*4;
#pragma unroll
      for (int r=0; r<4; ++r)
        C[(size_t)(row+r)*N + col] = acc[mf][nf][r]*rscale[row+r] + bv;
    }
  }
}

// ---------------- row scale for out RMS-norm (folded into GEMM2) -----------
__global__ __launch_bounds__(256) void k_rowscale(const unsigned short* __restrict__ A,
                                                  float* __restrict__ sc){
  const int row = blockIdx.x;
  const int tid = threadIdx.x;
  s16x8 v = *(const s16x8*)&A[(size_t)row*Dq + tid*8];
  float ss = 0.f;
#pragma unroll
  for (int i=0;i<8;i++){ float f = bf2f((unsigned short)v[i]); ss += f*f; }
#pragma unroll
  for (int m=1;m<64;m<<=1) ss += __shfl_xor(ss, m);
  __shared__ float red[4];
  if ((tid&63)==0) red[tid>>6] = ss;
  __syncthreads();
  if (tid==0){
    float t = red[0]+red[1]+red[2]+red[3];
    sc[row] = rsqrtf(t*(1.f/2048.f) + 1e-6f);
  }
}

// ---------------- causal MFMA flash attention (swapped-operand) -------------
__global__ __launch_bounds__(256, 2) void k_attn(const unsigned short* __restrict__ Qp,
                                                 const unsigned short* __restrict__ Kp,
                                                 const unsigned short* __restrict__ Vt,
                                                 unsigned short* __restrict__ Ar){
  const int L = blockIdx.x;
  int bh, qtile;
  if (L < 256){ bh = L >> 3; qtile = 8 + (L & 7); }
  else { int Ml = L - 256; bh = Ml >> 3; qtile = 7 - (Ml & 7); }
  const int b = bh >> 4, h = bh & 15;
  const int tid = threadIdx.x;
  const int w = tid >> 6, lane = tid & 63, g = lane >> 4, c = lane & 15;
  const int r0w = qtile*128 + w*32;

  const unsigned short* Qh = Qp + (size_t)bh * Sq * DHq;
  const unsigned short* Kh = Kp + (size_t)bh * Sq * DHq;
  const unsigned short* Vh = Vt + (size_t)bh * DHq * Sq;

  __shared__ __align__(16) unsigned short Ks[2][64*128];   // 32 KB
  __shared__ __align__(16) unsigned short Vs[2][128*64];   // 32 KB
  __shared__ __align__(16) unsigned short Pl[4][32*64];    // 16 KB  (per-wave [q][k])
  unsigned short* Pw = &Pl[w][0];

  s16x8 qf[2][4];
#pragma unroll
  for (int mi=0;mi<2;mi++)
#pragma unroll
    for (int kc=0;kc<4;kc++)
      qf[mi][kc] = *(const s16x8*)&Qh[(size_t)(r0w + mi*16 + c)*DHq + kc*32 + g*8];

  f32x4 acc[2][8];
#pragma unroll
  for (int mi=0;mi<2;mi++)
#pragma unroll
    for (int dt=0;dt<8;dt++)
#pragma unroll
      for (int r=0;r<4;r++) acc[mi][dt][r] = 0.f;
  float m_r[2] = { -INFINITY, -INFINITY };
  float l_p[2] = { 0.f, 0.f };             // per-lane PARTIAL sums

  const int nsteps = 2*qtile + 2;

  auto stage = [&](int j0s, int bufi){
#pragma unroll
    for (int i=0;i<4;i++){
      int pk = tid + i*256;              // K: 1024 chunks of 16B
      int row = pk>>4, pcc = pk&15;
      gload_lds16(&Kh[(size_t)(j0s+row)*DHq + ((pcc^(row&7))<<3)], &Ks[bufi][pk*8]);
    }
#pragma unroll
    for (int i=0;i<4;i++){
      int pk = tid + i*256;              // V: 1024 chunks of 16B
      int row = pk>>3, pcc = pk&7;
      gload_lds16(&Vh[(size_t)row*Sq + j0s + ((pcc^(row&7))<<3)], &Vs[bufi][pk*8]);
    }
  };

  stage(0, 0);
  __syncthreads();

  for (int t=0; t<nsteps; ++t){
    const int j0 = t*64;
    if (t+1 < nsteps) stage((t+1)*64, (t+1)&1);

    if (j0 <= r0w + 31){
      const unsigned short* Kc = &Ks[t&1][0];
      const unsigned short* Vc = &Vs[t&1][0];

      // ---- S^T = K.Q^T ----
      f32x4 sv[2][4];
#pragma unroll
      for (int mi=0;mi<2;mi++)
#pragma unroll
        for (int js=0;js<4;js++)
#pragma unroll
          for (int r=0;r<4;r++) sv[mi][js][r] = 0.f;

      __builtin_amdgcn_s_setprio(1);
#pragma unroll
      for (int js=0;js<4;js++){
        s16x8 kf[4];
#pragma unroll
        for (int kc=0;kc<4;kc++)
          kf[kc] = *(const s16x8*)&Kc[(js*16 + c)*128 + (((kc*4+g)^(c&7))<<3)];
#pragma unroll
        for (int mi=0;mi<2;mi++)
#pragma unroll
          for (int kc=0;kc<4;kc++)
            sv[mi][js] = __builtin_amdgcn_mfma_f32_16x16x32_bf16(kf[kc], qf[mi][kc], sv[mi][js], 0,0,0);
      }
      __builtin_amdgcn_s_setprio(0);

      if (j0 + 63 > r0w){
#pragma unroll
        for (int mi=0;mi<2;mi++){
          const int q = r0w + mi*16 + c;
#pragma unroll
          for (int js=0;js<4;js++)
#pragma unroll
            for (int r=0;r<4;r++)
              if (j0 + js*16 + g*4 + r > q) sv[mi][js][r] = -INFINITY;
        }
      }

      float pmx[2];
#pragma unroll
      for (int mi=0;mi<2;mi++){
        float mx = fmaxf(fmaxf(sv[mi][0][0],sv[mi][0][1]), fmaxf(sv[mi][0][2],sv[mi][0][3]));
#pragma unroll
        for (int js=1;js<4;js++){
          float a = fmaxf(fmaxf(sv[mi][js][0],sv[mi][js][1]), fmaxf(sv[mi][js][2],sv[mi][js][3]));
          mx = fmaxf(mx, a);
        }
        mx = fmaxf(mx, __shfl_xor(mx, 16));
        mx = fmaxf(mx, __shfl_xor(mx, 32));
        pmx[mi] = mx;
      }
      int need = (pmx[0] > m_r[0] + 8.f) | (pmx[1] > m_r[1] + 8.f);
      if (__any(need)){
#pragma unroll
        for (int mi=0;mi<2;mi++){
          float mnew = fmaxf(m_r[mi], pmx[mi]);
          float corr = exp2f(m_r[mi] - mnew);
          l_p[mi] *= corr;
          m_r[mi] = mnew;
#pragma unroll
          for (int dt=0;dt<8;dt++)
#pragma unroll
            for (int r=0;r<4;r++) acc[mi][dt][r] *= corr;
        }
      }
#pragma unroll
      for (int mi=0;mi<2;mi++){
        const float mm = m_r[mi];
        const int rowoff = (mi*16 + c)*64;
#pragma unroll
        for (int js=0;js<4;js++){
          float e0 = exp2f(sv[mi][js][0] - mm);
          float e1 = exp2f(sv[mi][js][1] - mm);
          float e2 = exp2f(sv[mi][js][2] - mm);
          float e3 = exp2f(sv[mi][js][3] - mm);
          l_p[mi] += (e0+e1)+(e2+e3);
          uint2 pk2;
          pk2.x = cvtpk_bf16(e0, e1);
          pk2.y = cvtpk_bf16(e2, e3);
          const int kc8 = js*2 + (g>>1);
          *(uint2*)&Pw[rowoff + ((kc8 ^ (c&7))<<3) + (g&1)*4] = pk2;
        }
      }

      s16x8 pfr[2][2];
#pragma unroll
      for (int mi=0;mi<2;mi++)
#pragma unroll
        for (int kc=0;kc<2;kc++)
          pfr[mi][kc] = *(const s16x8*)&Pw[(mi*16 + c)*64 + (((kc*4+g)^(c&7))<<3)];
      __builtin_amdgcn_s_setprio(1);
#pragma unroll
      for (int dt=0; dt<8; dt++){
#pragma unroll
        for (int kc=0;kc<2;kc++){
          s16x8 vfr = *(const s16x8*)&Vc[(dt*16 + c)*64 + (((kc*4+g)^(c&7))<<3)];
#pragma unroll
          for (int mi=0;mi<2;mi++)
            acc[mi][dt] = __builtin_amdgcn_mfma_f32_16x16x32_bf16(vfr, pfr[mi][kc], acc[mi][dt], 0,0,0);
        }
      }
      __builtin_amdgcn_s_setprio(0);
    }
    __syncthreads();
  }

#pragma unroll
  for (int mi=0;mi<2;mi++){
    float l = l_p[mi];
    l += __shfl_xor(l, 16);
    l += __shfl_xor(l, 32);
    const float inv = 1.f / l;
    const int row = r0w + mi*16 + c;
    unsigned short* dst = &Ar[((size_t)(b*Sq + row))*Dq + h*DHq];
#pragma unroll
    for (int dt=0; dt<8; dt++){
      uint2 o2;
      o2.x = cvtpk_bf16(acc[mi][dt][0]*inv, acc[mi][dt][1]*inv);
      o2.y = cvtpk_bf16(acc[mi][dt][2]*inv, acc[mi][dt][3]*inv);
      *(uint2*)&dst[dt*16 + g*4] = o2;
    }
  }
}

extern "C" void kernel_launch(void* const* d_in, const int* in_sizes, int n_in,
                              void* d_out, int out_size, void* d_ws, size_t ws_size,
                              hipStream_t stream){
  const float* x     = (const float*)d_in[0];
  const float* rp    = (const float*)d_in[1];
  const float* Win   = (const float*)d_in[2];
  const float* b_in  = (const float*)d_in[3];
  const float* Wout  = (const float*)d_in[4];
  const float* b_out = (const float*)d_in[5];
  const float* qk_w  = (const float*)d_in[6];
  const float* out_w = (const float*)d_in[7];
  float* outp = (float*)d_out;

  if (ws_size < (160ull<<20)) return;   // need 160 MiB scratch

  char* ws = (char*)d_ws;
  unsigned short* Xb    = (unsigned short*)(ws);                 // 16 MiB
  unsigned short* Wb    = (unsigned short*)(ws + (16ull<<20));   // 24 MiB
  unsigned short* Woutb = (unsigned short*)(ws + (40ull<<20));   //  8 MiB
  float*          rsc   = (float*)         (ws + (48ull<<20));   // 16 KiB
  float2*         rpcs  = (float2*)        (ws + (49ull<<20));   //  1 MiB
  unsigned short* Qp    = (unsigned short*)(ws + (96ull<<20));   // 16 MiB
  unsigned short* Kp    = (unsigned short*)(ws + (112ull<<20));  // 16 MiB
  unsigned short* Vt    = (unsigned short*)(ws + (128ull<<20));  // 16 MiB
  unsigned short* Ar    = (unsigned short*)(ws + (144ull<<20));  // 16 MiB

  // 1) fused converts (out_w folded into Woutb) + RoPE cos/sin table
  k_convert3<<<2048, 256, 0, stream>>>(x, Win, Wout, out_w, rp, Xb, Wb, Woutb, rpcs);
  // 2) QKV GEMM + fused RoPE/RMS-norm/V-transpose epilogue
  k_gemm1f<<<768, 512, 0, stream>>>(Xb, Wb, b_in, rpcs, qk_w, Qp, Kp, Vt);
  // 3) causal flash attention (pair-balanced 1D grid)
  k_attn<<<512, 256, 0, stream>>>(Qp, Kp, Vt, Ar);
  // 4) row scales for out RMS-norm
  k_rowscale<<<Bq*Sq, 256, 0, stream>>>(Ar, rsc);
  // 5) Out = (Ar . (out_w*Wout)^T) * rscale + b_out
  k_gemm2_8ph<<<256, 512, 0, stream>>>(Ar, Woutb, b_out, rsc, outp);
}